// Round 1
// baseline (4265.818 us; speedup 1.0000x reference)
//
#include <hip/hip_runtime.h>
#include <hip/hip_bf16.h>

// ---------------------------------------------------------------------------
// MotionMambaBlock forward, fp32, correctness-first implementation.
// B=2, L=2048, D_MODEL=512, D_INNER=1024, D_STATE=16, D_CONV=4, DT_RANK=32,
// HIDDEN=2048.
// ---------------------------------------------------------------------------

#define B_   2
#define L_   2048
#define DM   512
#define DI   1024
#define E2   2048   // 2*DI
#define NS   16
#define DTR  32
#define HID  2048
#define ROWS (B_ * L_)   // 4096

__device__ __forceinline__ float sigm(float x) { return 1.f / (1.f + expf(-x)); }

// ---------------------------------------------------------------------------
// LayerNorm over D=512, one wave (64 lanes) per row, 8 elements/lane.
// ---------------------------------------------------------------------------
__global__ __launch_bounds__(64)
void ln_kernel(const float* __restrict__ in, const float* __restrict__ w,
               const float* __restrict__ b, float* __restrict__ out)
{
    const int row  = blockIdx.x;
    const int lane = threadIdx.x;
    const float* p = in + (size_t)row * DM;
    float v[8];
    float s = 0.f;
#pragma unroll
    for (int i = 0; i < 8; ++i) { v[i] = p[lane + 64 * i]; s += v[i]; }
#pragma unroll
    for (int off = 32; off > 0; off >>= 1) s += __shfl_xor(s, off);
    const float mean = s * (1.f / DM);
    float vs = 0.f;
#pragma unroll
    for (int i = 0; i < 8; ++i) { float d = v[i] - mean; vs += d * d; }
#pragma unroll
    for (int off = 32; off > 0; off >>= 1) vs += __shfl_xor(vs, off);
    const float rstd = rsqrtf(vs * (1.f / DM) + 1e-5f);
    float* o = out + (size_t)row * DM;
#pragma unroll
    for (int i = 0; i < 8; ++i) {
        const int c = lane + 64 * i;
        o[c] = (v[i] - mean) * rstd * w[c] + b[c];
    }
}

// ---------------------------------------------------------------------------
// Generic tiled fp32 GEMM: C[M][N] = epilogue( A[M][K] * W[N][K]^T ).
// BM=BN=64, BK=16, 256 threads, 4x4 microtile per thread.
// MODE: 0=none, 1=softplus(v+bias), 2=res+v, 3=gelu(v+bias), 4=res+bias+v
// AVG: A_eff = 0.5*(A + A2)
// ---------------------------------------------------------------------------
template<int MODE, bool AVG>
__global__ __launch_bounds__(256)
void gemm_kernel(const float* __restrict__ A, const float* __restrict__ A2, int lda,
                 const float* __restrict__ W,
                 const float* __restrict__ bias,
                 const float* __restrict__ res, int ldres,
                 float* __restrict__ C,
                 int M, int N, int K)
{
    __shared__ float As[64][17];
    __shared__ float Ws[64][17];
    const int bm = blockIdx.y * 64, bn = blockIdx.x * 64;
    const int tid = threadIdx.x;
    const int lr = tid >> 2;          // 0..63 row of tile loaded by this thread
    const int lc = (tid & 3) << 2;    // 0,4,8,12
    const int tx = tid & 15, ty = tid >> 4;
    float acc[4][4] = {};

    for (int k0 = 0; k0 < K; k0 += 16) {
        float4 av = *(const float4*)(A + (size_t)(bm + lr) * lda + (k0 + lc));
        if (AVG) {
            float4 a2 = *(const float4*)(A2 + (size_t)(bm + lr) * lda + (k0 + lc));
            av.x = 0.5f * (av.x + a2.x); av.y = 0.5f * (av.y + a2.y);
            av.z = 0.5f * (av.z + a2.z); av.w = 0.5f * (av.w + a2.w);
        }
        float4 wv = *(const float4*)(W + (size_t)(bn + lr) * K + (k0 + lc));
        As[lr][lc + 0] = av.x; As[lr][lc + 1] = av.y;
        As[lr][lc + 2] = av.z; As[lr][lc + 3] = av.w;
        Ws[lr][lc + 0] = wv.x; Ws[lr][lc + 1] = wv.y;
        Ws[lr][lc + 2] = wv.z; Ws[lr][lc + 3] = wv.w;
        __syncthreads();
#pragma unroll
        for (int kk = 0; kk < 16; ++kk) {
            const float a0 = As[ty * 4 + 0][kk];
            const float a1 = As[ty * 4 + 1][kk];
            const float a2v = As[ty * 4 + 2][kk];
            const float a3 = As[ty * 4 + 3][kk];
            const float w0 = Ws[tx * 4 + 0][kk];
            const float w1 = Ws[tx * 4 + 1][kk];
            const float w2 = Ws[tx * 4 + 2][kk];
            const float w3 = Ws[tx * 4 + 3][kk];
            acc[0][0] += a0 * w0; acc[0][1] += a0 * w1; acc[0][2] += a0 * w2; acc[0][3] += a0 * w3;
            acc[1][0] += a1 * w0; acc[1][1] += a1 * w1; acc[1][2] += a1 * w2; acc[1][3] += a1 * w3;
            acc[2][0] += a2v * w0; acc[2][1] += a2v * w1; acc[2][2] += a2v * w2; acc[2][3] += a2v * w3;
            acc[3][0] += a3 * w0; acc[3][1] += a3 * w1; acc[3][2] += a3 * w2; acc[3][3] += a3 * w3;
        }
        __syncthreads();
    }

#pragma unroll
    for (int i = 0; i < 4; ++i) {
        const int row = bm + ty * 4 + i;
#pragma unroll
        for (int j = 0; j < 4; ++j) {
            const int col = bn + tx * 4 + j;
            float v = acc[i][j];
            if (MODE == 1) {            // softplus(v + bias)
                v += bias[col];
                v = (v > 20.f) ? v : log1pf(expf(v));
            } else if (MODE == 2) {     // residual + v
                v += res[(size_t)row * ldres + col];
            } else if (MODE == 3) {     // gelu_exact(v + bias)
                v += bias[col];
                v = 0.5f * v * (1.f + erff(v * 0.70710678118654752f));
            } else if (MODE == 4) {     // residual + bias + v
                v += res[(size_t)row * ldres + col] + bias[col];
            }
            C[(size_t)row * N + col] = v;
        }
    }
}

// ---------------------------------------------------------------------------
// Depthwise causal conv (k=4, left pad 3) + SiLU, direction-aware.
// Input: xz [B][L][E2] (u = channels 0..DI-1 in original time order).
// Output: ucv [B][tau][DI] in DIRECTION time order (tau flipped for dir=1).
// ---------------------------------------------------------------------------
__global__ __launch_bounds__(256)
void conv_silu_kernel(const float* __restrict__ xz, const float* __restrict__ w,
                      const float* __restrict__ bias, float* __restrict__ out,
                      int dir)
{
    const int idx = blockIdx.x * 256 + threadIdx.x;   // over B*L*DI
    const int d = idx & (DI - 1);
    const int t = (idx >> 10) & (L_ - 1);
    const int b = idx >> 21;
    const float* base = xz + (size_t)b * L_ * E2;
    float acc = bias[d];
#pragma unroll
    for (int k = 0; k < 4; ++k) {
        const int tt = t - 3 + k;
        if (tt >= 0) {
            const int ol = dir ? (L_ - 1 - tt) : tt;
            acc += w[d * 4 + k] * base[(size_t)ol * E2 + d];
        }
    }
    out[(size_t)idx] = acc * sigm(acc);
}

// ---------------------------------------------------------------------------
// Selective scan. One chain = (b, d), 16 lanes per chain (one per state n).
// 16 chains per 256-thread block. Sequential over L (direction time).
// Applies skip D*u and SiLU(z) gating; writes y at ORIGINAL time index.
// ---------------------------------------------------------------------------
__global__ __launch_bounds__(256)
void scan_kernel(const float* __restrict__ xdbl,   // [B*L][64] dir-time
                 const float* __restrict__ dt,     // [B*L][DI] dir-time (post softplus)
                 const float* __restrict__ ucv,    // [B*L][DI] dir-time (post conv+silu)
                 const float* __restrict__ xz,     // [B][L][E2] orig-time (for z)
                 const float* __restrict__ A_log,  // [DI][NS]
                 const float* __restrict__ Dp,     // [DI]
                 float* __restrict__ y,            // [B][L][DI] orig-time
                 int dir)
{
    const int tid = threadIdx.x;
    const int n = tid & 15;                 // state index
    const int cloc = tid >> 4;              // chain within block
    const int chain = blockIdx.x * 16 + cloc;   // 0 .. B_*DI-1
    const int b = chain >> 10;
    const int d = chain & (DI - 1);

    const float An = -expf(A_log[d * NS + n]);
    const float Dd = Dp[d];
    const float* dtp = dt + (size_t)b * L_ * DI + d;
    const float* up  = ucv + (size_t)b * L_ * DI + d;
    const float* xd  = xdbl + (size_t)b * L_ * 64;
    const float* zbase = xz + (size_t)b * L_ * E2 + DI + d;
    float* ybase = y + (size_t)b * L_ * DI + d;

    float h = 0.f;
    for (int t = 0; t < L_; ++t) {
        const float dtv = dtp[(size_t)t * DI];
        const float uv  = up[(size_t)t * DI];
        const float Bv  = xd[(size_t)t * 64 + 32 + n];
        const float Cv  = xd[(size_t)t * 64 + 48 + n];
        const float dA  = expf(dtv * An);
        h = dA * h + (dtv * uv) * Bv;
        float p = h * Cv;
        p += __shfl_xor(p, 1);
        p += __shfl_xor(p, 2);
        p += __shfl_xor(p, 4);
        p += __shfl_xor(p, 8);
        if (n == 0) {
            const int ol = dir ? (L_ - 1 - t) : t;
            const float zv = zbase[(size_t)ol * E2];
            const float yv = (p + uv * Dd) * (zv * sigm(zv));
            ybase[(size_t)ol * DI] = yv;
        }
    }
}

// ---------------------------------------------------------------------------
// Launch
// ---------------------------------------------------------------------------
extern "C" void kernel_launch(void* const* d_in, const int* in_sizes, int n_in,
                              void* d_out, int out_size, void* d_ws, size_t ws_size,
                              hipStream_t stream)
{
    const float* x         = (const float*)d_in[0];
    const float* ln1_w     = (const float*)d_in[1];
    const float* ln1_b     = (const float*)d_in[2];
    const float* in_proj_w = (const float*)d_in[3];
    // per-direction params: [4..10] fwd, [11..17] bwd
    const float* conv_w[2]    = { (const float*)d_in[4],  (const float*)d_in[11] };
    const float* conv_b[2]    = { (const float*)d_in[5],  (const float*)d_in[12] };
    const float* x_proj_w[2]  = { (const float*)d_in[6],  (const float*)d_in[13] };
    const float* dt_proj_w[2] = { (const float*)d_in[7],  (const float*)d_in[14] };
    const float* dt_proj_b[2] = { (const float*)d_in[8],  (const float*)d_in[15] };
    const float* A_log[2]     = { (const float*)d_in[9],  (const float*)d_in[16] };
    const float* D_param[2]   = { (const float*)d_in[10], (const float*)d_in[17] };
    const float* out_proj_w = (const float*)d_in[18];
    const float* ln2_w      = (const float*)d_in[19];
    const float* ln2_b      = (const float*)d_in[20];
    const float* fc1_w      = (const float*)d_in[21];
    const float* fc1_b      = (const float*)d_in[22];
    const float* fc2_w      = (const float*)d_in[23];
    const float* fc2_b      = (const float*)d_in[24];
    float* out = (float*)d_out;

    float* ws = (float*)d_ws;
    const size_t MF = 1u << 20;   // 1M floats
    // Phase 1 layout (mamba):
    float* xn1 = ws;                         // [0, 2M)      4096x512
    float* xz  = ws + 2 * MF;                // [2M, 10M)    4096x2048
    float* ucv = ws + 10 * MF;               // [10M, 14M)   4096x1024 (per-dir reuse)
    float* xdb = ws + 14 * MF;               // [14M, 14.25M) 4096x64
    float* dtb = ws + 14 * MF + 262144;      // [14.25M, 18.25M) 4096x1024
    float* y0  = ws + 18 * MF + 262144;      // [18.25M, 22.25M)
    float* y1  = ws + 22 * MF + 262144;      // [22.25M, 26.25M)
    // Phase 2 layout (MLP) — reuses phase-1 regions that are dead:
    float* xmid = ws;                        // [0, 2M)   (xn1 dead)
    float* xn2  = ws + 2 * MF;               // [2M, 4M)  (xz dead)
    float* h1   = ws + 4 * MF;               // [4M, 12M) (xz/ucv dead)

    // 1. LN1
    ln_kernel<<<ROWS, 64, 0, stream>>>(x, ln1_w, ln1_b, xn1);

    // 2. in_proj: xz[b][l][e] = xn1 @ in_proj_w^T   (M=4096,N=2048,K=512)
    gemm_kernel<0, false><<<dim3(E2 / 64, ROWS / 64), 256, 0, stream>>>(
        xn1, nullptr, DM, in_proj_w, nullptr, nullptr, 0, xz, ROWS, E2, DM);

    // 3. per-direction mamba
    for (int dir = 0; dir < 2; ++dir) {
        conv_silu_kernel<<<(B_ * L_ * DI) / 256, 256, 0, stream>>>(
            xz, conv_w[dir], conv_b[dir], ucv, dir);

        // x_proj: xdbl = ucv @ x_proj_w^T   (M=4096,N=64,K=1024)
        gemm_kernel<0, false><<<dim3(1, ROWS / 64), 256, 0, stream>>>(
            ucv, nullptr, DI, x_proj_w[dir], nullptr, nullptr, 0, xdb, ROWS, 64, DI);

        // dt = softplus(xdbl[:, :32] @ dt_proj_w^T + b)   (M=4096,N=1024,K=32)
        gemm_kernel<1, false><<<dim3(DI / 64, ROWS / 64), 256, 0, stream>>>(
            xdb, nullptr, 64, dt_proj_w[dir], dt_proj_b[dir], nullptr, 0, dtb,
            ROWS, DI, DTR);

        // selective scan + gating
        scan_kernel<<<(B_ * DI) / 16, 256, 0, stream>>>(
            xdb, dtb, ucv, xz, A_log[dir], D_param[dir],
            dir ? y1 : y0, dir);
    }

    // 4. out_proj with 0.5*(y0+y1) and residual x  (M=4096,N=512,K=1024)
    gemm_kernel<2, true><<<dim3(DM / 64, ROWS / 64), 256, 0, stream>>>(
        y0, y1, DI, out_proj_w, nullptr, x, DM, xmid, ROWS, DM, DI);

    // 5. LN2
    ln_kernel<<<ROWS, 64, 0, stream>>>(xmid, ln2_w, ln2_b, xn2);

    // 6. fc1 + exact GELU  (M=4096,N=2048,K=512)
    gemm_kernel<3, false><<<dim3(HID / 64, ROWS / 64), 256, 0, stream>>>(
        xn2, nullptr, DM, fc1_w, fc1_b, nullptr, 0, h1, ROWS, HID, DM);

    // 7. fc2 + bias + residual -> out  (M=4096,N=512,K=2048)
    gemm_kernel<4, false><<<dim3(DM / 64, ROWS / 64), 256, 0, stream>>>(
        h1, nullptr, HID, fc2_w, fc2_b, xmid, DM, out, ROWS, DM, HID);
}

// Round 2
// 1210.025 us; speedup vs baseline: 3.5254x; 3.5254x over previous
//
#include <hip/hip_runtime.h>
#include <hip/hip_bf16.h>

// ---------------------------------------------------------------------------
// MotionMambaBlock forward, fp32. Round 2: chunked parallel selective scan.
// B=2, L=2048, D_MODEL=512, D_INNER=1024, D_STATE=16, D_CONV=4, DT_RANK=32,
// HIDDEN=2048.
// ---------------------------------------------------------------------------

#define B_   2
#define L_   2048
#define DM   512
#define DI   1024
#define E2   2048   // 2*DI
#define NS   16
#define DTR  32
#define HID  2048
#define ROWS (B_ * L_)   // 4096
#define CH   32          // scan chunks
#define TT   (L_ / CH)   // 64 steps per chunk
#define NCHAIN (B_ * DI) // 2048

__device__ __forceinline__ float sigm(float x) { return 1.f / (1.f + expf(-x)); }

// ---------------------------------------------------------------------------
// LayerNorm over D=512, one wave (64 lanes) per row, 8 elements/lane.
// ---------------------------------------------------------------------------
__global__ __launch_bounds__(64)
void ln_kernel(const float* __restrict__ in, const float* __restrict__ w,
               const float* __restrict__ b, float* __restrict__ out)
{
    const int row  = blockIdx.x;
    const int lane = threadIdx.x;
    const float* p = in + (size_t)row * DM;
    float v[8];
    float s = 0.f;
#pragma unroll
    for (int i = 0; i < 8; ++i) { v[i] = p[lane + 64 * i]; s += v[i]; }
#pragma unroll
    for (int off = 32; off > 0; off >>= 1) s += __shfl_xor(s, off);
    const float mean = s * (1.f / DM);
    float vs = 0.f;
#pragma unroll
    for (int i = 0; i < 8; ++i) { float d = v[i] - mean; vs += d * d; }
#pragma unroll
    for (int off = 32; off > 0; off >>= 1) vs += __shfl_xor(vs, off);
    const float rstd = rsqrtf(vs * (1.f / DM) + 1e-5f);
    float* o = out + (size_t)row * DM;
#pragma unroll
    for (int i = 0; i < 8; ++i) {
        const int c = lane + 64 * i;
        o[c] = (v[i] - mean) * rstd * w[c] + b[c];
    }
}

// ---------------------------------------------------------------------------
// Generic tiled fp32 GEMM: C[M][N] = epilogue( A[M][K] * W[N][K]^T ).
// BM=BN=64, BK=16, 256 threads, 4x4 microtile per thread.
// MODE: 0=none, 1=softplus(v+bias), 2=res+v, 3=gelu(v+bias), 4=res+bias+v
// AVG: A_eff = 0.5*(A + A2)
// ---------------------------------------------------------------------------
template<int MODE, bool AVG>
__global__ __launch_bounds__(256)
void gemm_kernel(const float* __restrict__ A, const float* __restrict__ A2, int lda,
                 const float* __restrict__ W,
                 const float* __restrict__ bias,
                 const float* __restrict__ res, int ldres,
                 float* __restrict__ C,
                 int M, int N, int K)
{
    __shared__ float As[64][17];
    __shared__ float Ws[64][17];
    const int bm = blockIdx.y * 64, bn = blockIdx.x * 64;
    const int tid = threadIdx.x;
    const int lr = tid >> 2;          // 0..63 row of tile loaded by this thread
    const int lc = (tid & 3) << 2;    // 0,4,8,12
    const int tx = tid & 15, ty = tid >> 4;
    float acc[4][4] = {};

    for (int k0 = 0; k0 < K; k0 += 16) {
        float4 av = *(const float4*)(A + (size_t)(bm + lr) * lda + (k0 + lc));
        if (AVG) {
            float4 a2 = *(const float4*)(A2 + (size_t)(bm + lr) * lda + (k0 + lc));
            av.x = 0.5f * (av.x + a2.x); av.y = 0.5f * (av.y + a2.y);
            av.z = 0.5f * (av.z + a2.z); av.w = 0.5f * (av.w + a2.w);
        }
        float4 wv = *(const float4*)(W + (size_t)(bn + lr) * K + (k0 + lc));
        As[lr][lc + 0] = av.x; As[lr][lc + 1] = av.y;
        As[lr][lc + 2] = av.z; As[lr][lc + 3] = av.w;
        Ws[lr][lc + 0] = wv.x; Ws[lr][lc + 1] = wv.y;
        Ws[lr][lc + 2] = wv.z; Ws[lr][lc + 3] = wv.w;
        __syncthreads();
#pragma unroll
        for (int kk = 0; kk < 16; ++kk) {
            const float a0 = As[ty * 4 + 0][kk];
            const float a1 = As[ty * 4 + 1][kk];
            const float a2v = As[ty * 4 + 2][kk];
            const float a3 = As[ty * 4 + 3][kk];
            const float w0 = Ws[tx * 4 + 0][kk];
            const float w1 = Ws[tx * 4 + 1][kk];
            const float w2 = Ws[tx * 4 + 2][kk];
            const float w3 = Ws[tx * 4 + 3][kk];
            acc[0][0] += a0 * w0; acc[0][1] += a0 * w1; acc[0][2] += a0 * w2; acc[0][3] += a0 * w3;
            acc[1][0] += a1 * w0; acc[1][1] += a1 * w1; acc[1][2] += a1 * w2; acc[1][3] += a1 * w3;
            acc[2][0] += a2v * w0; acc[2][1] += a2v * w1; acc[2][2] += a2v * w2; acc[2][3] += a2v * w3;
            acc[3][0] += a3 * w0; acc[3][1] += a3 * w1; acc[3][2] += a3 * w2; acc[3][3] += a3 * w3;
        }
        __syncthreads();
    }

#pragma unroll
    for (int i = 0; i < 4; ++i) {
        const int row = bm + ty * 4 + i;
#pragma unroll
        for (int j = 0; j < 4; ++j) {
            const int col = bn + tx * 4 + j;
            float v = acc[i][j];
            if (MODE == 1) {            // softplus(v + bias)
                v += bias[col];
                v = (v > 20.f) ? v : log1pf(expf(v));
            } else if (MODE == 2) {     // residual + v
                v += res[(size_t)row * ldres + col];
            } else if (MODE == 3) {     // gelu_exact(v + bias)
                v += bias[col];
                v = 0.5f * v * (1.f + erff(v * 0.70710678118654752f));
            } else if (MODE == 4) {     // residual + bias + v
                v += res[(size_t)row * ldres + col] + bias[col];
            }
            C[(size_t)row * N + col] = v;
        }
    }
}

// ---------------------------------------------------------------------------
// Depthwise causal conv (k=4, left pad 3) + SiLU, direction-aware.
// ---------------------------------------------------------------------------
__global__ __launch_bounds__(256)
void conv_silu_kernel(const float* __restrict__ xz, const float* __restrict__ w,
                      const float* __restrict__ bias, float* __restrict__ out,
                      int dir)
{
    const int idx = blockIdx.x * 256 + threadIdx.x;   // over B*L*DI
    const int d = idx & (DI - 1);
    const int t = (idx >> 10) & (L_ - 1);
    const int b = idx >> 21;
    const float* base = xz + (size_t)b * L_ * E2;
    float acc = bias[d];
#pragma unroll
    for (int k = 0; k < 4; ++k) {
        const int tt = t - 3 + k;
        if (tt >= 0) {
            const int ol = dir ? (L_ - 1 - tt) : tt;
            acc += w[d * 4 + k] * base[(size_t)ol * E2 + d];
        }
    }
    out[(size_t)idx] = acc * sigm(acc);
}

// ---------------------------------------------------------------------------
// Chunked selective scan.
// Task = (chunk c, chain). chain = b*DI + d. 16 lanes (one per state n) per
// task, 16 tasks per 256-thread block. task id = c*NCHAIN + chain so that
// consecutive tasks in a wave share t-range and have consecutive d
// (coalesced dt/u, broadcast B/C).
// ---------------------------------------------------------------------------
__global__ __launch_bounds__(256)
void scan_pass1(const float* __restrict__ xdbl,   // [B*L][64] dir-time
                const float* __restrict__ dt,     // [B*L][DI] dir-time
                const float* __restrict__ ucv,    // [B*L][DI] dir-time
                const float* __restrict__ A_log,  // [DI][NS]
                float* __restrict__ P,            // [CH*NCHAIN][NS]
                float* __restrict__ Hend)         // [CH*NCHAIN][NS]
{
    const int tid = threadIdx.x;
    const int n = tid & 15;
    const int task = blockIdx.x * 16 + (tid >> 4);
    const int chain = task & (NCHAIN - 1);
    const int c = task >> 11;
    const int b = chain >> 10;
    const int d = chain & (DI - 1);

    const float An = -expf(A_log[d * NS + n]);
    const size_t t0 = (size_t)b * L_ + c * TT;
    const float* dtp = dt + t0 * DI + d;
    const float* up  = ucv + t0 * DI + d;
    const float* xd  = xdbl + t0 * 64;

    float h = 0.f, p = 1.f;
#pragma unroll 4
    for (int i = 0; i < TT; ++i) {
        const float dtv = dtp[(size_t)i * DI];
        const float uv  = up[(size_t)i * DI];
        const float Bv  = xd[i * 64 + 32 + n];
        const float dA  = expf(dtv * An);
        h = dA * h + (dtv * uv) * Bv;
        p *= dA;
    }
    P[(size_t)task * NS + n] = p;
    Hend[(size_t)task * NS + n] = h;
}

// Serial combine over chunks; Hend is rewritten in place to the INCOMING
// state for each chunk (Hin).
__global__ __launch_bounds__(256)
void scan_pass2(const float* __restrict__ P, float* __restrict__ Hend)
{
    const int tid = threadIdx.x;
    const int n = tid & 15;
    const int chain = blockIdx.x * 16 + (tid >> 4);
    float hin = 0.f;
    for (int c = 0; c < CH; ++c) {
        const size_t idx = ((size_t)c * NCHAIN + chain) * NS + n;
        const float nh = P[idx] * hin + Hend[idx];
        Hend[idx] = hin;
        hin = nh;
    }
}

__global__ __launch_bounds__(256)
void scan_pass3(const float* __restrict__ xdbl,   // [B*L][64] dir-time
                const float* __restrict__ dt,     // [B*L][DI] dir-time
                const float* __restrict__ ucv,    // [B*L][DI] dir-time
                const float* __restrict__ xz,     // [B][L][E2] orig-time (z)
                const float* __restrict__ A_log,  // [DI][NS]
                const float* __restrict__ Dp,     // [DI]
                const float* __restrict__ Hin,    // [CH*NCHAIN][NS]
                float* __restrict__ y,            // [B][L][DI] orig-time
                int dir)
{
    const int tid = threadIdx.x;
    const int n = tid & 15;
    const int task = blockIdx.x * 16 + (tid >> 4);
    const int chain = task & (NCHAIN - 1);
    const int c = task >> 11;
    const int b = chain >> 10;
    const int d = chain & (DI - 1);

    const float An = -expf(A_log[d * NS + n]);
    const float Dd = Dp[d];
    const size_t t0 = (size_t)b * L_ + c * TT;
    const float* dtp = dt + t0 * DI + d;
    const float* up  = ucv + t0 * DI + d;
    const float* xd  = xdbl + t0 * 64;
    const float* zbase = xz + (size_t)b * L_ * E2 + DI + d;
    float* ybase = y + (size_t)b * L_ * DI + d;

    float h = Hin[(size_t)task * NS + n];
    for (int i = 0; i < TT; ++i) {
        const float dtv = dtp[(size_t)i * DI];
        const float uv  = up[(size_t)i * DI];
        const float Bv  = xd[i * 64 + 32 + n];
        const float Cv  = xd[i * 64 + 48 + n];
        const float dA  = expf(dtv * An);
        h = dA * h + (dtv * uv) * Bv;
        float p = h * Cv;
        p += __shfl_xor(p, 1);
        p += __shfl_xor(p, 2);
        p += __shfl_xor(p, 4);
        p += __shfl_xor(p, 8);
        if (n == 0) {
            const int t = c * TT + i;
            const int ol = dir ? (L_ - 1 - t) : t;
            const float zv = zbase[(size_t)ol * E2];
            const float yv = (p + uv * Dd) * (zv * sigm(zv));
            ybase[(size_t)ol * DI] = yv;
        }
    }
}

// ---------------------------------------------------------------------------
// Launch
// ---------------------------------------------------------------------------
extern "C" void kernel_launch(void* const* d_in, const int* in_sizes, int n_in,
                              void* d_out, int out_size, void* d_ws, size_t ws_size,
                              hipStream_t stream)
{
    const float* x         = (const float*)d_in[0];
    const float* ln1_w     = (const float*)d_in[1];
    const float* ln1_b     = (const float*)d_in[2];
    const float* in_proj_w = (const float*)d_in[3];
    const float* conv_w[2]    = { (const float*)d_in[4],  (const float*)d_in[11] };
    const float* conv_b[2]    = { (const float*)d_in[5],  (const float*)d_in[12] };
    const float* x_proj_w[2]  = { (const float*)d_in[6],  (const float*)d_in[13] };
    const float* dt_proj_w[2] = { (const float*)d_in[7],  (const float*)d_in[14] };
    const float* dt_proj_b[2] = { (const float*)d_in[8],  (const float*)d_in[15] };
    const float* A_log[2]     = { (const float*)d_in[9],  (const float*)d_in[16] };
    const float* D_param[2]   = { (const float*)d_in[10], (const float*)d_in[17] };
    const float* out_proj_w = (const float*)d_in[18];
    const float* ln2_w      = (const float*)d_in[19];
    const float* ln2_b      = (const float*)d_in[20];
    const float* fc1_w      = (const float*)d_in[21];
    const float* fc1_b      = (const float*)d_in[22];
    const float* fc2_w      = (const float*)d_in[23];
    const float* fc2_b      = (const float*)d_in[24];
    float* out = (float*)d_out;

    float* ws = (float*)d_ws;
    const size_t MF = 1u << 20;   // 1M floats
    // Phase 1 layout (mamba):
    float* xn1 = ws;                         // [0, 2M)      4096x512
    float* xz  = ws + 2 * MF;                // [2M, 10M)    4096x2048
    float* ucv = ws + 10 * MF;               // [10M, 14M)   4096x1024 (per-dir)
    float* xdb = ws + 14 * MF;               // [14M, 14.25M) 4096x64
    float* dtb = ws + 14 * MF + 262144;      // [14.25M, 18.25M) 4096x1024
    float* y0  = ws + 18 * MF + 262144;      // [18.25M, 22.25M)
    float* y1  = ws + 22 * MF + 262144;      // [22.25M, 26.25M)
    // Scan scratch reuses the dead xn1 region (xn1 unused after in_proj):
    float* Ps   = ws;                        // [0, 1M)  CH*NCHAIN*NS = 1M
    float* Hend = ws + MF;                   // [1M, 2M)
    // Phase 2 layout (MLP) — reuses phase-1 regions that are dead:
    float* xmid = ws;                        // [0, 2M)
    float* xn2  = ws + 2 * MF;               // [2M, 4M)
    float* h1   = ws + 4 * MF;               // [4M, 12M)

    // 1. LN1
    ln_kernel<<<ROWS, 64, 0, stream>>>(x, ln1_w, ln1_b, xn1);

    // 2. in_proj: xz = xn1 @ in_proj_w^T   (M=4096,N=2048,K=512)
    gemm_kernel<0, false><<<dim3(E2 / 64, ROWS / 64), 256, 0, stream>>>(
        xn1, nullptr, DM, in_proj_w, nullptr, nullptr, 0, xz, ROWS, E2, DM);

    // 3. per-direction mamba
    for (int dir = 0; dir < 2; ++dir) {
        conv_silu_kernel<<<(B_ * L_ * DI) / 256, 256, 0, stream>>>(
            xz, conv_w[dir], conv_b[dir], ucv, dir);

        // x_proj: xdbl = ucv @ x_proj_w^T   (M=4096,N=64,K=1024)
        gemm_kernel<0, false><<<dim3(1, ROWS / 64), 256, 0, stream>>>(
            ucv, nullptr, DI, x_proj_w[dir], nullptr, nullptr, 0, xdb, ROWS, 64, DI);

        // dt = softplus(xdbl[:, :32] @ dt_proj_w^T + b)   (M=4096,N=1024,K=32)
        gemm_kernel<1, false><<<dim3(DI / 64, ROWS / 64), 256, 0, stream>>>(
            xdb, nullptr, 64, dt_proj_w[dir], dt_proj_b[dir], nullptr, 0, dtb,
            ROWS, DI, DTR);

        // chunked selective scan
        scan_pass1<<<(CH * NCHAIN) / 16, 256, 0, stream>>>(
            xdb, dtb, ucv, A_log[dir], Ps, Hend);
        scan_pass2<<<NCHAIN / 16, 256, 0, stream>>>(Ps, Hend);
        scan_pass3<<<(CH * NCHAIN) / 16, 256, 0, stream>>>(
            xdb, dtb, ucv, xz, A_log[dir], D_param[dir], Hend,
            dir ? y1 : y0, dir);
    }

    // 4. out_proj with 0.5*(y0+y1) and residual x  (M=4096,N=512,K=1024)
    gemm_kernel<2, true><<<dim3(DM / 64, ROWS / 64), 256, 0, stream>>>(
        y0, y1, DI, out_proj_w, nullptr, x, DM, xmid, ROWS, DM, DI);

    // 5. LN2
    ln_kernel<<<ROWS, 64, 0, stream>>>(xmid, ln2_w, ln2_b, xn2);

    // 6. fc1 + exact GELU  (M=4096,N=2048,K=512)
    gemm_kernel<3, false><<<dim3(HID / 64, ROWS / 64), 256, 0, stream>>>(
        xn2, nullptr, DM, fc1_w, fc1_b, nullptr, 0, h1, ROWS, HID, DM);

    // 7. fc2 + bias + residual -> out  (M=4096,N=512,K=2048)
    gemm_kernel<4, false><<<dim3(DM / 64, ROWS / 64), 256, 0, stream>>>(
        h1, nullptr, HID, fc2_w, fc2_b, xmid, DM, out, ROWS, DM, HID);
}

// Round 3
// 606.991 us; speedup vs baseline: 7.0278x; 1.9935x over previous
//
#include <hip/hip_runtime.h>
#include <hip/hip_bf16.h>

// ---------------------------------------------------------------------------
// MotionMambaBlock forward. Round 3: bf16 MFMA GEMMs (16x16x32), orig-time
// bidirectional layout (no flips), combined-direction x_proj/dt_proj/scan.
// B=2, L=2048, D_MODEL=512, D_INNER=1024, D_STATE=16, D_CONV=4, DT_RANK=32,
// HIDDEN=2048.
// ---------------------------------------------------------------------------

#define B_   2
#define L_   2048
#define DM   512
#define DI   1024
#define E2   2048
#define NS   16
#define HID  2048
#define ROWS (B_ * L_)     // 4096
#define CH   32            // scan chunks
#define TT   (L_ / CH)     // 64
#define NCH  4096          // chains = 2 dirs * B * DI

typedef __bf16 bf16_t;
typedef bf16_t bf16x8 __attribute__((ext_vector_type(8)));
typedef float f32x4 __attribute__((ext_vector_type(4)));

__device__ __forceinline__ float sigm(float x) { return 1.f / (1.f + expf(-x)); }

// ---------------------------------------------------------------------------
// LayerNorm over D=512, one wave per row, bf16 output.
// ---------------------------------------------------------------------------
__global__ __launch_bounds__(64)
void ln_kernel(const float* __restrict__ in, const float* __restrict__ w,
               const float* __restrict__ b, __hip_bfloat16* __restrict__ out)
{
    const int row  = blockIdx.x;
    const int lane = threadIdx.x;
    const float* p = in + (size_t)row * DM;
    float v[8];
    float s = 0.f;
#pragma unroll
    for (int i = 0; i < 8; ++i) { v[i] = p[lane + 64 * i]; s += v[i]; }
#pragma unroll
    for (int off = 32; off > 0; off >>= 1) s += __shfl_xor(s, off);
    const float mean = s * (1.f / DM);
    float vs = 0.f;
#pragma unroll
    for (int i = 0; i < 8; ++i) { float d = v[i] - mean; vs += d * d; }
#pragma unroll
    for (int off = 32; off > 0; off >>= 1) vs += __shfl_xor(vs, off);
    const float rstd = rsqrtf(vs * (1.f / DM) + 1e-5f);
    __hip_bfloat16* o = out + (size_t)row * DM;
#pragma unroll
    for (int i = 0; i < 8; ++i) {
        const int c = lane + 64 * i;
        o[c] = __float2bfloat16((v[i] - mean) * rstd * w[c] + b[c]);
    }
}

// ---------------------------------------------------------------------------
// bf16 MFMA GEMM: C[M][N] = epi( A[M][K] * W[N][K]^T ).
// 128x128 tile, BK=32, 256 threads (4 waves 2x2, each 64x64 = 4x4 frags).
// global_load_lds(16B) staging with XOR-swizzled SOURCE (linear LDS dest),
// swizzled ds_read_b128 fragment loads. 2-barrier K-loop.
// MODE: 0=none, 1=softplus(v+bias), 2=res+v, 3=gelu(v+bias), 4=res+bias+v
// OUT:  0=f32, 1=bf16, 2=f32 split-K partial (stride M*ldc per z, MODE=0)
// ---------------------------------------------------------------------------
template<int MODE, int OUT, int SPLITK>
__global__ __launch_bounds__(256)
void mgemm(const __hip_bfloat16* __restrict__ A, int lda,
           const __hip_bfloat16* __restrict__ W, int ldw,
           const float* __restrict__ bias,
           const float* __restrict__ res, int ldres,
           void* __restrict__ Cptr, int ldc,
           int M, int K)
{
    __shared__ __align__(16) bf16_t lsA[128 * 32];
    __shared__ __align__(16) bf16_t lsB[128 * 32];

    const int bm = blockIdx.y * 128;
    const int bn = blockIdx.x * 128;
    const int kLen = K / SPLITK;
    const int kBeg = blockIdx.z * kLen;

    const int t = threadIdx.x;
    const int l = t & 63, wid = t >> 6;
    const int wr = wid >> 1, wc = wid & 1;
    const int lrow = l & 15, lk = l >> 4;
    const int xorf = (lrow >> 1) & 3;
    const int rdoff = (lk ^ xorf) * 8;    // element offset of 16B chunk in row

    // staging indices: chunk ci covers LDS bytes [ci*16, ci*16+16); row=ci>>2,
    // nominal col-chunk=ci&3; source fetches chunk c^((row>>1)&3) of the row.
    const int r0 = t >> 2,          c0 = t & 3;
    const int r1 = (256 + t) >> 2,  c1 = t & 3;   // second issue: rows 64..127
    const int sc0 = c0 ^ ((r0 >> 1) & 3);
    const int sc1 = c1 ^ ((r1 >> 1) & 3);

    const bf16_t* gA0 = (const bf16_t*)A + (size_t)(bm + r0) * lda + kBeg + sc0 * 8;
    const bf16_t* gA1 = (const bf16_t*)A + (size_t)(bm + r1) * lda + kBeg + sc1 * 8;
    const bf16_t* gB0 = (const bf16_t*)W + (size_t)(bn + r0) * ldw + kBeg + sc0 * 8;
    const bf16_t* gB1 = (const bf16_t*)W + (size_t)(bn + r1) * ldw + kBeg + sc1 * 8;
    bf16_t* dA0 = &lsA[(size_t)t * 8];
    bf16_t* dA1 = &lsA[(size_t)(256 + t) * 8];
    bf16_t* dB0 = &lsB[(size_t)t * 8];
    bf16_t* dB1 = &lsB[(size_t)(256 + t) * 8];

    f32x4 acc[4][4] = {};

    for (int k0 = 0; k0 < kLen; k0 += 32) {
        __builtin_amdgcn_global_load_lds(
            (const __attribute__((address_space(1))) void*)gA0,
            (__attribute__((address_space(3))) void*)dA0, 16, 0, 0);
        __builtin_amdgcn_global_load_lds(
            (const __attribute__((address_space(1))) void*)gA1,
            (__attribute__((address_space(3))) void*)dA1, 16, 0, 0);
        __builtin_amdgcn_global_load_lds(
            (const __attribute__((address_space(1))) void*)gB0,
            (__attribute__((address_space(3))) void*)dB0, 16, 0, 0);
        __builtin_amdgcn_global_load_lds(
            (const __attribute__((address_space(1))) void*)gB1,
            (__attribute__((address_space(3))) void*)dB1, 16, 0, 0);
        gA0 += 32; gA1 += 32; gB0 += 32; gB1 += 32;
        __syncthreads();

        bf16x8 af[4], bfv[4];
#pragma unroll
        for (int m = 0; m < 4; ++m) {
            const int ra = wr * 64 + m * 16 + lrow;
            af[m] = *(const bf16x8*)&lsA[ra * 32 + rdoff];
        }
#pragma unroll
        for (int n = 0; n < 4; ++n) {
            const int rb = wc * 64 + n * 16 + lrow;
            bfv[n] = *(const bf16x8*)&lsB[rb * 32 + rdoff];
        }
#pragma unroll
        for (int m = 0; m < 4; ++m)
#pragma unroll
            for (int n = 0; n < 4; ++n)
                acc[m][n] = __builtin_amdgcn_mfma_f32_16x16x32_bf16(
                    af[m], bfv[n], acc[m][n], 0, 0, 0);
        __syncthreads();
    }

    // Epilogue. C layout per 16x16 frag: col = lane&15, row = (lane>>4)*4+reg.
    float* Cf = (float*)Cptr;
    __hip_bfloat16* Cb = (__hip_bfloat16*)Cptr;
    if (OUT == 2) Cf += (size_t)blockIdx.z * M * ldc;

#pragma unroll
    for (int m = 0; m < 4; ++m) {
#pragma unroll
        for (int n = 0; n < 4; ++n) {
#pragma unroll
            for (int j = 0; j < 4; ++j) {
                const int row = bm + wr * 64 + m * 16 + lk * 4 + j;
                const int col = bn + wc * 64 + n * 16 + lrow;
                float v = acc[m][n][j];
                if (MODE == 1) {
                    v += bias[col];
                    v = (v > 20.f) ? v : log1pf(expf(v));
                } else if (MODE == 2) {
                    v += res[(size_t)row * ldres + col];
                } else if (MODE == 3) {
                    v += bias[col];
                    v = 0.5f * v * (1.f + erff(v * 0.70710678118654752f));
                } else if (MODE == 4) {
                    v += res[(size_t)row * ldres + col] + bias[col];
                }
                if (OUT == 1) Cb[(size_t)row * ldc + col] = __float2bfloat16(v);
                else          Cf[(size_t)row * ldc + col] = v;
            }
        }
    }
}

// ---------------------------------------------------------------------------
// Weight prep kernels (fp32 -> bf16, combined layouts). Run each launch.
// ---------------------------------------------------------------------------
__global__ void k_cvt(const float* __restrict__ s, __hip_bfloat16* __restrict__ d, int n)
{
    const int i = blockIdx.x * 256 + threadIdx.x;
    if (i < n) d[i] = __float2bfloat16(s[i]);
}

// Wxp [128][2048]: block-diag of x_proj_w fwd/bwd (each [64][1024])
__global__ void k_build_xp(const float* __restrict__ Wf, const float* __restrict__ Wb,
                           __hip_bfloat16* __restrict__ o)
{
    const int idx = blockIdx.x * 256 + threadIdx.x;   // 128*2048
    const int r = idx >> 11, c = idx & 2047;
    float v = 0.f;
    if (r < 64) { if (c < 1024) v = Wf[r * 1024 + c]; }
    else        { if (c >= 1024) v = Wb[(r - 64) * 1024 + (c - 1024)]; }
    o[idx] = __float2bfloat16(v);
}

// Wdt [2048][128]: rows<1024: dt_proj_w_f in cols 0..31; rows>=1024: bwd in 64..95
__global__ void k_build_dt(const float* __restrict__ Wf, const float* __restrict__ Wb,
                           const float* __restrict__ bf_, const float* __restrict__ bb_,
                           __hip_bfloat16* __restrict__ o, float* __restrict__ biasO)
{
    const int idx = blockIdx.x * 256 + threadIdx.x;   // 2048*128
    const int r = idx >> 7, c = idx & 127;
    float v = 0.f;
    if (r < 1024) { if (c < 32) v = Wf[r * 32 + c]; }
    else          { if (c >= 64 && c < 96) v = Wb[(r - 1024) * 32 + (c - 64)]; }
    o[idx] = __float2bfloat16(v);
    if (idx < 2048) biasO[idx] = (idx < 1024) ? bf_[idx] : bb_[idx - 1024];
}

// Wop [512][2048]: 0.5*out_proj_w duplicated over both halves of K
__global__ void k_build_wo(const float* __restrict__ Wo, __hip_bfloat16* __restrict__ o)
{
    const int idx = blockIdx.x * 256 + threadIdx.x;   // 512*2048
    const int r = idx >> 11, c = idx & 2047;
    o[idx] = __float2bfloat16(0.5f * Wo[r * 1024 + (c & 1023)]);
}

// ---------------------------------------------------------------------------
// Depthwise conv (k=4) + SiLU, BOTH directions in original time order.
// dir0: causal sum w[k]*xz[t-3+k]; dir1: anticausal sum w[k]*xz[t+3-k].
// out ucv [B][L][2048] bf16, col = dir*1024 + d.
// ---------------------------------------------------------------------------
__global__ __launch_bounds__(256)
void conv2_kernel(const __hip_bfloat16* __restrict__ xz,
                  const float* __restrict__ wf, const float* __restrict__ bf_,
                  const float* __restrict__ wb, const float* __restrict__ bb_,
                  __hip_bfloat16* __restrict__ out)
{
    const int idx = blockIdx.x * 256 + threadIdx.x;   // B*L*2048
    const int e = idx & 2047;
    const int dir = e >> 10;
    const int d = e & 1023;
    const int t = (idx >> 11) & (L_ - 1);
    const int b = idx >> 22;
    const __hip_bfloat16* base = xz + (size_t)b * L_ * E2 + d;  // u columns
    const float* w = dir ? wb : wf;
    float acc = dir ? bb_[d] : bf_[d];
#pragma unroll
    for (int k = 0; k < 4; ++k) {
        const int tt = dir ? (t + 3 - k) : (t - 3 + k);
        if (tt >= 0 && tt < L_)
            acc += w[d * 4 + k] * __bfloat162float(base[(size_t)tt * E2]);
    }
    out[idx] = __float2bfloat16(acc * sigm(acc));
}

// sum 4 split-K partials -> xdb f32 + bf16
__global__ void k_red_xdb(const float* __restrict__ part, float* __restrict__ xf,
                          __hip_bfloat16* __restrict__ xb)
{
    const int idx = blockIdx.x * 256 + threadIdx.x;   // 4096*128
    float s = part[idx] + part[idx + 524288] + part[idx + 2 * 524288] + part[idx + 3 * 524288];
    xf[idx] = s;
    xb[idx] = __float2bfloat16(s);
}

// ---------------------------------------------------------------------------
// Chunked selective scan, both directions. chain = dir*2048 + b*1024 + d.
// Scan step s in [0,L): orig t = dir ? L-1-s : s.
// ---------------------------------------------------------------------------
__global__ __launch_bounds__(256)
void scan_p1(const float* __restrict__ xdb,          // [B*L][128] orig-time
             const __hip_bfloat16* __restrict__ dtb, // [B*L][2048]
             const __hip_bfloat16* __restrict__ ucv, // [B*L][2048]
             const float* __restrict__ AlF, const float* __restrict__ AlB,
             float* __restrict__ P, float* __restrict__ Hend)
{
    const int tid = threadIdx.x;
    const int n = tid & 15;
    const int task = blockIdx.x * 16 + (tid >> 4);
    const int chain = task & (NCH - 1);
    const int c = task >> 12;
    const int dir = chain >> 11;
    const int b = (chain >> 10) & 1;
    const int d = chain & 1023;

    const float* Al = dir ? AlB : AlF;
    const float An = -expf(Al[d * NS + n]);
    const int ecol = dir * 1024 + d;

    float h = 0.f, p = 1.f;
    for (int i = 0; i < TT; ++i) {
        const int s = c * TT + i;
        const int tt = dir ? (L_ - 1 - s) : s;
        const size_t row = (size_t)b * L_ + tt;
        const float dtv = __bfloat162float(dtb[row * E2 + ecol]);
        const float uv  = __bfloat162float(ucv[row * E2 + ecol]);
        const float Bv  = xdb[row * 128 + dir * 64 + 32 + n];
        const float dA  = expf(dtv * An);
        h = dA * h + (dtv * uv) * Bv;
        p *= dA;
    }
    P[(size_t)task * NS + n] = p;
    Hend[(size_t)task * NS + n] = h;
}

__global__ __launch_bounds__(256)
void scan_p2(const float* __restrict__ P, float* __restrict__ Hend)
{
    const int tid = threadIdx.x;
    const int n = tid & 15;
    const int chain = blockIdx.x * 16 + (tid >> 4);
    float hin = 0.f;
    for (int c = 0; c < CH; ++c) {
        const size_t idx = ((size_t)c * NCH + chain) * NS + n;
        const float nh = P[idx] * hin + Hend[idx];
        Hend[idx] = hin;
        hin = nh;
    }
}

__global__ __launch_bounds__(256)
void scan_p3(const float* __restrict__ xdb,
             const __hip_bfloat16* __restrict__ dtb,
             const __hip_bfloat16* __restrict__ ucv,
             const __hip_bfloat16* __restrict__ xz,   // z gate, orig time
             const float* __restrict__ AlF, const float* __restrict__ AlB,
             const float* __restrict__ DpF, const float* __restrict__ DpB,
             const float* __restrict__ Hin,
             __hip_bfloat16* __restrict__ yall)       // [B*L][2048]
{
    const int tid = threadIdx.x;
    const int n = tid & 15;
    const int task = blockIdx.x * 16 + (tid >> 4);
    const int chain = task & (NCH - 1);
    const int c = task >> 12;
    const int dir = chain >> 11;
    const int b = (chain >> 10) & 1;
    const int d = chain & 1023;

    const float* Al = dir ? AlB : AlF;
    const float An = -expf(Al[d * NS + n]);
    const float Dd = (dir ? DpB : DpF)[d];
    const int ecol = dir * 1024 + d;

    float h = Hin[(size_t)task * NS + n];
    for (int i = 0; i < TT; ++i) {
        const int s = c * TT + i;
        const int tt = dir ? (L_ - 1 - s) : s;
        const size_t row = (size_t)b * L_ + tt;
        const float dtv = __bfloat162float(dtb[row * E2 + ecol]);
        const float uv  = __bfloat162float(ucv[row * E2 + ecol]);
        const float Bv  = xdb[row * 128 + dir * 64 + 32 + n];
        const float Cv  = xdb[row * 128 + dir * 64 + 48 + n];
        const float dA  = expf(dtv * An);
        h = dA * h + (dtv * uv) * Bv;
        float p = h * Cv;
        p += __shfl_xor(p, 1);
        p += __shfl_xor(p, 2);
        p += __shfl_xor(p, 4);
        p += __shfl_xor(p, 8);
        if (n == 0) {
            const float zv = __bfloat162float(xz[row * E2 + 1024 + d]);
            yall[row * E2 + ecol] = __float2bfloat16((p + uv * Dd) * (zv * sigm(zv)));
        }
    }
}

// ---------------------------------------------------------------------------
// Launch
// ---------------------------------------------------------------------------
extern "C" void kernel_launch(void* const* d_in, const int* in_sizes, int n_in,
                              void* d_out, int out_size, void* d_ws, size_t ws_size,
                              hipStream_t stream)
{
    const float* x         = (const float*)d_in[0];
    const float* ln1_w     = (const float*)d_in[1];
    const float* ln1_b     = (const float*)d_in[2];
    const float* in_proj_w = (const float*)d_in[3];
    const float* conv_w[2]    = { (const float*)d_in[4],  (const float*)d_in[11] };
    const float* conv_b[2]    = { (const float*)d_in[5],  (const float*)d_in[12] };
    const float* x_proj_w[2]  = { (const float*)d_in[6],  (const float*)d_in[13] };
    const float* dt_proj_w[2] = { (const float*)d_in[7],  (const float*)d_in[14] };
    const float* dt_proj_b[2] = { (const float*)d_in[8],  (const float*)d_in[15] };
    const float* A_log[2]     = { (const float*)d_in[9],  (const float*)d_in[16] };
    const float* D_param[2]   = { (const float*)d_in[10], (const float*)d_in[17] };
    const float* out_proj_w = (const float*)d_in[18];
    const float* ln2_w      = (const float*)d_in[19];
    const float* ln2_b      = (const float*)d_in[20];
    const float* fc1_w      = (const float*)d_in[21];
    const float* fc1_b      = (const float*)d_in[22];
    const float* fc2_w      = (const float*)d_in[23];
    const float* fc2_b      = (const float*)d_in[24];
    float* out = (float*)d_out;

    char* ws = (char*)d_ws;
    const size_t MB = 1u << 20;
    // bf16 weights (resident): 9 MB
    __hip_bfloat16* wip  = (__hip_bfloat16*)(ws + 0 * MB);        // [2048][512]
    __hip_bfloat16* wxp  = (__hip_bfloat16*)(ws + 2 * MB);        // [128][2048]
    __hip_bfloat16* wdt  = (__hip_bfloat16*)(ws + 2 * MB + 512 * 1024); // [2048][128]
    __hip_bfloat16* wop  = (__hip_bfloat16*)(ws + 3 * MB);        // [512][2048]
    __hip_bfloat16* wfc1 = (__hip_bfloat16*)(ws + 5 * MB);        // [2048][512]
    __hip_bfloat16* wfc2 = (__hip_bfloat16*)(ws + 7 * MB);        // [512][2048]
    float* dtbias        = (float*)(ws + 9 * MB);                 // [2048]
    // activations
    __hip_bfloat16* xz   = (__hip_bfloat16*)(ws + 10 * MB);       // [4096][2048]
    __hip_bfloat16* ucv  = (__hip_bfloat16*)(ws + 26 * MB);       // [4096][2048]
    __hip_bfloat16* dtb  = (__hip_bfloat16*)(ws + 42 * MB);       // [4096][2048]
    __hip_bfloat16* yall = (__hip_bfloat16*)(ws + 58 * MB);       // [4096][2048]
    float* xdbf          = (float*)(ws + 74 * MB);                // [4096][128]
    __hip_bfloat16* xdbb = (__hip_bfloat16*)(ws + 76 * MB);       // [4096][128]
    __hip_bfloat16* xn1  = (__hip_bfloat16*)(ws + 77 * MB);       // [4096][512]
    float* xdbp          = (float*)(ws + 81 * MB);                // [4][4096][128] (dead after reduce)
    float* Ps            = (float*)(ws + 81 * MB);                // [CH*NCH][16] (after reduce)
    float* Hend          = (float*)(ws + 89 * MB);                // [CH*NCH][16]  -> 97 MB peak
    // phase 2 (mamba buffers dead)
    float* xmid          = (float*)(ws + 10 * MB);                // [4096][512] f32
    __hip_bfloat16* xn2  = (__hip_bfloat16*)(ws + 18 * MB);       // [4096][512]
    __hip_bfloat16* h1   = (__hip_bfloat16*)(ws + 26 * MB);       // [4096][2048]

    // --- weight prep ---
    k_cvt<<<4096, 256, 0, stream>>>(in_proj_w, wip, 2048 * 512);
    k_cvt<<<4096, 256, 0, stream>>>(fc1_w, wfc1, 2048 * 512);
    k_cvt<<<4096, 256, 0, stream>>>(fc2_w, wfc2, 512 * 2048);
    k_build_xp<<<1024, 256, 0, stream>>>(x_proj_w[0], x_proj_w[1], wxp);
    k_build_dt<<<1024, 256, 0, stream>>>(dt_proj_w[0], dt_proj_w[1],
                                         dt_proj_b[0], dt_proj_b[1], wdt, dtbias);
    k_build_wo<<<4096, 256, 0, stream>>>(out_proj_w, wop);

    // --- mamba branch ---
    ln_kernel<<<ROWS, 64, 0, stream>>>(x, ln1_w, ln1_b, xn1);

    // in_proj: xz = xn1 @ wip^T  (M=4096,N=2048,K=512) -> bf16
    mgemm<0, 1, 1><<<dim3(16, 32, 1), 256, 0, stream>>>(
        xn1, DM, wip, DM, nullptr, nullptr, 0, xz, E2, ROWS, DM);

    conv2_kernel<<<(B_ * L_ * E2) / 256, 256, 0, stream>>>(
        xz, conv_w[0], conv_b[0], conv_w[1], conv_b[1], ucv);

    // x_proj combined: xdb = ucv @ wxp^T  (M=4096,N=128,K=2048), split-K=4
    mgemm<0, 2, 4><<<dim3(1, 32, 4), 256, 0, stream>>>(
        ucv, E2, wxp, E2, nullptr, nullptr, 0, xdbp, 128, ROWS, E2);
    k_red_xdb<<<2048, 256, 0, stream>>>(xdbp, xdbf, xdbb);

    // dt_proj combined: dtb = softplus(xdb @ wdt^T + bias)  (M=4096,N=2048,K=128)
    mgemm<1, 1, 1><<<dim3(16, 32, 1), 256, 0, stream>>>(
        xdbb, 128, wdt, 128, dtbias, nullptr, 0, dtb, E2, ROWS, 128);

    // selective scan, both dirs
    scan_p1<<<(CH * NCH) / 16, 256, 0, stream>>>(
        xdbf, dtb, ucv, A_log[0], A_log[1], Ps, Hend);
    scan_p2<<<NCH / 16, 256, 0, stream>>>(Ps, Hend);
    scan_p3<<<(CH * NCH) / 16, 256, 0, stream>>>(
        xdbf, dtb, ucv, xz, A_log[0], A_log[1], D_param[0], D_param[1],
        Hend, yall);

    // out_proj: xmid = x + yall @ wop^T  (M=4096,N=512,K=2048; 0.5 folded in W)
    mgemm<2, 0, 1><<<dim3(4, 32, 1), 256, 0, stream>>>(
        yall, E2, wop, E2, nullptr, x, DM, xmid, DM, ROWS, E2);

    // --- MLP branch ---
    ln_kernel<<<ROWS, 64, 0, stream>>>(xmid, ln2_w, ln2_b, xn2);

    // fc1 + gelu  (M=4096,N=2048,K=512) -> bf16
    mgemm<3, 1, 1><<<dim3(16, 32, 1), 256, 0, stream>>>(
        xn2, DM, wfc1, DM, fc1_b, nullptr, 0, h1, HID, ROWS, DM);

    // fc2 + bias + residual -> out  (M=4096,N=512,K=2048) f32
    mgemm<4, 0, 1><<<dim3(4, 32, 1), 256, 0, stream>>>(
        h1, HID, wfc2, HID, fc2_b, xmid, DM, out, DM, ROWS, HID);
}

// Round 4
// 522.876 us; speedup vs baseline: 8.1584x; 1.1609x over previous
//
#include <hip/hip_runtime.h>
#include <hip/hip_bf16.h>

// ---------------------------------------------------------------------------
// MotionMambaBlock forward. Round 4: scan-native transposed layout, packed
// bf16 (dt|u) operands, v_exp_f32 fast math, ds_swizzle reduce.
// ---------------------------------------------------------------------------

#define B_   2
#define L_   2048
#define DM   512
#define DI   1024
#define E2   2048
#define NS   16
#define HID  2048
#define ROWS (B_ * L_)     // 4096
#define CH   32            // scan chunks
#define TT   (L_ / CH)     // 64
#define NCH  4096          // chains = 2 dirs * B * DI

typedef __bf16 bf16_t;
typedef bf16_t bf16x8 __attribute__((ext_vector_type(8)));
typedef float f32x4 __attribute__((ext_vector_type(4)));
typedef unsigned int u32;
typedef unsigned short u16;

__device__ __forceinline__ float fexp2(float x) { return __builtin_amdgcn_exp2f(x); }
__device__ __forceinline__ float fexp(float x)  { return fexp2(x * 1.44269504f); }
__device__ __forceinline__ float frcp(float x)  { return __builtin_amdgcn_rcpf(x); }
__device__ __forceinline__ float sigm(float x)  { return frcp(1.f + fexp2(-1.44269504f * x)); }

// ---------------------------------------------------------------------------
// LayerNorm over D=512, one wave per row, bf16 output.
// ---------------------------------------------------------------------------
__global__ __launch_bounds__(64)
void ln_kernel(const float* __restrict__ in, const float* __restrict__ w,
               const float* __restrict__ b, __hip_bfloat16* __restrict__ out)
{
    const int row  = blockIdx.x;
    const int lane = threadIdx.x;
    const float* p = in + (size_t)row * DM;
    float v[8];
    float s = 0.f;
#pragma unroll
    for (int i = 0; i < 8; ++i) { v[i] = p[lane + 64 * i]; s += v[i]; }
#pragma unroll
    for (int off = 32; off > 0; off >>= 1) s += __shfl_xor(s, off);
    const float mean = s * (1.f / DM);
    float vs = 0.f;
#pragma unroll
    for (int i = 0; i < 8; ++i) { float d = v[i] - mean; vs += d * d; }
#pragma unroll
    for (int off = 32; off > 0; off >>= 1) vs += __shfl_xor(vs, off);
    const float rstd = rsqrtf(vs * (1.f / DM) + 1e-5f);
    __hip_bfloat16* o = out + (size_t)row * DM;
#pragma unroll
    for (int i = 0; i < 8; ++i) {
        const int c = lane + 64 * i;
        o[c] = __float2bfloat16((v[i] - mean) * rstd * w[c] + b[c]);
    }
}

// ---------------------------------------------------------------------------
// bf16 MFMA GEMM: C[M][N] = epi( A[M][K] * W[N][K]^T ). 128x128 tile, BK=32.
// MODE: 0=none, 1=softplus(v+bias), 2=res+v, 3=gelu(v+bias), 4=res+bias+v
// OUT:  0=f32, 1=bf16, 2=f32 split-K partial
// ---------------------------------------------------------------------------
template<int MODE, int OUT, int SPLITK>
__global__ __launch_bounds__(256)
void mgemm(const __hip_bfloat16* __restrict__ A, int lda,
           const __hip_bfloat16* __restrict__ W, int ldw,
           const float* __restrict__ bias,
           const float* __restrict__ res, int ldres,
           void* __restrict__ Cptr, int ldc,
           int M, int K)
{
    __shared__ __align__(16) bf16_t lsA[128 * 32];
    __shared__ __align__(16) bf16_t lsB[128 * 32];

    const int bm = blockIdx.y * 128;
    const int bn = blockIdx.x * 128;
    const int kLen = K / SPLITK;
    const int kBeg = blockIdx.z * kLen;

    const int t = threadIdx.x;
    const int l = t & 63, wid = t >> 6;
    const int wr = wid >> 1, wc = wid & 1;
    const int lrow = l & 15, lk = l >> 4;
    const int xorf = (lrow >> 1) & 3;
    const int rdoff = (lk ^ xorf) * 8;

    const int r0 = t >> 2,          c0 = t & 3;
    const int r1 = (256 + t) >> 2,  c1 = t & 3;
    const int sc0 = c0 ^ ((r0 >> 1) & 3);
    const int sc1 = c1 ^ ((r1 >> 1) & 3);

    const bf16_t* gA0 = (const bf16_t*)A + (size_t)(bm + r0) * lda + kBeg + sc0 * 8;
    const bf16_t* gA1 = (const bf16_t*)A + (size_t)(bm + r1) * lda + kBeg + sc1 * 8;
    const bf16_t* gB0 = (const bf16_t*)W + (size_t)(bn + r0) * ldw + kBeg + sc0 * 8;
    const bf16_t* gB1 = (const bf16_t*)W + (size_t)(bn + r1) * ldw + kBeg + sc1 * 8;
    bf16_t* dA0 = &lsA[(size_t)t * 8];
    bf16_t* dA1 = &lsA[(size_t)(256 + t) * 8];
    bf16_t* dB0 = &lsB[(size_t)t * 8];
    bf16_t* dB1 = &lsB[(size_t)(256 + t) * 8];

    f32x4 acc[4][4] = {};

    for (int k0 = 0; k0 < kLen; k0 += 32) {
        __builtin_amdgcn_global_load_lds(
            (const __attribute__((address_space(1))) void*)gA0,
            (__attribute__((address_space(3))) void*)dA0, 16, 0, 0);
        __builtin_amdgcn_global_load_lds(
            (const __attribute__((address_space(1))) void*)gA1,
            (__attribute__((address_space(3))) void*)dA1, 16, 0, 0);
        __builtin_amdgcn_global_load_lds(
            (const __attribute__((address_space(1))) void*)gB0,
            (__attribute__((address_space(3))) void*)dB0, 16, 0, 0);
        __builtin_amdgcn_global_load_lds(
            (const __attribute__((address_space(1))) void*)gB1,
            (__attribute__((address_space(3))) void*)dB1, 16, 0, 0);
        gA0 += 32; gA1 += 32; gB0 += 32; gB1 += 32;
        __syncthreads();

        bf16x8 af[4], bfv[4];
#pragma unroll
        for (int m = 0; m < 4; ++m) {
            const int ra = wr * 64 + m * 16 + lrow;
            af[m] = *(const bf16x8*)&lsA[ra * 32 + rdoff];
        }
#pragma unroll
        for (int n = 0; n < 4; ++n) {
            const int rb = wc * 64 + n * 16 + lrow;
            bfv[n] = *(const bf16x8*)&lsB[rb * 32 + rdoff];
        }
#pragma unroll
        for (int m = 0; m < 4; ++m)
#pragma unroll
            for (int n = 0; n < 4; ++n)
                acc[m][n] = __builtin_amdgcn_mfma_f32_16x16x32_bf16(
                    af[m], bfv[n], acc[m][n], 0, 0, 0);
        __syncthreads();
    }

    float* Cf = (float*)Cptr;
    __hip_bfloat16* Cb = (__hip_bfloat16*)Cptr;
    if (OUT == 2) Cf += (size_t)blockIdx.z * M * ldc;

#pragma unroll
    for (int m = 0; m < 4; ++m) {
#pragma unroll
        for (int n = 0; n < 4; ++n) {
#pragma unroll
            for (int j = 0; j < 4; ++j) {
                const int row = bm + wr * 64 + m * 16 + lk * 4 + j;
                const int col = bn + wc * 64 + n * 16 + lrow;
                float v = acc[m][n][j];
                if (MODE == 1) {            // softplus, fast-exp form
                    v += bias[col];
                    v = (v > 20.f) ? v
                        : 0.69314718f * __builtin_amdgcn_logf(1.f + fexp2(1.44269504f * v));
                } else if (MODE == 2) {
                    v += res[(size_t)row * ldres + col];
                } else if (MODE == 3) {
                    v += bias[col];
                    v = 0.5f * v * (1.f + erff(v * 0.70710678118654752f));
                } else if (MODE == 4) {
                    v += res[(size_t)row * ldres + col] + bias[col];
                }
                if (OUT == 1) Cb[(size_t)row * ldc + col] = __float2bfloat16(v);
                else          Cf[(size_t)row * ldc + col] = v;
            }
        }
    }
}

// ---------------------------------------------------------------------------
// Weight prep kernels.
// ---------------------------------------------------------------------------
__global__ void k_cvt(const float* __restrict__ s, __hip_bfloat16* __restrict__ d, int n)
{
    const int i = blockIdx.x * 256 + threadIdx.x;
    if (i < n) d[i] = __float2bfloat16(s[i]);
}

__global__ void k_build_xp(const float* __restrict__ Wf, const float* __restrict__ Wb,
                           __hip_bfloat16* __restrict__ o)
{
    const int idx = blockIdx.x * 256 + threadIdx.x;   // 128*2048
    const int r = idx >> 11, c = idx & 2047;
    float v = 0.f;
    if (r < 64) { if (c < 1024) v = Wf[r * 1024 + c]; }
    else        { if (c >= 1024) v = Wb[(r - 64) * 1024 + (c - 1024)]; }
    o[idx] = __float2bfloat16(v);
}

__global__ void k_build_dt(const float* __restrict__ Wf, const float* __restrict__ Wb,
                           const float* __restrict__ bf_, const float* __restrict__ bb_,
                           __hip_bfloat16* __restrict__ o, float* __restrict__ biasO)
{
    const int idx = blockIdx.x * 256 + threadIdx.x;   // 2048*128
    const int r = idx >> 7, c = idx & 127;
    float v = 0.f;
    if (r < 1024) { if (c < 32) v = Wf[r * 32 + c]; }
    else          { if (c >= 64 && c < 96) v = Wb[(r - 1024) * 32 + (c - 64)]; }
    o[idx] = __float2bfloat16(v);
    if (idx < 2048) biasO[idx] = (idx < 1024) ? bf_[idx] : bb_[idx - 1024];
}

__global__ void k_build_wo(const float* __restrict__ Wo, __hip_bfloat16* __restrict__ o)
{
    const int idx = blockIdx.x * 256 + threadIdx.x;   // 512*2048
    const int r = idx >> 11, c = idx & 2047;
    o[idx] = __float2bfloat16(0.5f * Wo[r * 1024 + (c & 1023)]);
}

// ---------------------------------------------------------------------------
// Depthwise conv (k=4) + SiLU, both directions, original time order.
// ---------------------------------------------------------------------------
__global__ __launch_bounds__(256)
void conv2_kernel(const __hip_bfloat16* __restrict__ xz,
                  const float* __restrict__ wf, const float* __restrict__ bf_,
                  const float* __restrict__ wb, const float* __restrict__ bb_,
                  __hip_bfloat16* __restrict__ out)
{
    const int idx = blockIdx.x * 256 + threadIdx.x;   // B*L*2048
    const int e = idx & 2047;
    const int dir = e >> 10;
    const int d = e & 1023;
    const int t = (idx >> 11) & (L_ - 1);
    const int b = idx >> 22;
    const __hip_bfloat16* base = xz + (size_t)b * L_ * E2 + d;
    const float* w = dir ? wb : wf;
    float acc = dir ? bb_[d] : bf_[d];
#pragma unroll
    for (int k = 0; k < 4; ++k) {
        const int tt = dir ? (t + 3 - k) : (t - 3 + k);
        if (tt >= 0 && tt < L_)
            acc += w[d * 4 + k] * __bfloat162float(base[(size_t)tt * E2]);
    }
    out[idx] = __float2bfloat16(acc * sigm(acc));
}

// ---------------------------------------------------------------------------
// Split-K reduce for x_proj + scatter B/C into scan-order [chIdx][s] f32.
// ---------------------------------------------------------------------------
__global__ void k_red2(const float* __restrict__ part,
                       __hip_bfloat16* __restrict__ xb,
                       float* __restrict__ sB, float* __restrict__ sC)
{
    const int idx = blockIdx.x * 256 + threadIdx.x;   // 4096*128
    const float s4 = part[idx] + part[idx + 524288]
                   + part[idx + 2 * 524288] + part[idx + 3 * 524288];
    xb[idx] = __float2bfloat16(s4);
    const int col = idx & 127, row = idx >> 7;
    const int c64 = col & 63, dirq = col >> 6;
    if (c64 >= 32) {
        const int bq = row >> 11, tt = row & 2047;
        const int s = dirq ? (L_ - 1 - tt) : tt;
        const int n = c64 & 15;
        float* dst = (c64 < 48 ? sB : sC)
                     + ((size_t)((dirq * 2 + bq) * 16 + n)) * L_ + s;
        *dst = s4;
    }
}

// ---------------------------------------------------------------------------
// Transpose dt/u into packed scan-order layout: sdtdu[chain][s] u32
// (lo16 = bf16 dt, hi16 = bf16 u). LDS-tiled: 64 d x 32 s per block.
// ---------------------------------------------------------------------------
__global__ __launch_bounds__(256)
void k_scanprep(const __hip_bfloat16* __restrict__ dtb,
                const __hip_bfloat16* __restrict__ ucv,
                u32* __restrict__ sdtdu)
{
    __shared__ u32 lds[32][65];
    const int bid = blockIdx.x;
    const int st  = bid & 63;
    const int dtl = (bid >> 6) & 15;
    const int b   = (bid >> 10) & 1;
    const int dir = bid >> 11;
    const int tid = threadIdx.x;
    {
        const int r = tid >> 3, c8 = (tid & 7) * 8;
        const int s = st * 32 + r;
        const int tt = dir ? (L_ - 1 - s) : s;
        const size_t row = (size_t)b * L_ + tt;
        const int e = dir * 1024 + dtl * 64 + c8;
        const uint4 dv = *(const uint4*)((const u16*)dtb + row * E2 + e);
        const uint4 uv = *(const uint4*)((const u16*)ucv + row * E2 + e);
        const u32 dw[4] = { dv.x, dv.y, dv.z, dv.w };
        const u32 uw[4] = { uv.x, uv.y, uv.z, uv.w };
#pragma unroll
        for (int j = 0; j < 4; ++j) {
            lds[r][c8 + 2 * j]     = ((uw[j] & 0xffffu) << 16) | (dw[j] & 0xffffu);
            lds[r][c8 + 2 * j + 1] = (uw[j] & 0xffff0000u) | (dw[j] >> 16);
        }
    }
    __syncthreads();
    {
        const int cd = tid >> 2, s8 = (tid & 3) * 8;
        const int chain = dir * 2048 + b * 1024 + dtl * 64 + cd;
        u32* dst = sdtdu + (size_t)chain * L_ + st * 32 + s8;
#pragma unroll
        for (int j = 0; j < 8; ++j) dst[j] = lds[s8 + j][cd];
    }
}

// ---------------------------------------------------------------------------
// Chunked selective scan on scan-native layout.
// ---------------------------------------------------------------------------
__global__ __launch_bounds__(256)
void scan_p1(const u32* __restrict__ sdtdu, const float* __restrict__ sB,
             const float* __restrict__ AlF, const float* __restrict__ AlB,
             float* __restrict__ P, float* __restrict__ Hend)
{
    const int tid = threadIdx.x;
    const int n = tid & 15;
    const int task = blockIdx.x * 16 + (tid >> 4);
    const int chain = task & (NCH - 1);
    const int c = task >> 12;
    const int dir = chain >> 11;
    const int b = (chain >> 10) & 1;
    const int d = chain & 1023;

    const float* Al = dir ? AlB : AlF;
    const float An2 = -fexp(Al[d * NS + n]) * 1.44269504f;
    const u32* pdt = sdtdu + (size_t)chain * L_ + c * TT;
    const float* pB = sB + ((size_t)((dir * 2 + b) * 16 + n)) * L_ + c * TT;

    float h = 0.f, pp = 1.f;
    for (int i = 0; i < TT; i += 4) {
        const uint4 pk = *(const uint4*)(pdt + i);
        const float4 B4 = *(const float4*)(pB + i);
        const u32 wv[4] = { pk.x, pk.y, pk.z, pk.w };
        const float Bv[4] = { B4.x, B4.y, B4.z, B4.w };
#pragma unroll
        for (int k = 0; k < 4; ++k) {
            const float dt = __uint_as_float(wv[k] << 16);
            const float uu = __uint_as_float(wv[k] & 0xffff0000u);
            const float dA = fexp2(dt * An2);
            h = dA * h + (dt * uu) * Bv[k];
            pp *= dA;
        }
    }
    P[(size_t)task * NS + n] = pp;
    Hend[(size_t)task * NS + n] = h;
}

__global__ __launch_bounds__(256)
void scan_p2(const float* __restrict__ P, float* __restrict__ Hend)
{
    const int tid = threadIdx.x;
    const int n = tid & 15;
    const int chain = blockIdx.x * 16 + (tid >> 4);
    float hin = 0.f;
    for (int c = 0; c < CH; ++c) {
        const size_t idx = ((size_t)c * NCH + chain) * NS + n;
        const float nh = P[idx] * hin + Hend[idx];
        Hend[idx] = hin;
        hin = nh;
    }
}

__global__ __launch_bounds__(256)
void scan_p3(const u32* __restrict__ sdtdu, const float* __restrict__ sB,
             const float* __restrict__ sC,
             const __hip_bfloat16* __restrict__ xz,
             const float* __restrict__ AlF, const float* __restrict__ AlB,
             const float* __restrict__ DpF, const float* __restrict__ DpB,
             const float* __restrict__ Hin,
             __hip_bfloat16* __restrict__ yall)
{
    const int tid = threadIdx.x;
    const int n = tid & 15;
    const int task = blockIdx.x * 16 + (tid >> 4);
    const int chain = task & (NCH - 1);
    const int c = task >> 12;
    const int dir = chain >> 11;
    const int b = (chain >> 10) & 1;
    const int d = chain & 1023;

    const float* Al = dir ? AlB : AlF;
    const float An2 = -fexp(Al[d * NS + n]) * 1.44269504f;
    const float Dd = (dir ? DpB : DpF)[d];
    const int chIdx = (dir * 2 + b) * 16 + n;
    const u32* pdt = sdtdu + (size_t)chain * L_ + c * TT;
    const float* pB = sB + (size_t)chIdx * L_ + c * TT;
    const float* pC = sC + (size_t)chIdx * L_ + c * TT;

    const int t0 = dir ? (L_ - 1 - c * TT) : (c * TT);
    const int step = dir ? -E2 : E2;
    const __hip_bfloat16* zp = xz + ((size_t)b * L_ + t0) * E2 + 1024 + d;
    __hip_bfloat16* yp = yall + ((size_t)b * L_ + t0) * E2 + dir * 1024 + d;

    float h = Hin[(size_t)task * NS + n];
    for (int i = 0; i < TT; i += 4) {
        const uint4 pk = *(const uint4*)(pdt + i);
        const float4 B4 = *(const float4*)(pB + i);
        const float4 C4 = *(const float4*)(pC + i);
        const u32 wv[4] = { pk.x, pk.y, pk.z, pk.w };
        const float Bv[4] = { B4.x, B4.y, B4.z, B4.w };
        const float Cv[4] = { C4.x, C4.y, C4.z, C4.w };
#pragma unroll
        for (int k = 0; k < 4; ++k) {
            const float dt = __uint_as_float(wv[k] << 16);
            const float uu = __uint_as_float(wv[k] & 0xffff0000u);
            const float dA = fexp2(dt * An2);
            h = dA * h + (dt * uu) * Bv[k];
            float q = h * Cv[k];
            q += __int_as_float(__builtin_amdgcn_ds_swizzle(__float_as_int(q), 0x041F));
            q += __int_as_float(__builtin_amdgcn_ds_swizzle(__float_as_int(q), 0x081F));
            q += __int_as_float(__builtin_amdgcn_ds_swizzle(__float_as_int(q), 0x101F));
            q += __int_as_float(__builtin_amdgcn_ds_swizzle(__float_as_int(q), 0x201F));
            if (n == 0) {
                const float z = __bfloat162float(*zp);
                const float g = z * sigm(z);
                *yp = __float2bfloat16((q + uu * Dd) * g);
            }
            zp += step; yp += step;
        }
    }
}

// ---------------------------------------------------------------------------
// Launch
// ---------------------------------------------------------------------------
extern "C" void kernel_launch(void* const* d_in, const int* in_sizes, int n_in,
                              void* d_out, int out_size, void* d_ws, size_t ws_size,
                              hipStream_t stream)
{
    const float* x         = (const float*)d_in[0];
    const float* ln1_w     = (const float*)d_in[1];
    const float* ln1_b     = (const float*)d_in[2];
    const float* in_proj_w = (const float*)d_in[3];
    const float* conv_w[2]    = { (const float*)d_in[4],  (const float*)d_in[11] };
    const float* conv_b[2]    = { (const float*)d_in[5],  (const float*)d_in[12] };
    const float* x_proj_w[2]  = { (const float*)d_in[6],  (const float*)d_in[13] };
    const float* dt_proj_w[2] = { (const float*)d_in[7],  (const float*)d_in[14] };
    const float* dt_proj_b[2] = { (const float*)d_in[8],  (const float*)d_in[15] };
    const float* A_log[2]     = { (const float*)d_in[9],  (const float*)d_in[16] };
    const float* D_param[2]   = { (const float*)d_in[10], (const float*)d_in[17] };
    const float* out_proj_w = (const float*)d_in[18];
    const float* ln2_w      = (const float*)d_in[19];
    const float* ln2_b      = (const float*)d_in[20];
    const float* fc1_w      = (const float*)d_in[21];
    const float* fc1_b      = (const float*)d_in[22];
    const float* fc2_w      = (const float*)d_in[23];
    const float* fc2_b      = (const float*)d_in[24];
    float* out = (float*)d_out;

    char* ws = (char*)d_ws;
    const size_t MB = 1u << 20;
    // resident weights: 0..9.01 MB
    __hip_bfloat16* wip  = (__hip_bfloat16*)(ws + 0 * MB);
    __hip_bfloat16* wxp  = (__hip_bfloat16*)(ws + 2 * MB);
    __hip_bfloat16* wdt  = (__hip_bfloat16*)(ws + 2 * MB + 512 * 1024);
    __hip_bfloat16* wop  = (__hip_bfloat16*)(ws + 3 * MB);
    __hip_bfloat16* wfc1 = (__hip_bfloat16*)(ws + 5 * MB);
    __hip_bfloat16* wfc2 = (__hip_bfloat16*)(ws + 7 * MB);
    float* dtbias        = (float*)(ws + 9 * MB);
    // phase 1
    __hip_bfloat16* xz   = (__hip_bfloat16*)(ws + 10 * MB);  // live thru p3
    __hip_bfloat16* ucv  = (__hip_bfloat16*)(ws + 26 * MB);  // dead after scanprep
    __hip_bfloat16* dtb  = (__hip_bfloat16*)(ws + 42 * MB);  // dead after scanprep
    __hip_bfloat16* xn1  = (__hip_bfloat16*)(ws + 58 * MB);  // dead after in_proj
    float* xdbp          = (float*)(ws + 62 * MB);           // dead after k_red2
    __hip_bfloat16* xdbb = (__hip_bfloat16*)(ws + 70 * MB);  // dead after dt gemm
    u32* sdtdu           = (u32*)(ws + 58 * MB);             // scanprep..p3 (32 MB)
    float* Ps            = (float*)(ws + 26 * MB);           // p1..p3 (in dead ucv)
    float* Hend          = (float*)(ws + 34 * MB);
    __hip_bfloat16* yall = (__hip_bfloat16*)(ws + 90 * MB);  // p3..out_proj
    float* sB            = (float*)(ws + 106 * MB);
    float* sC            = (float*)(ws + 106 * MB + 512 * 1024);  // peak 107 MB
    // phase 2
    float* xmid          = (float*)(ws + 42 * MB);           // over dead dtb
    __hip_bfloat16* xn2  = (__hip_bfloat16*)(ws + 50 * MB);
    __hip_bfloat16* h1   = (__hip_bfloat16*)(ws + 58 * MB);  // over dead sdtdu

    // --- weight prep ---
    k_cvt<<<4096, 256, 0, stream>>>(in_proj_w, wip, 2048 * 512);
    k_cvt<<<4096, 256, 0, stream>>>(fc1_w, wfc1, 2048 * 512);
    k_cvt<<<4096, 256, 0, stream>>>(fc2_w, wfc2, 512 * 2048);
    k_build_xp<<<1024, 256, 0, stream>>>(x_proj_w[0], x_proj_w[1], wxp);
    k_build_dt<<<1024, 256, 0, stream>>>(dt_proj_w[0], dt_proj_w[1],
                                         dt_proj_b[0], dt_proj_b[1], wdt, dtbias);
    k_build_wo<<<4096, 256, 0, stream>>>(out_proj_w, wop);

    // --- mamba branch ---
    ln_kernel<<<ROWS, 64, 0, stream>>>(x, ln1_w, ln1_b, xn1);

    mgemm<0, 1, 1><<<dim3(16, 32, 1), 256, 0, stream>>>(
        xn1, DM, wip, DM, nullptr, nullptr, 0, xz, E2, ROWS, DM);

    conv2_kernel<<<(B_ * L_ * E2) / 256, 256, 0, stream>>>(
        xz, conv_w[0], conv_b[0], conv_w[1], conv_b[1], ucv);

    mgemm<0, 2, 4><<<dim3(1, 32, 4), 256, 0, stream>>>(
        ucv, E2, wxp, E2, nullptr, nullptr, 0, xdbp, 128, ROWS, E2);
    k_red2<<<2048, 256, 0, stream>>>(xdbp, xdbb, sB, sC);

    mgemm<1, 1, 1><<<dim3(16, 32, 1), 256, 0, stream>>>(
        xdbb, 128, wdt, 128, dtbias, nullptr, 0, dtb, E2, ROWS, 128);

    k_scanprep<<<4096, 256, 0, stream>>>(dtb, ucv, sdtdu);

    scan_p1<<<(CH * NCH) / 16, 256, 0, stream>>>(
        sdtdu, sB, A_log[0], A_log[1], Ps, Hend);
    scan_p2<<<NCH / 16, 256, 0, stream>>>(Ps, Hend);
    scan_p3<<<(CH * NCH) / 16, 256, 0, stream>>>(
        sdtdu, sB, sC, xz, A_log[0], A_log[1], D_param[0], D_param[1],
        Hend, yall);

    mgemm<2, 0, 1><<<dim3(4, 32, 1), 256, 0, stream>>>(
        yall, E2, wop, E2, nullptr, x, DM, xmid, DM, ROWS, E2);

    // --- MLP branch ---
    ln_kernel<<<ROWS, 64, 0, stream>>>(xmid, ln2_w, ln2_b, xn2);

    mgemm<3, 1, 1><<<dim3(16, 32, 1), 256, 0, stream>>>(
        xn2, DM, wfc1, DM, fc1_b, nullptr, 0, h1, HID, ROWS, DM);

    mgemm<4, 0, 1><<<dim3(4, 32, 1), 256, 0, stream>>>(
        h1, HID, wfc2, HID, fc2_b, xmid, DM, out, DM, ROWS, HID);
}

// Round 6
// 477.758 us; speedup vs baseline: 8.9288x; 1.0944x over previous
//
#include <hip/hip_runtime.h>
#include <hip/hip_bf16.h>

// ---------------------------------------------------------------------------
// MotionMambaBlock forward. Round 6: R5 structure but reduce reverted to the
// R4-proven ds_swizzle butterfly (DPP showed replay nondeterminism), with
// batched 4-way-ILP reduces. ytr + gate/transpose post-pass retained.
// ---------------------------------------------------------------------------

#define B_   2
#define L_   2048
#define DM   512
#define DI   1024
#define E2   2048
#define NS   16
#define HID  2048
#define ROWS (B_ * L_)     // 4096
#define CH   32            // scan chunks
#define TT   (L_ / CH)     // 64
#define NCH  4096          // chains = 2 dirs * B * DI

typedef __bf16 bf16_t;
typedef bf16_t bf16x8 __attribute__((ext_vector_type(8)));
typedef float f32x4 __attribute__((ext_vector_type(4)));
typedef unsigned int u32;
typedef unsigned short u16;

__device__ __forceinline__ float fexp2(float x) { return __builtin_amdgcn_exp2f(x); }
__device__ __forceinline__ float fexp(float x)  { return fexp2(x * 1.44269504f); }
__device__ __forceinline__ float frcp(float x)  { return __builtin_amdgcn_rcpf(x); }
__device__ __forceinline__ float sigm(float x)  { return frcp(1.f + fexp2(-1.44269504f * x)); }

__device__ __forceinline__ u16 f2bu(float f)
{
    __hip_bfloat16 h = __float2bfloat16(f);
    return *(u16*)&h;
}

// ---------------------------------------------------------------------------
// LayerNorm over D=512, one wave per row, bf16 output.
// ---------------------------------------------------------------------------
__global__ __launch_bounds__(64)
void ln_kernel(const float* __restrict__ in, const float* __restrict__ w,
               const float* __restrict__ b, __hip_bfloat16* __restrict__ out)
{
    const int row  = blockIdx.x;
    const int lane = threadIdx.x;
    const float* p = in + (size_t)row * DM;
    float v[8];
    float s = 0.f;
#pragma unroll
    for (int i = 0; i < 8; ++i) { v[i] = p[lane + 64 * i]; s += v[i]; }
#pragma unroll
    for (int off = 32; off > 0; off >>= 1) s += __shfl_xor(s, off);
    const float mean = s * (1.f / DM);
    float vs = 0.f;
#pragma unroll
    for (int i = 0; i < 8; ++i) { float d = v[i] - mean; vs += d * d; }
#pragma unroll
    for (int off = 32; off > 0; off >>= 1) vs += __shfl_xor(vs, off);
    const float rstd = rsqrtf(vs * (1.f / DM) + 1e-5f);
    __hip_bfloat16* o = out + (size_t)row * DM;
#pragma unroll
    for (int i = 0; i < 8; ++i) {
        const int c = lane + 64 * i;
        o[c] = __float2bfloat16((v[i] - mean) * rstd * w[c] + b[c]);
    }
}

// ---------------------------------------------------------------------------
// bf16 MFMA GEMM: C[M][N] = epi( A[M][K] * W[N][K]^T ). 128x128 tile, BK=32.
// MODE: 0=none, 1=softplus(v+bias), 2=res+v, 3=gelu(v+bias), 4=res+bias+v
// OUT:  0=f32, 1=bf16, 2=f32 split-K partial
// ---------------------------------------------------------------------------
template<int MODE, int OUT, int SPLITK>
__global__ __launch_bounds__(256)
void mgemm(const __hip_bfloat16* __restrict__ A, int lda,
           const __hip_bfloat16* __restrict__ W, int ldw,
           const float* __restrict__ bias,
           const float* __restrict__ res, int ldres,
           void* __restrict__ Cptr, int ldc,
           int M, int K)
{
    __shared__ __align__(16) bf16_t lsA[128 * 32];
    __shared__ __align__(16) bf16_t lsB[128 * 32];

    const int bm = blockIdx.y * 128;
    const int bn = blockIdx.x * 128;
    const int kLen = K / SPLITK;
    const int kBeg = blockIdx.z * kLen;

    const int t = threadIdx.x;
    const int l = t & 63, wid = t >> 6;
    const int wr = wid >> 1, wc = wid & 1;
    const int lrow = l & 15, lk = l >> 4;
    const int xorf = (lrow >> 1) & 3;
    const int rdoff = (lk ^ xorf) * 8;

    const int r0 = t >> 2,          c0 = t & 3;
    const int r1 = (256 + t) >> 2,  c1 = t & 3;
    const int sc0 = c0 ^ ((r0 >> 1) & 3);
    const int sc1 = c1 ^ ((r1 >> 1) & 3);

    const bf16_t* gA0 = (const bf16_t*)A + (size_t)(bm + r0) * lda + kBeg + sc0 * 8;
    const bf16_t* gA1 = (const bf16_t*)A + (size_t)(bm + r1) * lda + kBeg + sc1 * 8;
    const bf16_t* gB0 = (const bf16_t*)W + (size_t)(bn + r0) * ldw + kBeg + sc0 * 8;
    const bf16_t* gB1 = (const bf16_t*)W + (size_t)(bn + r1) * ldw + kBeg + sc1 * 8;
    bf16_t* dA0 = &lsA[(size_t)t * 8];
    bf16_t* dA1 = &lsA[(size_t)(256 + t) * 8];
    bf16_t* dB0 = &lsB[(size_t)t * 8];
    bf16_t* dB1 = &lsB[(size_t)(256 + t) * 8];

    f32x4 acc[4][4] = {};

    for (int k0 = 0; k0 < kLen; k0 += 32) {
        __builtin_amdgcn_global_load_lds(
            (const __attribute__((address_space(1))) void*)gA0,
            (__attribute__((address_space(3))) void*)dA0, 16, 0, 0);
        __builtin_amdgcn_global_load_lds(
            (const __attribute__((address_space(1))) void*)gA1,
            (__attribute__((address_space(3))) void*)dA1, 16, 0, 0);
        __builtin_amdgcn_global_load_lds(
            (const __attribute__((address_space(1))) void*)gB0,
            (__attribute__((address_space(3))) void*)dB0, 16, 0, 0);
        __builtin_amdgcn_global_load_lds(
            (const __attribute__((address_space(1))) void*)gB1,
            (__attribute__((address_space(3))) void*)dB1, 16, 0, 0);
        gA0 += 32; gA1 += 32; gB0 += 32; gB1 += 32;
        __syncthreads();

        bf16x8 af[4], bfv[4];
#pragma unroll
        for (int m = 0; m < 4; ++m) {
            const int ra = wr * 64 + m * 16 + lrow;
            af[m] = *(const bf16x8*)&lsA[ra * 32 + rdoff];
        }
#pragma unroll
        for (int n = 0; n < 4; ++n) {
            const int rb = wc * 64 + n * 16 + lrow;
            bfv[n] = *(const bf16x8*)&lsB[rb * 32 + rdoff];
        }
#pragma unroll
        for (int m = 0; m < 4; ++m)
#pragma unroll
            for (int n = 0; n < 4; ++n)
                acc[m][n] = __builtin_amdgcn_mfma_f32_16x16x32_bf16(
                    af[m], bfv[n], acc[m][n], 0, 0, 0);
        __syncthreads();
    }

    float* Cf = (float*)Cptr;
    __hip_bfloat16* Cb = (__hip_bfloat16*)Cptr;
    if (OUT == 2) Cf += (size_t)blockIdx.z * M * ldc;

#pragma unroll
    for (int m = 0; m < 4; ++m) {
#pragma unroll
        for (int n = 0; n < 4; ++n) {
#pragma unroll
            for (int j = 0; j < 4; ++j) {
                const int row = bm + wr * 64 + m * 16 + lk * 4 + j;
                const int col = bn + wc * 64 + n * 16 + lrow;
                float v = acc[m][n][j];
                if (MODE == 1) {
                    v += bias[col];
                    v = (v > 20.f) ? v
                        : 0.69314718f * __builtin_amdgcn_logf(1.f + fexp2(1.44269504f * v));
                } else if (MODE == 2) {
                    v += res[(size_t)row * ldres + col];
                } else if (MODE == 3) {
                    v += bias[col];
                    v = 0.5f * v * (1.f + erff(v * 0.70710678118654752f));
                } else if (MODE == 4) {
                    v += res[(size_t)row * ldres + col] + bias[col];
                }
                if (OUT == 1) Cb[(size_t)row * ldc + col] = __float2bfloat16(v);
                else          Cf[(size_t)row * ldc + col] = v;
            }
        }
    }
}

// ---------------------------------------------------------------------------
// Weight prep kernels.
// ---------------------------------------------------------------------------
__global__ void k_cvt(const float* __restrict__ s, __hip_bfloat16* __restrict__ d, int n)
{
    const int i = blockIdx.x * 256 + threadIdx.x;
    if (i < n) d[i] = __float2bfloat16(s[i]);
}

__global__ void k_build_xp(const float* __restrict__ Wf, const float* __restrict__ Wb,
                           __hip_bfloat16* __restrict__ o)
{
    const int idx = blockIdx.x * 256 + threadIdx.x;   // 128*2048
    const int r = idx >> 11, c = idx & 2047;
    float v = 0.f;
    if (r < 64) { if (c < 1024) v = Wf[r * 1024 + c]; }
    else        { if (c >= 1024) v = Wb[(r - 64) * 1024 + (c - 1024)]; }
    o[idx] = __float2bfloat16(v);
}

__global__ void k_build_dt(const float* __restrict__ Wf, const float* __restrict__ Wb,
                           const float* __restrict__ bf_, const float* __restrict__ bb_,
                           __hip_bfloat16* __restrict__ o, float* __restrict__ biasO)
{
    const int idx = blockIdx.x * 256 + threadIdx.x;   // 2048*128
    const int r = idx >> 7, c = idx & 127;
    float v = 0.f;
    if (r < 1024) { if (c < 32) v = Wf[r * 32 + c]; }
    else          { if (c >= 64 && c < 96) v = Wb[(r - 1024) * 32 + (c - 64)]; }
    o[idx] = __float2bfloat16(v);
    if (idx < 2048) biasO[idx] = (idx < 1024) ? bf_[idx] : bb_[idx - 1024];
}

__global__ void k_build_wo(const float* __restrict__ Wo, __hip_bfloat16* __restrict__ o)
{
    const int idx = blockIdx.x * 256 + threadIdx.x;   // 512*2048
    const int r = idx >> 11, c = idx & 2047;
    o[idx] = __float2bfloat16(0.5f * Wo[r * 1024 + (c & 1023)]);
}

// ---------------------------------------------------------------------------
// Depthwise conv (k=4) + SiLU, both directions, original time order.
// ---------------------------------------------------------------------------
__global__ __launch_bounds__(256)
void conv2_kernel(const __hip_bfloat16* __restrict__ xz,
                  const float* __restrict__ wf, const float* __restrict__ bf_,
                  const float* __restrict__ wb, const float* __restrict__ bb_,
                  __hip_bfloat16* __restrict__ out)
{
    const int idx = blockIdx.x * 256 + threadIdx.x;   // B*L*2048
    const int e = idx & 2047;
    const int dir = e >> 10;
    const int d = e & 1023;
    const int t = (idx >> 11) & (L_ - 1);
    const int b = idx >> 22;
    const __hip_bfloat16* base = xz + (size_t)b * L_ * E2 + d;
    const float* w = dir ? wb : wf;
    float acc = dir ? bb_[d] : bf_[d];
#pragma unroll
    for (int k = 0; k < 4; ++k) {
        const int tt = dir ? (t + 3 - k) : (t - 3 + k);
        if (tt >= 0 && tt < L_)
            acc += w[d * 4 + k] * __bfloat162float(base[(size_t)tt * E2]);
    }
    out[idx] = __float2bfloat16(acc * sigm(acc));
}

// ---------------------------------------------------------------------------
// Split-K reduce for x_proj + scatter B/C into scan-order [chIdx][s] f32.
// ---------------------------------------------------------------------------
__global__ void k_red2(const float* __restrict__ part,
                       __hip_bfloat16* __restrict__ xb,
                       float* __restrict__ sB, float* __restrict__ sC)
{
    const int idx = blockIdx.x * 256 + threadIdx.x;   // 4096*128
    const float s4 = part[idx] + part[idx + 524288]
                   + part[idx + 2 * 524288] + part[idx + 3 * 524288];
    xb[idx] = __float2bfloat16(s4);
    const int col = idx & 127, row = idx >> 7;
    const int c64 = col & 63, dirq = col >> 6;
    if (c64 >= 32) {
        const int bq = row >> 11, tt = row & 2047;
        const int s = dirq ? (L_ - 1 - tt) : tt;
        const int n = c64 & 15;
        float* dst = (c64 < 48 ? sB : sC)
                     + ((size_t)((dirq * 2 + bq) * 16 + n)) * L_ + s;
        *dst = s4;
    }
}

// ---------------------------------------------------------------------------
// Transpose dt/u into packed scan-order layout: sdtdu[chain][s] u32
// (lo16 = bf16 dt, hi16 = bf16 u). LDS-tiled: 64 d x 32 s per block.
// ---------------------------------------------------------------------------
__global__ __launch_bounds__(256)
void k_scanprep(const __hip_bfloat16* __restrict__ dtb,
                const __hip_bfloat16* __restrict__ ucv,
                u32* __restrict__ sdtdu)
{
    __shared__ u32 lds[32][65];
    const int bid = blockIdx.x;
    const int st  = bid & 63;
    const int dtl = (bid >> 6) & 15;
    const int b   = (bid >> 10) & 1;
    const int dir = bid >> 11;
    const int tid = threadIdx.x;
    {
        const int r = tid >> 3, c8 = (tid & 7) * 8;
        const int s = st * 32 + r;
        const int tt = dir ? (L_ - 1 - s) : s;
        const size_t row = (size_t)b * L_ + tt;
        const int e = dir * 1024 + dtl * 64 + c8;
        const uint4 dv = *(const uint4*)((const u16*)dtb + row * E2 + e);
        const uint4 uv = *(const uint4*)((const u16*)ucv + row * E2 + e);
        const u32 dw[4] = { dv.x, dv.y, dv.z, dv.w };
        const u32 uw[4] = { uv.x, uv.y, uv.z, uv.w };
#pragma unroll
        for (int j = 0; j < 4; ++j) {
            lds[r][c8 + 2 * j]     = ((uw[j] & 0xffffu) << 16) | (dw[j] & 0xffffu);
            lds[r][c8 + 2 * j + 1] = (uw[j] & 0xffff0000u) | (dw[j] >> 16);
        }
    }
    __syncthreads();
    {
        const int cd = tid >> 2, s8 = (tid & 3) * 8;
        const int chain = dir * 2048 + b * 1024 + dtl * 64 + cd;
        u32* dst = sdtdu + (size_t)chain * L_ + st * 32 + s8;
#pragma unroll
        for (int j = 0; j < 8; ++j) dst[j] = lds[s8 + j][cd];
    }
}

// ---------------------------------------------------------------------------
// Chunked selective scan on scan-native layout.
// ---------------------------------------------------------------------------
__global__ __launch_bounds__(256)
void scan_p1(const u32* __restrict__ sdtdu, const float* __restrict__ sB,
             const float* __restrict__ AlF, const float* __restrict__ AlB,
             float* __restrict__ P, float* __restrict__ Hend)
{
    const int tid = threadIdx.x;
    const int n = tid & 15;
    const int task = blockIdx.x * 16 + (tid >> 4);
    const int chain = task & (NCH - 1);
    const int c = task >> 12;
    const int dir = chain >> 11;
    const int b = (chain >> 10) & 1;
    const int d = chain & 1023;

    const float* Al = dir ? AlB : AlF;
    const float An2 = -fexp(Al[d * NS + n]) * 1.44269504f;
    const u32* pdt = sdtdu + (size_t)chain * L_ + c * TT;
    const float* pB = sB + ((size_t)((dir * 2 + b) * 16 + n)) * L_ + c * TT;

    float h = 0.f, pp = 1.f;
    for (int i = 0; i < TT; i += 4) {
        const uint4 pk = *(const uint4*)(pdt + i);
        const float4 B4 = *(const float4*)(pB + i);
        const u32 wv[4] = { pk.x, pk.y, pk.z, pk.w };
        const float Bv[4] = { B4.x, B4.y, B4.z, B4.w };
#pragma unroll
        for (int k = 0; k < 4; ++k) {
            const float dt = __uint_as_float(wv[k] << 16);
            const float uu = __uint_as_float(wv[k] & 0xffff0000u);
            const float dA = fexp2(dt * An2);
            h = dA * h + (dt * uu) * Bv[k];
            pp *= dA;
        }
    }
    P[(size_t)task * NS + n] = pp;
    Hend[(size_t)task * NS + n] = h;
}

__global__ __launch_bounds__(256)
void scan_p2(const float* __restrict__ P, float* __restrict__ Hend)
{
    const int tid = threadIdx.x;
    const int n = tid & 15;
    const int chain = blockIdx.x * 16 + (tid >> 4);
    float hin = 0.f;
    for (int c = 0; c < CH; ++c) {
        const size_t idx = ((size_t)c * NCH + chain) * NS + n;
        const float nh = P[idx] * hin + Hend[idx];
        Hend[idx] = hin;
        hin = nh;
    }
}

// p3: h-chain first, then 4 independent ds_swizzle xor-butterflies (R4-proven
// intrinsic; all 16 lanes end with the group sum). Raw y (+D-skip) packed
// 4 steps per 8-byte store into scan-order ytr[chain][s]. No gating here.
__global__ __launch_bounds__(256)
void scan_p3(const u32* __restrict__ sdtdu, const float* __restrict__ sB,
             const float* __restrict__ sC,
             const float* __restrict__ AlF, const float* __restrict__ AlB,
             const float* __restrict__ DpF, const float* __restrict__ DpB,
             const float* __restrict__ Hin,
             u16* __restrict__ ytr)                   // [NCH][L] bf16 raw
{
    const int tid = threadIdx.x;
    const int n = tid & 15;
    const int task = blockIdx.x * 16 + (tid >> 4);
    const int chain = task & (NCH - 1);
    const int c = task >> 12;
    const int dir = chain >> 11;
    const int b = (chain >> 10) & 1;
    const int d = chain & 1023;

    const float* Al = dir ? AlB : AlF;
    const float An2 = -fexp(Al[d * NS + n]) * 1.44269504f;
    const float Dd = (dir ? DpB : DpF)[d];
    const int chIdx = (dir * 2 + b) * 16 + n;
    const u32* pdt = sdtdu + (size_t)chain * L_ + c * TT;
    const float* pB = sB + (size_t)chIdx * L_ + c * TT;
    const float* pC = sC + (size_t)chIdx * L_ + c * TT;
    u16* yo = ytr + (size_t)chain * L_ + c * TT;

    float h = Hin[(size_t)task * NS + n];
    for (int i = 0; i < TT; i += 4) {
        const uint4 pk = *(const uint4*)(pdt + i);
        const float4 B4 = *(const float4*)(pB + i);
        const float4 C4 = *(const float4*)(pC + i);
        const u32 wv[4] = { pk.x, pk.y, pk.z, pk.w };
        const float Bv[4] = { B4.x, B4.y, B4.z, B4.w };
        const float Cv[4] = { C4.x, C4.y, C4.z, C4.w };
        float qv[4], us[4];
#pragma unroll
        for (int k = 0; k < 4; ++k) {
            const float dt = __uint_as_float(wv[k] << 16);
            const float uu = __uint_as_float(wv[k] & 0xffff0000u);
            us[k] = uu;
            const float dA = fexp2(dt * An2);
            h = dA * h + (dt * uu) * Bv[k];
            qv[k] = h * Cv[k];
        }
        // 4 independent xor-butterfly reduces over the 16-lane group.
#pragma unroll
        for (int k = 0; k < 4; ++k)
            qv[k] += __int_as_float(__builtin_amdgcn_ds_swizzle(__float_as_int(qv[k]), 0x041F));
#pragma unroll
        for (int k = 0; k < 4; ++k)
            qv[k] += __int_as_float(__builtin_amdgcn_ds_swizzle(__float_as_int(qv[k]), 0x081F));
#pragma unroll
        for (int k = 0; k < 4; ++k)
            qv[k] += __int_as_float(__builtin_amdgcn_ds_swizzle(__float_as_int(qv[k]), 0x101F));
#pragma unroll
        for (int k = 0; k < 4; ++k)
            qv[k] += __int_as_float(__builtin_amdgcn_ds_swizzle(__float_as_int(qv[k]), 0x201F));
        if (n == 0) {
            uint2 pkd;
            pkd.x = (u32)f2bu(qv[0] + us[0] * Dd) | ((u32)f2bu(qv[1] + us[1] * Dd) << 16);
            pkd.y = (u32)f2bu(qv[2] + us[2] * Dd) | ((u32)f2bu(qv[3] + us[3] * Dd) << 16);
            *(uint2*)(yo + i) = pkd;
        }
    }
}

// ---------------------------------------------------------------------------
// Post-pass: transpose ytr[chain][s] -> yall[B,L,2048] (orig time), applying
// the SiLU(z) gate. LDS tile 64 chains x 32 s.
// ---------------------------------------------------------------------------
__global__ __launch_bounds__(256)
void k_scanpost(const u16* __restrict__ ytr,
                const __hip_bfloat16* __restrict__ xz,
                __hip_bfloat16* __restrict__ yall)
{
    __shared__ u16 lds[64][34];
    const int bid = blockIdx.x;
    const int st  = bid & 63;
    const int dtl = (bid >> 6) & 15;
    const int b   = (bid >> 10) & 1;
    const int dir = bid >> 11;
    const int tid = threadIdx.x;
    {
        const int cl = tid >> 2, s8 = (tid & 3) * 8;
        const int chain = dir * 2048 + b * 1024 + dtl * 64 + cl;
        const uint4 v = *(const uint4*)(ytr + (size_t)chain * L_ + st * 32 + s8);
        u32* dst = (u32*)&lds[cl][s8];
        dst[0] = v.x; dst[1] = v.y; dst[2] = v.z; dst[3] = v.w;
    }
    __syncthreads();
    {
        const int sl = tid >> 3, d8 = (tid & 7) * 8;
        const int s = st * 32 + sl;
        const int tt = dir ? (L_ - 1 - s) : s;
        const size_t row = (size_t)b * L_ + tt;
        const u16* zp = (const u16*)xz + row * E2 + 1024 + dtl * 64 + d8;
        const uint4 zv = *(const uint4*)zp;
        const u32 zw[4] = { zv.x, zv.y, zv.z, zv.w };
        u16 ov[8];
#pragma unroll
        for (int j = 0; j < 4; ++j) {
            const float z0 = __uint_as_float(zw[j] << 16);
            const float z1 = __uint_as_float(zw[j] & 0xffff0000u);
            const float y0 = __uint_as_float((u32)lds[d8 + 2 * j][sl] << 16);
            const float y1 = __uint_as_float((u32)lds[d8 + 2 * j + 1][sl] << 16);
            ov[2 * j]     = f2bu(y0 * (z0 * sigm(z0)));
            ov[2 * j + 1] = f2bu(y1 * (z1 * sigm(z1)));
        }
        u16* op = (u16*)yall + row * E2 + dir * 1024 + dtl * 64 + d8;
        *(uint4*)op = *(uint4*)ov;
    }
}

// ---------------------------------------------------------------------------
// Launch
// ---------------------------------------------------------------------------
extern "C" void kernel_launch(void* const* d_in, const int* in_sizes, int n_in,
                              void* d_out, int out_size, void* d_ws, size_t ws_size,
                              hipStream_t stream)
{
    const float* x         = (const float*)d_in[0];
    const float* ln1_w     = (const float*)d_in[1];
    const float* ln1_b     = (const float*)d_in[2];
    const float* in_proj_w = (const float*)d_in[3];
    const float* conv_w[2]    = { (const float*)d_in[4],  (const float*)d_in[11] };
    const float* conv_b[2]    = { (const float*)d_in[5],  (const float*)d_in[12] };
    const float* x_proj_w[2]  = { (const float*)d_in[6],  (const float*)d_in[13] };
    const float* dt_proj_w[2] = { (const float*)d_in[7],  (const float*)d_in[14] };
    const float* dt_proj_b[2] = { (const float*)d_in[8],  (const float*)d_in[15] };
    const float* A_log[2]     = { (const float*)d_in[9],  (const float*)d_in[16] };
    const float* D_param[2]   = { (const float*)d_in[10], (const float*)d_in[17] };
    const float* out_proj_w = (const float*)d_in[18];
    const float* ln2_w      = (const float*)d_in[19];
    const float* ln2_b      = (const float*)d_in[20];
    const float* fc1_w      = (const float*)d_in[21];
    const float* fc1_b      = (const float*)d_in[22];
    const float* fc2_w      = (const float*)d_in[23];
    const float* fc2_b      = (const float*)d_in[24];
    float* out = (float*)d_out;

    char* ws = (char*)d_ws;
    const size_t MB = 1u << 20;
    // resident weights: 0..9.01 MB
    __hip_bfloat16* wip  = (__hip_bfloat16*)(ws + 0 * MB);
    __hip_bfloat16* wxp  = (__hip_bfloat16*)(ws + 2 * MB);
    __hip_bfloat16* wdt  = (__hip_bfloat16*)(ws + 2 * MB + 512 * 1024);
    __hip_bfloat16* wop  = (__hip_bfloat16*)(ws + 3 * MB);
    __hip_bfloat16* wfc1 = (__hip_bfloat16*)(ws + 5 * MB);
    __hip_bfloat16* wfc2 = (__hip_bfloat16*)(ws + 7 * MB);
    float* dtbias        = (float*)(ws + 9 * MB);
    // phase 1 lifetimes:
    __hip_bfloat16* xz   = (__hip_bfloat16*)(ws + 10 * MB);  // in_proj..scanpost
    __hip_bfloat16* ucv  = (__hip_bfloat16*)(ws + 26 * MB);  // conv..scanprep
    float* Ps            = (float*)(ws + 26 * MB);           // p1..p2 (over dead ucv)
    float* Hend          = (float*)(ws + 34 * MB);           // p1..p3
    __hip_bfloat16* dtb  = (__hip_bfloat16*)(ws + 42 * MB);  // dtgemm..scanprep
    u16* ytr             = (u16*)(ws + 42 * MB);             // p3..scanpost (over dead dtb)
    __hip_bfloat16* xn1  = (__hip_bfloat16*)(ws + 58 * MB);  // ln1..in_proj
    float* xdbp          = (float*)(ws + 62 * MB);           // xproj..k_red2
    __hip_bfloat16* xdbb = (__hip_bfloat16*)(ws + 70 * MB);  // k_red2..dtgemm
    u32* sdtdu           = (u32*)(ws + 58 * MB);             // scanprep..p3 (32 MB)
    __hip_bfloat16* yall = (__hip_bfloat16*)(ws + 90 * MB);  // scanpost..out_proj
    float* sB            = (float*)(ws + 106 * MB);          // k_red2..p3
    float* sC            = (float*)(ws + 106 * MB + 512 * 1024);  // peak 107 MB
    // phase 2 (mamba buffers dead):
    float* xmid          = (float*)(ws + 10 * MB);           // out_proj..fc2
    __hip_bfloat16* xn2  = (__hip_bfloat16*)(ws + 18 * MB);
    __hip_bfloat16* h1   = (__hip_bfloat16*)(ws + 26 * MB);

    // --- weight prep ---
    k_cvt<<<4096, 256, 0, stream>>>(in_proj_w, wip, 2048 * 512);
    k_cvt<<<4096, 256, 0, stream>>>(fc1_w, wfc1, 2048 * 512);
    k_cvt<<<4096, 256, 0, stream>>>(fc2_w, wfc2, 512 * 2048);
    k_build_xp<<<1024, 256, 0, stream>>>(x_proj_w[0], x_proj_w[1], wxp);
    k_build_dt<<<1024, 256, 0, stream>>>(dt_proj_w[0], dt_proj_w[1],
                                         dt_proj_b[0], dt_proj_b[1], wdt, dtbias);
    k_build_wo<<<4096, 256, 0, stream>>>(out_proj_w, wop);

    // --- mamba branch ---
    ln_kernel<<<ROWS, 64, 0, stream>>>(x, ln1_w, ln1_b, xn1);

    mgemm<0, 1, 1><<<dim3(16, 32, 1), 256, 0, stream>>>(
        xn1, DM, wip, DM, nullptr, nullptr, 0, xz, E2, ROWS, DM);

    conv2_kernel<<<(B_ * L_ * E2) / 256, 256, 0, stream>>>(
        xz, conv_w[0], conv_b[0], conv_w[1], conv_b[1], ucv);

    mgemm<0, 2, 4><<<dim3(1, 32, 4), 256, 0, stream>>>(
        ucv, E2, wxp, E2, nullptr, nullptr, 0, xdbp, 128, ROWS, E2);
    k_red2<<<2048, 256, 0, stream>>>(xdbp, xdbb, sB, sC);

    mgemm<1, 1, 1><<<dim3(16, 32, 1), 256, 0, stream>>>(
        xdbb, 128, wdt, 128, dtbias, nullptr, 0, dtb, E2, ROWS, 128);

    k_scanprep<<<4096, 256, 0, stream>>>(dtb, ucv, sdtdu);

    scan_p1<<<(CH * NCH) / 16, 256, 0, stream>>>(
        sdtdu, sB, A_log[0], A_log[1], Ps, Hend);
    scan_p2<<<NCH / 16, 256, 0, stream>>>(Ps, Hend);
    scan_p3<<<(CH * NCH) / 16, 256, 0, stream>>>(
        sdtdu, sB, sC, A_log[0], A_log[1], D_param[0], D_param[1],
        Hend, ytr);

    k_scanpost<<<4096, 256, 0, stream>>>(ytr, xz, yall);

    mgemm<2, 0, 1><<<dim3(4, 32, 1), 256, 0, stream>>>(
        yall, E2, wop, E2, nullptr, x, DM, xmid, DM, ROWS, E2);

    // --- MLP branch ---
    ln_kernel<<<ROWS, 64, 0, stream>>>(xmid, ln2_w, ln2_b, xn2);

    mgemm<3, 1, 1><<<dim3(16, 32, 1), 256, 0, stream>>>(
        xn2, DM, wfc1, DM, fc1_b, nullptr, 0, h1, HID, ROWS, DM);

    mgemm<4, 0, 1><<<dim3(4, 32, 1), 256, 0, stream>>>(
        h1, HID, wfc2, HID, fc2_b, xmid, DM, out, DM, ROWS, HID);
}

// Round 8
// 333.508 us; speedup vs baseline: 12.7908x; 1.4325x over previous
//
#include <hip/hip_runtime.h>
#include <hip/hip_bf16.h>

// ---------------------------------------------------------------------------
// MotionMambaBlock forward. Round 8: R7 (4 states/lane scan) with the
// ds_swizzle pattern as a template constant (compile fix).
// ---------------------------------------------------------------------------

#define B_   2
#define L_   2048
#define DM   512
#define DI   1024
#define E2   2048
#define NS   16
#define HID  2048
#define ROWS (B_ * L_)     // 4096
#define CH   32            // scan chunks
#define TT   (L_ / CH)     // 64
#define NCH  4096          // chains = 2 dirs * B * DI

typedef __bf16 bf16_t;
typedef bf16_t bf16x8 __attribute__((ext_vector_type(8)));
typedef float f32x4 __attribute__((ext_vector_type(4)));
typedef unsigned int u32;
typedef unsigned short u16;

__device__ __forceinline__ float fexp2(float x) { return __builtin_amdgcn_exp2f(x); }
__device__ __forceinline__ float fexp(float x)  { return fexp2(x * 1.44269504f); }
__device__ __forceinline__ float frcp(float x)  { return __builtin_amdgcn_rcpf(x); }
__device__ __forceinline__ float sigm(float x)  { return frcp(1.f + fexp2(-1.44269504f * x)); }

template<int PAT>
__device__ __forceinline__ float swzadd(float q)
{
    return q + __int_as_float(__builtin_amdgcn_ds_swizzle(__float_as_int(q), PAT));
}

__device__ __forceinline__ u16 f2bu(float f)
{
    __hip_bfloat16 h = __float2bfloat16(f);
    return *(u16*)&h;
}

// ---------------------------------------------------------------------------
// LayerNorm over D=512, one wave per row, bf16 output.
// ---------------------------------------------------------------------------
__global__ __launch_bounds__(64)
void ln_kernel(const float* __restrict__ in, const float* __restrict__ w,
               const float* __restrict__ b, __hip_bfloat16* __restrict__ out)
{
    const int row  = blockIdx.x;
    const int lane = threadIdx.x;
    const float* p = in + (size_t)row * DM;
    float v[8];
    float s = 0.f;
#pragma unroll
    for (int i = 0; i < 8; ++i) { v[i] = p[lane + 64 * i]; s += v[i]; }
#pragma unroll
    for (int off = 32; off > 0; off >>= 1) s += __shfl_xor(s, off);
    const float mean = s * (1.f / DM);
    float vs = 0.f;
#pragma unroll
    for (int i = 0; i < 8; ++i) { float d = v[i] - mean; vs += d * d; }
#pragma unroll
    for (int off = 32; off > 0; off >>= 1) vs += __shfl_xor(vs, off);
    const float rstd = rsqrtf(vs * (1.f / DM) + 1e-5f);
    __hip_bfloat16* o = out + (size_t)row * DM;
#pragma unroll
    for (int i = 0; i < 8; ++i) {
        const int c = lane + 64 * i;
        o[c] = __float2bfloat16((v[i] - mean) * rstd * w[c] + b[c]);
    }
}

// ---------------------------------------------------------------------------
// bf16 MFMA GEMM: C[M][N] = epi( A[M][K] * W[N][K]^T ). 128x128 tile, BK=32.
// MODE: 0=none, 1=softplus(v+bias), 2=res+v, 3=gelu(v+bias), 4=res+bias+v
// OUT:  0=f32, 1=bf16, 2=f32 split-K partial
// ---------------------------------------------------------------------------
template<int MODE, int OUT, int SPLITK>
__global__ __launch_bounds__(256)
void mgemm(const __hip_bfloat16* __restrict__ A, int lda,
           const __hip_bfloat16* __restrict__ W, int ldw,
           const float* __restrict__ bias,
           const float* __restrict__ res, int ldres,
           void* __restrict__ Cptr, int ldc,
           int M, int K)
{
    __shared__ __align__(16) bf16_t lsA[128 * 32];
    __shared__ __align__(16) bf16_t lsB[128 * 32];

    const int bm = blockIdx.y * 128;
    const int bn = blockIdx.x * 128;
    const int kLen = K / SPLITK;
    const int kBeg = blockIdx.z * kLen;

    const int t = threadIdx.x;
    const int l = t & 63, wid = t >> 6;
    const int wr = wid >> 1, wc = wid & 1;
    const int lrow = l & 15, lk = l >> 4;
    const int xorf = (lrow >> 1) & 3;
    const int rdoff = (lk ^ xorf) * 8;

    const int r0 = t >> 2,          c0 = t & 3;
    const int r1 = (256 + t) >> 2,  c1 = t & 3;
    const int sc0 = c0 ^ ((r0 >> 1) & 3);
    const int sc1 = c1 ^ ((r1 >> 1) & 3);

    const bf16_t* gA0 = (const bf16_t*)A + (size_t)(bm + r0) * lda + kBeg + sc0 * 8;
    const bf16_t* gA1 = (const bf16_t*)A + (size_t)(bm + r1) * lda + kBeg + sc1 * 8;
    const bf16_t* gB0 = (const bf16_t*)W + (size_t)(bn + r0) * ldw + kBeg + sc0 * 8;
    const bf16_t* gB1 = (const bf16_t*)W + (size_t)(bn + r1) * ldw + kBeg + sc1 * 8;
    bf16_t* dA0 = &lsA[(size_t)t * 8];
    bf16_t* dA1 = &lsA[(size_t)(256 + t) * 8];
    bf16_t* dB0 = &lsB[(size_t)t * 8];
    bf16_t* dB1 = &lsB[(size_t)(256 + t) * 8];

    f32x4 acc[4][4] = {};

    for (int k0 = 0; k0 < kLen; k0 += 32) {
        __builtin_amdgcn_global_load_lds(
            (const __attribute__((address_space(1))) void*)gA0,
            (__attribute__((address_space(3))) void*)dA0, 16, 0, 0);
        __builtin_amdgcn_global_load_lds(
            (const __attribute__((address_space(1))) void*)gA1,
            (__attribute__((address_space(3))) void*)dA1, 16, 0, 0);
        __builtin_amdgcn_global_load_lds(
            (const __attribute__((address_space(1))) void*)gB0,
            (__attribute__((address_space(3))) void*)dB0, 16, 0, 0);
        __builtin_amdgcn_global_load_lds(
            (const __attribute__((address_space(1))) void*)gB1,
            (__attribute__((address_space(3))) void*)dB1, 16, 0, 0);
        gA0 += 32; gA1 += 32; gB0 += 32; gB1 += 32;
        __syncthreads();

        bf16x8 af[4], bfv[4];
#pragma unroll
        for (int m = 0; m < 4; ++m) {
            const int ra = wr * 64 + m * 16 + lrow;
            af[m] = *(const bf16x8*)&lsA[ra * 32 + rdoff];
        }
#pragma unroll
        for (int n = 0; n < 4; ++n) {
            const int rb = wc * 64 + n * 16 + lrow;
            bfv[n] = *(const bf16x8*)&lsB[rb * 32 + rdoff];
        }
#pragma unroll
        for (int m = 0; m < 4; ++m)
#pragma unroll
            for (int n = 0; n < 4; ++n)
                acc[m][n] = __builtin_amdgcn_mfma_f32_16x16x32_bf16(
                    af[m], bfv[n], acc[m][n], 0, 0, 0);
        __syncthreads();
    }

    float* Cf = (float*)Cptr;
    __hip_bfloat16* Cb = (__hip_bfloat16*)Cptr;
    if (OUT == 2) Cf += (size_t)blockIdx.z * M * ldc;

#pragma unroll
    for (int m = 0; m < 4; ++m) {
#pragma unroll
        for (int n = 0; n < 4; ++n) {
#pragma unroll
            for (int j = 0; j < 4; ++j) {
                const int row = bm + wr * 64 + m * 16 + lk * 4 + j;
                const int col = bn + wc * 64 + n * 16 + lrow;
                float v = acc[m][n][j];
                if (MODE == 1) {
                    v += bias[col];
                    v = (v > 20.f) ? v
                        : 0.69314718f * __builtin_amdgcn_logf(1.f + fexp2(1.44269504f * v));
                } else if (MODE == 2) {
                    v += res[(size_t)row * ldres + col];
                } else if (MODE == 3) {
                    v += bias[col];
                    v = 0.5f * v * (1.f + erff(v * 0.70710678118654752f));
                } else if (MODE == 4) {
                    v += res[(size_t)row * ldres + col] + bias[col];
                }
                if (OUT == 1) Cb[(size_t)row * ldc + col] = __float2bfloat16(v);
                else          Cf[(size_t)row * ldc + col] = v;
            }
        }
    }
}

// ---------------------------------------------------------------------------
// Weight prep kernels.
// ---------------------------------------------------------------------------
__global__ void k_cvt(const float* __restrict__ s, __hip_bfloat16* __restrict__ d, int n)
{
    const int i = blockIdx.x * 256 + threadIdx.x;
    if (i < n) d[i] = __float2bfloat16(s[i]);
}

__global__ void k_build_xp(const float* __restrict__ Wf, const float* __restrict__ Wb,
                           __hip_bfloat16* __restrict__ o)
{
    const int idx = blockIdx.x * 256 + threadIdx.x;   // 128*2048
    const int r = idx >> 11, c = idx & 2047;
    float v = 0.f;
    if (r < 64) { if (c < 1024) v = Wf[r * 1024 + c]; }
    else        { if (c >= 1024) v = Wb[(r - 64) * 1024 + (c - 1024)]; }
    o[idx] = __float2bfloat16(v);
}

__global__ void k_build_dt(const float* __restrict__ Wf, const float* __restrict__ Wb,
                           const float* __restrict__ bf_, const float* __restrict__ bb_,
                           __hip_bfloat16* __restrict__ o, float* __restrict__ biasO)
{
    const int idx = blockIdx.x * 256 + threadIdx.x;   // 2048*128
    const int r = idx >> 7, c = idx & 127;
    float v = 0.f;
    if (r < 1024) { if (c < 32) v = Wf[r * 32 + c]; }
    else          { if (c >= 64 && c < 96) v = Wb[(r - 1024) * 32 + (c - 64)]; }
    o[idx] = __float2bfloat16(v);
    if (idx < 2048) biasO[idx] = (idx < 1024) ? bf_[idx] : bb_[idx - 1024];
}

__global__ void k_build_wo(const float* __restrict__ Wo, __hip_bfloat16* __restrict__ o)
{
    const int idx = blockIdx.x * 256 + threadIdx.x;   // 512*2048
    const int r = idx >> 11, c = idx & 2047;
    o[idx] = __float2bfloat16(0.5f * Wo[r * 1024 + (c & 1023)]);
}

// ---------------------------------------------------------------------------
// Depthwise conv (k=4) + SiLU, both directions, original time order.
// ---------------------------------------------------------------------------
__global__ __launch_bounds__(256)
void conv2_kernel(const __hip_bfloat16* __restrict__ xz,
                  const float* __restrict__ wf, const float* __restrict__ bf_,
                  const float* __restrict__ wb, const float* __restrict__ bb_,
                  __hip_bfloat16* __restrict__ out)
{
    const int idx = blockIdx.x * 256 + threadIdx.x;   // B*L*2048
    const int e = idx & 2047;
    const int dir = e >> 10;
    const int d = e & 1023;
    const int t = (idx >> 11) & (L_ - 1);
    const int b = idx >> 22;
    const __hip_bfloat16* base = xz + (size_t)b * L_ * E2 + d;
    const float* w = dir ? wb : wf;
    float acc = dir ? bb_[d] : bf_[d];
#pragma unroll
    for (int k = 0; k < 4; ++k) {
        const int tt = dir ? (t + 3 - k) : (t - 3 + k);
        if (tt >= 0 && tt < L_)
            acc += w[d * 4 + k] * __bfloat162float(base[(size_t)tt * E2]);
    }
    out[idx] = __float2bfloat16(acc * sigm(acc));
}

// ---------------------------------------------------------------------------
// Split-K reduce for x_proj + scatter B/C into scan-order [g][s][16] f32.
// g = dir*2 + b.
// ---------------------------------------------------------------------------
__global__ void k_red2(const float* __restrict__ part,
                       __hip_bfloat16* __restrict__ xb,
                       float* __restrict__ sB4, float* __restrict__ sC4)
{
    const int idx = blockIdx.x * 256 + threadIdx.x;   // 4096*128
    const float s4 = part[idx] + part[idx + 524288]
                   + part[idx + 2 * 524288] + part[idx + 3 * 524288];
    xb[idx] = __float2bfloat16(s4);
    const int col = idx & 127, row = idx >> 7;
    const int c64 = col & 63, dirq = col >> 6;
    if (c64 >= 32) {
        const int bq = row >> 11, tt = row & 2047;
        const int s = dirq ? (L_ - 1 - tt) : tt;
        const int n = c64 & 15;
        const int g = dirq * 2 + bq;
        float* dst = (c64 < 48 ? sB4 : sC4) + ((size_t)g * L_ + s) * 16 + n;
        *dst = s4;
    }
}

// ---------------------------------------------------------------------------
// Transpose dt/u into packed scan-order layout: sdtdu[chain][s] u32
// (lo16 = bf16 dt, hi16 = bf16 u). LDS-tiled: 64 d x 32 s per block.
// ---------------------------------------------------------------------------
__global__ __launch_bounds__(256)
void k_scanprep(const __hip_bfloat16* __restrict__ dtb,
                const __hip_bfloat16* __restrict__ ucv,
                u32* __restrict__ sdtdu)
{
    __shared__ u32 lds[32][65];
    const int bid = blockIdx.x;
    const int st  = bid & 63;
    const int dtl = (bid >> 6) & 15;
    const int b   = (bid >> 10) & 1;
    const int dir = bid >> 11;
    const int tid = threadIdx.x;
    {
        const int r = tid >> 3, c8 = (tid & 7) * 8;
        const int s = st * 32 + r;
        const int tt = dir ? (L_ - 1 - s) : s;
        const size_t row = (size_t)b * L_ + tt;
        const int e = dir * 1024 + dtl * 64 + c8;
        const uint4 dv = *(const uint4*)((const u16*)dtb + row * E2 + e);
        const uint4 uv = *(const uint4*)((const u16*)ucv + row * E2 + e);
        const u32 dw[4] = { dv.x, dv.y, dv.z, dv.w };
        const u32 uw[4] = { uv.x, uv.y, uv.z, uv.w };
#pragma unroll
        for (int j = 0; j < 4; ++j) {
            lds[r][c8 + 2 * j]     = ((uw[j] & 0xffffu) << 16) | (dw[j] & 0xffffu);
            lds[r][c8 + 2 * j + 1] = (uw[j] & 0xffff0000u) | (dw[j] >> 16);
        }
    }
    __syncthreads();
    {
        const int cd = tid >> 2, s8 = (tid & 3) * 8;
        const int chain = dir * 2048 + b * 1024 + dtl * 64 + cd;
        u32* dst = sdtdu + (size_t)chain * L_ + st * 32 + s8;
#pragma unroll
        for (int j = 0; j < 8; ++j) dst[j] = lds[s8 + j][cd];
    }
}

// ---------------------------------------------------------------------------
// Chunked selective scan: 4 states per lane, 4 lanes per chain, 64 chains
// per 256-thread block. task = c*NCH + chain.
// ---------------------------------------------------------------------------
__global__ __launch_bounds__(256)
void scan_p1(const u32* __restrict__ sdtdu, const float* __restrict__ sB4,
             const float* __restrict__ AlF, const float* __restrict__ AlB,
             float* __restrict__ P, float* __restrict__ Hend)
{
    const int tid = threadIdx.x;
    const int j = tid & 3;
    const int task = blockIdx.x * 64 + (tid >> 2);
    const int chain = task & (NCH - 1);
    const int c = task >> 12;
    const int dir = chain >> 11;
    const int b = (chain >> 10) & 1;
    const int d = chain & 1023;
    const int g = dir * 2 + b;

    const float* Al = dir ? AlB : AlF;
    const float4 al = *(const float4*)(Al + d * NS + j * 4);
    const float An2[4] = { -fexp(al.x) * 1.44269504f, -fexp(al.y) * 1.44269504f,
                           -fexp(al.z) * 1.44269504f, -fexp(al.w) * 1.44269504f };

    const u32* pdt = sdtdu + (size_t)chain * L_ + c * TT;
    const float* pB = sB4 + ((size_t)g * L_ + c * TT) * 16 + j * 4;

    float h[4] = { 0.f, 0.f, 0.f, 0.f };
    float sdt = 0.f;
    for (int i = 0; i < TT; i += 4) {
        const uint4 pk = *(const uint4*)(pdt + i);
        const u32 wv[4] = { pk.x, pk.y, pk.z, pk.w };
#pragma unroll
        for (int k = 0; k < 4; ++k) {
            const float dt = __uint_as_float(wv[k] << 16);
            const float uu = __uint_as_float(wv[k] & 0xffff0000u);
            const float w = dt * uu;
            const float4 B4 = *(const float4*)(pB + (i + k) * 16);
            h[0] = fexp2(dt * An2[0]) * h[0] + w * B4.x;
            h[1] = fexp2(dt * An2[1]) * h[1] + w * B4.y;
            h[2] = fexp2(dt * An2[2]) * h[2] + w * B4.z;
            h[3] = fexp2(dt * An2[3]) * h[3] + w * B4.w;
            sdt += dt;
        }
    }
    // P_n = prod exp2(dt*An2) = exp2(An2 * sum dt)
    float4 Pv = { fexp2(An2[0] * sdt), fexp2(An2[1] * sdt),
                  fexp2(An2[2] * sdt), fexp2(An2[3] * sdt) };
    *(float4*)(P + (size_t)task * NS + j * 4) = Pv;
    float4 Hv = { h[0], h[1], h[2], h[3] };
    *(float4*)(Hend + (size_t)task * NS + j * 4) = Hv;
}

__global__ __launch_bounds__(256)
void scan_p2(const float* __restrict__ P, float* __restrict__ Hend)
{
    const int tid = threadIdx.x;
    const int n = tid & 15;
    const int chain = blockIdx.x * 16 + (tid >> 4);
    float hin = 0.f;
    for (int c = 0; c < CH; ++c) {
        const size_t idx = ((size_t)c * NCH + chain) * NS + n;
        const float nh = P[idx] * hin + Hend[idx];
        Hend[idx] = hin;
        hin = nh;
    }
}

__global__ __launch_bounds__(256)
void scan_p3(const u32* __restrict__ sdtdu, const float* __restrict__ sB4,
             const float* __restrict__ sC4,
             const float* __restrict__ AlF, const float* __restrict__ AlB,
             const float* __restrict__ DpF, const float* __restrict__ DpB,
             const float* __restrict__ Hin,
             u16* __restrict__ ytr)                   // [NCH][L] bf16 raw
{
    const int tid = threadIdx.x;
    const int j = tid & 3;
    const int task = blockIdx.x * 64 + (tid >> 2);
    const int chain = task & (NCH - 1);
    const int c = task >> 12;
    const int dir = chain >> 11;
    const int b = (chain >> 10) & 1;
    const int d = chain & 1023;
    const int g = dir * 2 + b;

    const float* Al = dir ? AlB : AlF;
    const float4 al = *(const float4*)(Al + d * NS + j * 4);
    const float An2[4] = { -fexp(al.x) * 1.44269504f, -fexp(al.y) * 1.44269504f,
                           -fexp(al.z) * 1.44269504f, -fexp(al.w) * 1.44269504f };
    const float Dd = (dir ? DpB : DpF)[d];

    const u32* pdt = sdtdu + (size_t)chain * L_ + c * TT;
    const float* pB = sB4 + ((size_t)g * L_ + c * TT) * 16 + j * 4;
    const float* pC = sC4 + ((size_t)g * L_ + c * TT) * 16 + j * 4;
    u16* yo = ytr + (size_t)chain * L_ + c * TT;

    const float4 hv = *(const float4*)(Hin + (size_t)task * NS + j * 4);
    float h[4] = { hv.x, hv.y, hv.z, hv.w };

    for (int i = 0; i < TT; i += 4) {
        const uint4 pk = *(const uint4*)(pdt + i);
        const u32 wv[4] = { pk.x, pk.y, pk.z, pk.w };
        float qv[4], us[4];
#pragma unroll
        for (int k = 0; k < 4; ++k) {
            const float dt = __uint_as_float(wv[k] << 16);
            const float uu = __uint_as_float(wv[k] & 0xffff0000u);
            us[k] = uu;
            const float w = dt * uu;
            const float4 B4 = *(const float4*)(pB + (i + k) * 16);
            const float4 C4 = *(const float4*)(pC + (i + k) * 16);
            h[0] = fexp2(dt * An2[0]) * h[0] + w * B4.x;
            h[1] = fexp2(dt * An2[1]) * h[1] + w * B4.y;
            h[2] = fexp2(dt * An2[2]) * h[2] + w * B4.z;
            h[3] = fexp2(dt * An2[3]) * h[3] + w * B4.w;
            qv[k] = h[0] * C4.x + h[1] * C4.y + h[2] * C4.z + h[3] * C4.w;
        }
        // 2-stage xor butterfly over the 4-lane group (independent per k).
#pragma unroll
        for (int k = 0; k < 4; ++k) qv[k] = swzadd<0x041F>(qv[k]);
#pragma unroll
        for (int k = 0; k < 4; ++k) qv[k] = swzadd<0x081F>(qv[k]);
        if (j == 0) {
            uint2 pkd;
            pkd.x = (u32)f2bu(qv[0] + us[0] * Dd) | ((u32)f2bu(qv[1] + us[1] * Dd) << 16);
            pkd.y = (u32)f2bu(qv[2] + us[2] * Dd) | ((u32)f2bu(qv[3] + us[3] * Dd) << 16);
            *(uint2*)(yo + i) = pkd;
        }
    }
}

// ---------------------------------------------------------------------------
// Post-pass: transpose ytr[chain][s] -> yall[B,L,2048] (orig time), applying
// the SiLU(z) gate. LDS tile 64 chains x 32 s.
// ---------------------------------------------------------------------------
__global__ __launch_bounds__(256)
void k_scanpost(const u16* __restrict__ ytr,
                const __hip_bfloat16* __restrict__ xz,
                __hip_bfloat16* __restrict__ yall)
{
    __shared__ u16 lds[64][34];
    const int bid = blockIdx.x;
    const int st  = bid & 63;
    const int dtl = (bid >> 6) & 15;
    const int b   = (bid >> 10) & 1;
    const int dir = bid >> 11;
    const int tid = threadIdx.x;
    {
        const int cl = tid >> 2, s8 = (tid & 3) * 8;
        const int chain = dir * 2048 + b * 1024 + dtl * 64 + cl;
        const uint4 v = *(const uint4*)(ytr + (size_t)chain * L_ + st * 32 + s8);
        u32* dst = (u32*)&lds[cl][s8];
        dst[0] = v.x; dst[1] = v.y; dst[2] = v.z; dst[3] = v.w;
    }
    __syncthreads();
    {
        const int sl = tid >> 3, d8 = (tid & 7) * 8;
        const int s = st * 32 + sl;
        const int tt = dir ? (L_ - 1 - s) : s;
        const size_t row = (size_t)b * L_ + tt;
        const u16* zp = (const u16*)xz + row * E2 + 1024 + dtl * 64 + d8;
        const uint4 zv = *(const uint4*)zp;
        const u32 zw[4] = { zv.x, zv.y, zv.z, zv.w };
        u16 ov[8];
#pragma unroll
        for (int jj = 0; jj < 4; ++jj) {
            const float z0 = __uint_as_float(zw[jj] << 16);
            const float z1 = __uint_as_float(zw[jj] & 0xffff0000u);
            const float y0 = __uint_as_float((u32)lds[d8 + 2 * jj][sl] << 16);
            const float y1 = __uint_as_float((u32)lds[d8 + 2 * jj + 1][sl] << 16);
            ov[2 * jj]     = f2bu(y0 * (z0 * sigm(z0)));
            ov[2 * jj + 1] = f2bu(y1 * (z1 * sigm(z1)));
        }
        u16* op = (u16*)yall + row * E2 + dir * 1024 + dtl * 64 + d8;
        *(uint4*)op = *(uint4*)ov;
    }
}

// ---------------------------------------------------------------------------
// Launch
// ---------------------------------------------------------------------------
extern "C" void kernel_launch(void* const* d_in, const int* in_sizes, int n_in,
                              void* d_out, int out_size, void* d_ws, size_t ws_size,
                              hipStream_t stream)
{
    const float* x         = (const float*)d_in[0];
    const float* ln1_w     = (const float*)d_in[1];
    const float* ln1_b     = (const float*)d_in[2];
    const float* in_proj_w = (const float*)d_in[3];
    const float* conv_w[2]    = { (const float*)d_in[4],  (const float*)d_in[11] };
    const float* conv_b[2]    = { (const float*)d_in[5],  (const float*)d_in[12] };
    const float* x_proj_w[2]  = { (const float*)d_in[6],  (const float*)d_in[13] };
    const float* dt_proj_w[2] = { (const float*)d_in[7],  (const float*)d_in[14] };
    const float* dt_proj_b[2] = { (const float*)d_in[8],  (const float*)d_in[15] };
    const float* A_log[2]     = { (const float*)d_in[9],  (const float*)d_in[16] };
    const float* D_param[2]   = { (const float*)d_in[10], (const float*)d_in[17] };
    const float* out_proj_w = (const float*)d_in[18];
    const float* ln2_w      = (const float*)d_in[19];
    const float* ln2_b      = (const float*)d_in[20];
    const float* fc1_w      = (const float*)d_in[21];
    const float* fc1_b      = (const float*)d_in[22];
    const float* fc2_w      = (const float*)d_in[23];
    const float* fc2_b      = (const float*)d_in[24];
    float* out = (float*)d_out;

    char* ws = (char*)d_ws;
    const size_t MB = 1u << 20;
    // resident weights: 0..9.01 MB
    __hip_bfloat16* wip  = (__hip_bfloat16*)(ws + 0 * MB);
    __hip_bfloat16* wxp  = (__hip_bfloat16*)(ws + 2 * MB);
    __hip_bfloat16* wdt  = (__hip_bfloat16*)(ws + 2 * MB + 512 * 1024);
    __hip_bfloat16* wop  = (__hip_bfloat16*)(ws + 3 * MB);
    __hip_bfloat16* wfc1 = (__hip_bfloat16*)(ws + 5 * MB);
    __hip_bfloat16* wfc2 = (__hip_bfloat16*)(ws + 7 * MB);
    float* dtbias        = (float*)(ws + 9 * MB);
    // phase 1 lifetimes:
    __hip_bfloat16* xz   = (__hip_bfloat16*)(ws + 10 * MB);  // in_proj..scanpost
    __hip_bfloat16* ucv  = (__hip_bfloat16*)(ws + 26 * MB);  // conv..scanprep
    float* Ps            = (float*)(ws + 26 * MB);           // p1..p2 (over dead ucv)
    float* Hend          = (float*)(ws + 34 * MB);           // p1..p3
    __hip_bfloat16* dtb  = (__hip_bfloat16*)(ws + 42 * MB);  // dtgemm..scanprep
    u16* ytr             = (u16*)(ws + 42 * MB);             // p3..scanpost (over dead dtb)
    __hip_bfloat16* xn1  = (__hip_bfloat16*)(ws + 58 * MB);  // ln1..in_proj
    float* xdbp          = (float*)(ws + 62 * MB);           // xproj..k_red2
    __hip_bfloat16* xdbb = (__hip_bfloat16*)(ws + 70 * MB);  // k_red2..dtgemm
    u32* sdtdu           = (u32*)(ws + 58 * MB);             // scanprep..p3 (32 MB)
    __hip_bfloat16* yall = (__hip_bfloat16*)(ws + 90 * MB);  // scanpost..out_proj
    float* sB4           = (float*)(ws + 106 * MB);          // k_red2..p3
    float* sC4           = (float*)(ws + 106 * MB + 512 * 1024);  // peak 107 MB
    // phase 2 (mamba buffers dead):
    float* xmid          = (float*)(ws + 10 * MB);           // out_proj..fc2
    __hip_bfloat16* xn2  = (__hip_bfloat16*)(ws + 18 * MB);
    __hip_bfloat16* h1   = (__hip_bfloat16*)(ws + 26 * MB);

    // --- weight prep ---
    k_cvt<<<4096, 256, 0, stream>>>(in_proj_w, wip, 2048 * 512);
    k_cvt<<<4096, 256, 0, stream>>>(fc1_w, wfc1, 2048 * 512);
    k_cvt<<<4096, 256, 0, stream>>>(fc2_w, wfc2, 512 * 2048);
    k_build_xp<<<1024, 256, 0, stream>>>(x_proj_w[0], x_proj_w[1], wxp);
    k_build_dt<<<1024, 256, 0, stream>>>(dt_proj_w[0], dt_proj_w[1],
                                         dt_proj_b[0], dt_proj_b[1], wdt, dtbias);
    k_build_wo<<<4096, 256, 0, stream>>>(out_proj_w, wop);

    // --- mamba branch ---
    ln_kernel<<<ROWS, 64, 0, stream>>>(x, ln1_w, ln1_b, xn1);

    mgemm<0, 1, 1><<<dim3(16, 32, 1), 256, 0, stream>>>(
        xn1, DM, wip, DM, nullptr, nullptr, 0, xz, E2, ROWS, DM);

    conv2_kernel<<<(B_ * L_ * E2) / 256, 256, 0, stream>>>(
        xz, conv_w[0], conv_b[0], conv_w[1], conv_b[1], ucv);

    mgemm<0, 2, 4><<<dim3(1, 32, 4), 256, 0, stream>>>(
        ucv, E2, wxp, E2, nullptr, nullptr, 0, xdbp, 128, ROWS, E2);
    k_red2<<<2048, 256, 0, stream>>>(xdbp, xdbb, sB4, sC4);

    mgemm<1, 1, 1><<<dim3(16, 32, 1), 256, 0, stream>>>(
        xdbb, 128, wdt, 128, dtbias, nullptr, 0, dtb, E2, ROWS, 128);

    k_scanprep<<<4096, 256, 0, stream>>>(dtb, ucv, sdtdu);

    scan_p1<<<(CH * NCH) / 64, 256, 0, stream>>>(
        sdtdu, sB4, A_log[0], A_log[1], Ps, Hend);
    scan_p2<<<NCH / 16, 256, 0, stream>>>(Ps, Hend);
    scan_p3<<<(CH * NCH) / 64, 256, 0, stream>>>(
        sdtdu, sB4, sC4, A_log[0], A_log[1], D_param[0], D_param[1],
        Hend, ytr);

    k_scanpost<<<4096, 256, 0, stream>>>(ytr, xz, yall);

    mgemm<2, 0, 1><<<dim3(4, 32, 1), 256, 0, stream>>>(
        yall, E2, wop, E2, nullptr, x, DM, xmid, DM, ROWS, E2);

    // --- MLP branch ---
    ln_kernel<<<ROWS, 64, 0, stream>>>(xmid, ln2_w, ln2_b, xn2);

    mgemm<3, 1, 1><<<dim3(16, 32, 1), 256, 0, stream>>>(
        xn2, DM, wfc1, DM, fc1_b, nullptr, 0, h1, HID, ROWS, DM);

    mgemm<4, 0, 1><<<dim3(4, 32, 1), 256, 0, stream>>>(
        h1, HID, wfc2, HID, fc2_b, xmid, DM, out, DM, ROWS, HID);
}

// Round 9
// 308.382 us; speedup vs baseline: 13.8329x; 1.0815x over previous
//
#include <hip/hip_runtime.h>
#include <hip/hip_bf16.h>

// ---------------------------------------------------------------------------
// MotionMambaBlock forward. Round 9: split-K=2 for the two N=512 GEMMs
// (out_proj, fc2) + fused residual/bias reduce kernels. Scan as in R8.
// ---------------------------------------------------------------------------

#define B_   2
#define L_   2048
#define DM   512
#define DI   1024
#define E2   2048
#define NS   16
#define HID  2048
#define ROWS (B_ * L_)     // 4096
#define CH   32            // scan chunks
#define TT   (L_ / CH)     // 64
#define NCH  4096          // chains = 2 dirs * B * DI

typedef __bf16 bf16_t;
typedef bf16_t bf16x8 __attribute__((ext_vector_type(8)));
typedef float f32x4 __attribute__((ext_vector_type(4)));
typedef unsigned int u32;
typedef unsigned short u16;

__device__ __forceinline__ float fexp2(float x) { return __builtin_amdgcn_exp2f(x); }
__device__ __forceinline__ float fexp(float x)  { return fexp2(x * 1.44269504f); }
__device__ __forceinline__ float frcp(float x)  { return __builtin_amdgcn_rcpf(x); }
__device__ __forceinline__ float sigm(float x)  { return frcp(1.f + fexp2(-1.44269504f * x)); }

template<int PAT>
__device__ __forceinline__ float swzadd(float q)
{
    return q + __int_as_float(__builtin_amdgcn_ds_swizzle(__float_as_int(q), PAT));
}

__device__ __forceinline__ u16 f2bu(float f)
{
    __hip_bfloat16 h = __float2bfloat16(f);
    return *(u16*)&h;
}

// ---------------------------------------------------------------------------
// LayerNorm over D=512, one wave per row, bf16 output.
// ---------------------------------------------------------------------------
__global__ __launch_bounds__(64)
void ln_kernel(const float* __restrict__ in, const float* __restrict__ w,
               const float* __restrict__ b, __hip_bfloat16* __restrict__ out)
{
    const int row  = blockIdx.x;
    const int lane = threadIdx.x;
    const float* p = in + (size_t)row * DM;
    float v[8];
    float s = 0.f;
#pragma unroll
    for (int i = 0; i < 8; ++i) { v[i] = p[lane + 64 * i]; s += v[i]; }
#pragma unroll
    for (int off = 32; off > 0; off >>= 1) s += __shfl_xor(s, off);
    const float mean = s * (1.f / DM);
    float vs = 0.f;
#pragma unroll
    for (int i = 0; i < 8; ++i) { float d = v[i] - mean; vs += d * d; }
#pragma unroll
    for (int off = 32; off > 0; off >>= 1) vs += __shfl_xor(vs, off);
    const float rstd = rsqrtf(vs * (1.f / DM) + 1e-5f);
    __hip_bfloat16* o = out + (size_t)row * DM;
#pragma unroll
    for (int i = 0; i < 8; ++i) {
        const int c = lane + 64 * i;
        o[c] = __float2bfloat16((v[i] - mean) * rstd * w[c] + b[c]);
    }
}

// ---------------------------------------------------------------------------
// bf16 MFMA GEMM: C[M][N] = epi( A[M][K] * W[N][K]^T ). 128x128 tile, BK=32.
// MODE: 0=none, 1=softplus(v+bias), 2=res+v, 3=gelu(v+bias), 4=res+bias+v
// OUT:  0=f32, 1=bf16, 2=f32 split-K partial
// ---------------------------------------------------------------------------
template<int MODE, int OUT, int SPLITK>
__global__ __launch_bounds__(256)
void mgemm(const __hip_bfloat16* __restrict__ A, int lda,
           const __hip_bfloat16* __restrict__ W, int ldw,
           const float* __restrict__ bias,
           const float* __restrict__ res, int ldres,
           void* __restrict__ Cptr, int ldc,
           int M, int K)
{
    __shared__ __align__(16) bf16_t lsA[128 * 32];
    __shared__ __align__(16) bf16_t lsB[128 * 32];

    const int bm = blockIdx.y * 128;
    const int bn = blockIdx.x * 128;
    const int kLen = K / SPLITK;
    const int kBeg = blockIdx.z * kLen;

    const int t = threadIdx.x;
    const int l = t & 63, wid = t >> 6;
    const int wr = wid >> 1, wc = wid & 1;
    const int lrow = l & 15, lk = l >> 4;
    const int xorf = (lrow >> 1) & 3;
    const int rdoff = (lk ^ xorf) * 8;

    const int r0 = t >> 2,          c0 = t & 3;
    const int r1 = (256 + t) >> 2,  c1 = t & 3;
    const int sc0 = c0 ^ ((r0 >> 1) & 3);
    const int sc1 = c1 ^ ((r1 >> 1) & 3);

    const bf16_t* gA0 = (const bf16_t*)A + (size_t)(bm + r0) * lda + kBeg + sc0 * 8;
    const bf16_t* gA1 = (const bf16_t*)A + (size_t)(bm + r1) * lda + kBeg + sc1 * 8;
    const bf16_t* gB0 = (const bf16_t*)W + (size_t)(bn + r0) * ldw + kBeg + sc0 * 8;
    const bf16_t* gB1 = (const bf16_t*)W + (size_t)(bn + r1) * ldw + kBeg + sc1 * 8;
    bf16_t* dA0 = &lsA[(size_t)t * 8];
    bf16_t* dA1 = &lsA[(size_t)(256 + t) * 8];
    bf16_t* dB0 = &lsB[(size_t)t * 8];
    bf16_t* dB1 = &lsB[(size_t)(256 + t) * 8];

    f32x4 acc[4][4] = {};

    for (int k0 = 0; k0 < kLen; k0 += 32) {
        __builtin_amdgcn_global_load_lds(
            (const __attribute__((address_space(1))) void*)gA0,
            (__attribute__((address_space(3))) void*)dA0, 16, 0, 0);
        __builtin_amdgcn_global_load_lds(
            (const __attribute__((address_space(1))) void*)gA1,
            (__attribute__((address_space(3))) void*)dA1, 16, 0, 0);
        __builtin_amdgcn_global_load_lds(
            (const __attribute__((address_space(1))) void*)gB0,
            (__attribute__((address_space(3))) void*)dB0, 16, 0, 0);
        __builtin_amdgcn_global_load_lds(
            (const __attribute__((address_space(1))) void*)gB1,
            (__attribute__((address_space(3))) void*)dB1, 16, 0, 0);
        gA0 += 32; gA1 += 32; gB0 += 32; gB1 += 32;
        __syncthreads();

        bf16x8 af[4], bfv[4];
#pragma unroll
        for (int m = 0; m < 4; ++m) {
            const int ra = wr * 64 + m * 16 + lrow;
            af[m] = *(const bf16x8*)&lsA[ra * 32 + rdoff];
        }
#pragma unroll
        for (int n = 0; n < 4; ++n) {
            const int rb = wc * 64 + n * 16 + lrow;
            bfv[n] = *(const bf16x8*)&lsB[rb * 32 + rdoff];
        }
#pragma unroll
        for (int m = 0; m < 4; ++m)
#pragma unroll
            for (int n = 0; n < 4; ++n)
                acc[m][n] = __builtin_amdgcn_mfma_f32_16x16x32_bf16(
                    af[m], bfv[n], acc[m][n], 0, 0, 0);
        __syncthreads();
    }

    float* Cf = (float*)Cptr;
    __hip_bfloat16* Cb = (__hip_bfloat16*)Cptr;
    if (OUT == 2) Cf += (size_t)blockIdx.z * M * ldc;

#pragma unroll
    for (int m = 0; m < 4; ++m) {
#pragma unroll
        for (int n = 0; n < 4; ++n) {
#pragma unroll
            for (int j = 0; j < 4; ++j) {
                const int row = bm + wr * 64 + m * 16 + lk * 4 + j;
                const int col = bn + wc * 64 + n * 16 + lrow;
                float v = acc[m][n][j];
                if (MODE == 1) {
                    v += bias[col];
                    v = (v > 20.f) ? v
                        : 0.69314718f * __builtin_amdgcn_logf(1.f + fexp2(1.44269504f * v));
                } else if (MODE == 2) {
                    v += res[(size_t)row * ldres + col];
                } else if (MODE == 3) {
                    v += bias[col];
                    v = 0.5f * v * (1.f + erff(v * 0.70710678118654752f));
                } else if (MODE == 4) {
                    v += res[(size_t)row * ldres + col] + bias[col];
                }
                if (OUT == 1) Cb[(size_t)row * ldc + col] = __float2bfloat16(v);
                else          Cf[(size_t)row * ldc + col] = v;
            }
        }
    }
}

// ---------------------------------------------------------------------------
// Split-K reduce kernels for the N=512 GEMMs (float4-vectorized).
// ---------------------------------------------------------------------------
__global__ __launch_bounds__(256)
void k_redout(const float* __restrict__ part, const float* __restrict__ x,
              float* __restrict__ xmid)
{
    const int i = (blockIdx.x * 256 + threadIdx.x) * 4;   // over 4096*512
    const float4 p0 = *(const float4*)(part + i);
    const float4 p1 = *(const float4*)(part + 2097152 + i);
    const float4 xv = *(const float4*)(x + i);
    float4 o;
    o.x = xv.x + p0.x + p1.x; o.y = xv.y + p0.y + p1.y;
    o.z = xv.z + p0.z + p1.z; o.w = xv.w + p0.w + p1.w;
    *(float4*)(xmid + i) = o;
}

__global__ __launch_bounds__(256)
void k_redfc2(const float* __restrict__ part, const float* __restrict__ res,
              const float* __restrict__ bias, float* __restrict__ out)
{
    const int i = (blockIdx.x * 256 + threadIdx.x) * 4;   // over 4096*512
    const int col = i & (DM - 1);
    const float4 p0 = *(const float4*)(part + i);
    const float4 p1 = *(const float4*)(part + 2097152 + i);
    const float4 rv = *(const float4*)(res + i);
    const float4 bv = *(const float4*)(bias + col);
    float4 o;
    o.x = rv.x + bv.x + p0.x + p1.x; o.y = rv.y + bv.y + p0.y + p1.y;
    o.z = rv.z + bv.z + p0.z + p1.z; o.w = rv.w + bv.w + p0.w + p1.w;
    *(float4*)(out + i) = o;
}

// ---------------------------------------------------------------------------
// Weight prep kernels.
// ---------------------------------------------------------------------------
__global__ void k_cvt(const float* __restrict__ s, __hip_bfloat16* __restrict__ d, int n)
{
    const int i = blockIdx.x * 256 + threadIdx.x;
    if (i < n) d[i] = __float2bfloat16(s[i]);
}

__global__ void k_build_xp(const float* __restrict__ Wf, const float* __restrict__ Wb,
                           __hip_bfloat16* __restrict__ o)
{
    const int idx = blockIdx.x * 256 + threadIdx.x;   // 128*2048
    const int r = idx >> 11, c = idx & 2047;
    float v = 0.f;
    if (r < 64) { if (c < 1024) v = Wf[r * 1024 + c]; }
    else        { if (c >= 1024) v = Wb[(r - 64) * 1024 + (c - 1024)]; }
    o[idx] = __float2bfloat16(v);
}

__global__ void k_build_dt(const float* __restrict__ Wf, const float* __restrict__ Wb,
                           const float* __restrict__ bf_, const float* __restrict__ bb_,
                           __hip_bfloat16* __restrict__ o, float* __restrict__ biasO)
{
    const int idx = blockIdx.x * 256 + threadIdx.x;   // 2048*128
    const int r = idx >> 7, c = idx & 127;
    float v = 0.f;
    if (r < 1024) { if (c < 32) v = Wf[r * 32 + c]; }
    else          { if (c >= 64 && c < 96) v = Wb[(r - 1024) * 32 + (c - 64)]; }
    o[idx] = __float2bfloat16(v);
    if (idx < 2048) biasO[idx] = (idx < 1024) ? bf_[idx] : bb_[idx - 1024];
}

__global__ void k_build_wo(const float* __restrict__ Wo, __hip_bfloat16* __restrict__ o)
{
    const int idx = blockIdx.x * 256 + threadIdx.x;   // 512*2048
    const int r = idx >> 11, c = idx & 2047;
    o[idx] = __float2bfloat16(0.5f * Wo[r * 1024 + (c & 1023)]);
}

// ---------------------------------------------------------------------------
// Depthwise conv (k=4) + SiLU, both directions, original time order.
// ---------------------------------------------------------------------------
__global__ __launch_bounds__(256)
void conv2_kernel(const __hip_bfloat16* __restrict__ xz,
                  const float* __restrict__ wf, const float* __restrict__ bf_,
                  const float* __restrict__ wb, const float* __restrict__ bb_,
                  __hip_bfloat16* __restrict__ out)
{
    const int idx = blockIdx.x * 256 + threadIdx.x;   // B*L*2048
    const int e = idx & 2047;
    const int dir = e >> 10;
    const int d = e & 1023;
    const int t = (idx >> 11) & (L_ - 1);
    const int b = idx >> 22;
    const __hip_bfloat16* base = xz + (size_t)b * L_ * E2 + d;
    const float* w = dir ? wb : wf;
    float acc = dir ? bb_[d] : bf_[d];
#pragma unroll
    for (int k = 0; k < 4; ++k) {
        const int tt = dir ? (t + 3 - k) : (t - 3 + k);
        if (tt >= 0 && tt < L_)
            acc += w[d * 4 + k] * __bfloat162float(base[(size_t)tt * E2]);
    }
    out[idx] = __float2bfloat16(acc * sigm(acc));
}

// ---------------------------------------------------------------------------
// Split-K reduce for x_proj + scatter B/C into scan-order [g][s][16] f32.
// ---------------------------------------------------------------------------
__global__ void k_red2(const float* __restrict__ part,
                       __hip_bfloat16* __restrict__ xb,
                       float* __restrict__ sB4, float* __restrict__ sC4)
{
    const int idx = blockIdx.x * 256 + threadIdx.x;   // 4096*128
    const float s4 = part[idx] + part[idx + 524288]
                   + part[idx + 2 * 524288] + part[idx + 3 * 524288];
    xb[idx] = __float2bfloat16(s4);
    const int col = idx & 127, row = idx >> 7;
    const int c64 = col & 63, dirq = col >> 6;
    if (c64 >= 32) {
        const int bq = row >> 11, tt = row & 2047;
        const int s = dirq ? (L_ - 1 - tt) : tt;
        const int n = c64 & 15;
        const int g = dirq * 2 + bq;
        float* dst = (c64 < 48 ? sB4 : sC4) + ((size_t)g * L_ + s) * 16 + n;
        *dst = s4;
    }
}

// ---------------------------------------------------------------------------
// Transpose dt/u into packed scan-order layout: sdtdu[chain][s] u32.
// ---------------------------------------------------------------------------
__global__ __launch_bounds__(256)
void k_scanprep(const __hip_bfloat16* __restrict__ dtb,
                const __hip_bfloat16* __restrict__ ucv,
                u32* __restrict__ sdtdu)
{
    __shared__ u32 lds[32][65];
    const int bid = blockIdx.x;
    const int st  = bid & 63;
    const int dtl = (bid >> 6) & 15;
    const int b   = (bid >> 10) & 1;
    const int dir = bid >> 11;
    const int tid = threadIdx.x;
    {
        const int r = tid >> 3, c8 = (tid & 7) * 8;
        const int s = st * 32 + r;
        const int tt = dir ? (L_ - 1 - s) : s;
        const size_t row = (size_t)b * L_ + tt;
        const int e = dir * 1024 + dtl * 64 + c8;
        const uint4 dv = *(const uint4*)((const u16*)dtb + row * E2 + e);
        const uint4 uv = *(const uint4*)((const u16*)ucv + row * E2 + e);
        const u32 dw[4] = { dv.x, dv.y, dv.z, dv.w };
        const u32 uw[4] = { uv.x, uv.y, uv.z, uv.w };
#pragma unroll
        for (int j = 0; j < 4; ++j) {
            lds[r][c8 + 2 * j]     = ((uw[j] & 0xffffu) << 16) | (dw[j] & 0xffffu);
            lds[r][c8 + 2 * j + 1] = (uw[j] & 0xffff0000u) | (dw[j] >> 16);
        }
    }
    __syncthreads();
    {
        const int cd = tid >> 2, s8 = (tid & 3) * 8;
        const int chain = dir * 2048 + b * 1024 + dtl * 64 + cd;
        u32* dst = sdtdu + (size_t)chain * L_ + st * 32 + s8;
#pragma unroll
        for (int j = 0; j < 8; ++j) dst[j] = lds[s8 + j][cd];
    }
}

// ---------------------------------------------------------------------------
// Chunked selective scan: 4 states per lane, 4 lanes per chain.
// ---------------------------------------------------------------------------
__global__ __launch_bounds__(256)
void scan_p1(const u32* __restrict__ sdtdu, const float* __restrict__ sB4,
             const float* __restrict__ AlF, const float* __restrict__ AlB,
             float* __restrict__ P, float* __restrict__ Hend)
{
    const int tid = threadIdx.x;
    const int j = tid & 3;
    const int task = blockIdx.x * 64 + (tid >> 2);
    const int chain = task & (NCH - 1);
    const int c = task >> 12;
    const int dir = chain >> 11;
    const int b = (chain >> 10) & 1;
    const int d = chain & 1023;
    const int g = dir * 2 + b;

    const float* Al = dir ? AlB : AlF;
    const float4 al = *(const float4*)(Al + d * NS + j * 4);
    const float An2[4] = { -fexp(al.x) * 1.44269504f, -fexp(al.y) * 1.44269504f,
                           -fexp(al.z) * 1.44269504f, -fexp(al.w) * 1.44269504f };

    const u32* pdt = sdtdu + (size_t)chain * L_ + c * TT;
    const float* pB = sB4 + ((size_t)g * L_ + c * TT) * 16 + j * 4;

    float h[4] = { 0.f, 0.f, 0.f, 0.f };
    float sdt = 0.f;
    for (int i = 0; i < TT; i += 4) {
        const uint4 pk = *(const uint4*)(pdt + i);
        const u32 wv[4] = { pk.x, pk.y, pk.z, pk.w };
#pragma unroll
        for (int k = 0; k < 4; ++k) {
            const float dt = __uint_as_float(wv[k] << 16);
            const float uu = __uint_as_float(wv[k] & 0xffff0000u);
            const float w = dt * uu;
            const float4 B4 = *(const float4*)(pB + (i + k) * 16);
            h[0] = fexp2(dt * An2[0]) * h[0] + w * B4.x;
            h[1] = fexp2(dt * An2[1]) * h[1] + w * B4.y;
            h[2] = fexp2(dt * An2[2]) * h[2] + w * B4.z;
            h[3] = fexp2(dt * An2[3]) * h[3] + w * B4.w;
            sdt += dt;
        }
    }
    float4 Pv = { fexp2(An2[0] * sdt), fexp2(An2[1] * sdt),
                  fexp2(An2[2] * sdt), fexp2(An2[3] * sdt) };
    *(float4*)(P + (size_t)task * NS + j * 4) = Pv;
    float4 Hv = { h[0], h[1], h[2], h[3] };
    *(float4*)(Hend + (size_t)task * NS + j * 4) = Hv;
}

__global__ __launch_bounds__(256)
void scan_p2(const float* __restrict__ P, float* __restrict__ Hend)
{
    const int tid = threadIdx.x;
    const int n = tid & 15;
    const int chain = blockIdx.x * 16 + (tid >> 4);
    float hin = 0.f;
    for (int c = 0; c < CH; ++c) {
        const size_t idx = ((size_t)c * NCH + chain) * NS + n;
        const float nh = P[idx] * hin + Hend[idx];
        Hend[idx] = hin;
        hin = nh;
    }
}

__global__ __launch_bounds__(256)
void scan_p3(const u32* __restrict__ sdtdu, const float* __restrict__ sB4,
             const float* __restrict__ sC4,
             const float* __restrict__ AlF, const float* __restrict__ AlB,
             const float* __restrict__ DpF, const float* __restrict__ DpB,
             const float* __restrict__ Hin,
             u16* __restrict__ ytr)                   // [NCH][L] bf16 raw
{
    const int tid = threadIdx.x;
    const int j = tid & 3;
    const int task = blockIdx.x * 64 + (tid >> 2);
    const int chain = task & (NCH - 1);
    const int c = task >> 12;
    const int dir = chain >> 11;
    const int b = (chain >> 10) & 1;
    const int d = chain & 1023;
    const int g = dir * 2 + b;

    const float* Al = dir ? AlB : AlF;
    const float4 al = *(const float4*)(Al + d * NS + j * 4);
    const float An2[4] = { -fexp(al.x) * 1.44269504f, -fexp(al.y) * 1.44269504f,
                           -fexp(al.z) * 1.44269504f, -fexp(al.w) * 1.44269504f };
    const float Dd = (dir ? DpB : DpF)[d];

    const u32* pdt = sdtdu + (size_t)chain * L_ + c * TT;
    const float* pB = sB4 + ((size_t)g * L_ + c * TT) * 16 + j * 4;
    const float* pC = sC4 + ((size_t)g * L_ + c * TT) * 16 + j * 4;
    u16* yo = ytr + (size_t)chain * L_ + c * TT;

    const float4 hv = *(const float4*)(Hin + (size_t)task * NS + j * 4);
    float h[4] = { hv.x, hv.y, hv.z, hv.w };

    for (int i = 0; i < TT; i += 4) {
        const uint4 pk = *(const uint4*)(pdt + i);
        const u32 wv[4] = { pk.x, pk.y, pk.z, pk.w };
        float qv[4], us[4];
#pragma unroll
        for (int k = 0; k < 4; ++k) {
            const float dt = __uint_as_float(wv[k] << 16);
            const float uu = __uint_as_float(wv[k] & 0xffff0000u);
            us[k] = uu;
            const float w = dt * uu;
            const float4 B4 = *(const float4*)(pB + (i + k) * 16);
            const float4 C4 = *(const float4*)(pC + (i + k) * 16);
            h[0] = fexp2(dt * An2[0]) * h[0] + w * B4.x;
            h[1] = fexp2(dt * An2[1]) * h[1] + w * B4.y;
            h[2] = fexp2(dt * An2[2]) * h[2] + w * B4.z;
            h[3] = fexp2(dt * An2[3]) * h[3] + w * B4.w;
            qv[k] = h[0] * C4.x + h[1] * C4.y + h[2] * C4.z + h[3] * C4.w;
        }
#pragma unroll
        for (int k = 0; k < 4; ++k) qv[k] = swzadd<0x041F>(qv[k]);
#pragma unroll
        for (int k = 0; k < 4; ++k) qv[k] = swzadd<0x081F>(qv[k]);
        if (j == 0) {
            uint2 pkd;
            pkd.x = (u32)f2bu(qv[0] + us[0] * Dd) | ((u32)f2bu(qv[1] + us[1] * Dd) << 16);
            pkd.y = (u32)f2bu(qv[2] + us[2] * Dd) | ((u32)f2bu(qv[3] + us[3] * Dd) << 16);
            *(uint2*)(yo + i) = pkd;
        }
    }
}

// ---------------------------------------------------------------------------
// Post-pass: transpose ytr[chain][s] -> yall[B,L,2048], applying SiLU(z).
// ---------------------------------------------------------------------------
__global__ __launch_bounds__(256)
void k_scanpost(const u16* __restrict__ ytr,
                const __hip_bfloat16* __restrict__ xz,
                __hip_bfloat16* __restrict__ yall)
{
    __shared__ u16 lds[64][34];
    const int bid = blockIdx.x;
    const int st  = bid & 63;
    const int dtl = (bid >> 6) & 15;
    const int b   = (bid >> 10) & 1;
    const int dir = bid >> 11;
    const int tid = threadIdx.x;
    {
        const int cl = tid >> 2, s8 = (tid & 3) * 8;
        const int chain = dir * 2048 + b * 1024 + dtl * 64 + cl;
        const uint4 v = *(const uint4*)(ytr + (size_t)chain * L_ + st * 32 + s8);
        u32* dst = (u32*)&lds[cl][s8];
        dst[0] = v.x; dst[1] = v.y; dst[2] = v.z; dst[3] = v.w;
    }
    __syncthreads();
    {
        const int sl = tid >> 3, d8 = (tid & 7) * 8;
        const int s = st * 32 + sl;
        const int tt = dir ? (L_ - 1 - s) : s;
        const size_t row = (size_t)b * L_ + tt;
        const u16* zp = (const u16*)xz + row * E2 + 1024 + dtl * 64 + d8;
        const uint4 zv = *(const uint4*)zp;
        const u32 zw[4] = { zv.x, zv.y, zv.z, zv.w };
        u16 ov[8];
#pragma unroll
        for (int jj = 0; jj < 4; ++jj) {
            const float z0 = __uint_as_float(zw[jj] << 16);
            const float z1 = __uint_as_float(zw[jj] & 0xffff0000u);
            const float y0 = __uint_as_float((u32)lds[d8 + 2 * jj][sl] << 16);
            const float y1 = __uint_as_float((u32)lds[d8 + 2 * jj + 1][sl] << 16);
            ov[2 * jj]     = f2bu(y0 * (z0 * sigm(z0)));
            ov[2 * jj + 1] = f2bu(y1 * (z1 * sigm(z1)));
        }
        u16* op = (u16*)yall + row * E2 + dir * 1024 + dtl * 64 + d8;
        *(uint4*)op = *(uint4*)ov;
    }
}

// ---------------------------------------------------------------------------
// Launch
// ---------------------------------------------------------------------------
extern "C" void kernel_launch(void* const* d_in, const int* in_sizes, int n_in,
                              void* d_out, int out_size, void* d_ws, size_t ws_size,
                              hipStream_t stream)
{
    const float* x         = (const float*)d_in[0];
    const float* ln1_w     = (const float*)d_in[1];
    const float* ln1_b     = (const float*)d_in[2];
    const float* in_proj_w = (const float*)d_in[3];
    const float* conv_w[2]    = { (const float*)d_in[4],  (const float*)d_in[11] };
    const float* conv_b[2]    = { (const float*)d_in[5],  (const float*)d_in[12] };
    const float* x_proj_w[2]  = { (const float*)d_in[6],  (const float*)d_in[13] };
    const float* dt_proj_w[2] = { (const float*)d_in[7],  (const float*)d_in[14] };
    const float* dt_proj_b[2] = { (const float*)d_in[8],  (const float*)d_in[15] };
    const float* A_log[2]     = { (const float*)d_in[9],  (const float*)d_in[16] };
    const float* D_param[2]   = { (const float*)d_in[10], (const float*)d_in[17] };
    const float* out_proj_w = (const float*)d_in[18];
    const float* ln2_w      = (const float*)d_in[19];
    const float* ln2_b      = (const float*)d_in[20];
    const float* fc1_w      = (const float*)d_in[21];
    const float* fc1_b      = (const float*)d_in[22];
    const float* fc2_w      = (const float*)d_in[23];
    const float* fc2_b      = (const float*)d_in[24];
    float* out = (float*)d_out;

    char* ws = (char*)d_ws;
    const size_t MB = 1u << 20;
    // resident weights: 0..9.01 MB
    __hip_bfloat16* wip  = (__hip_bfloat16*)(ws + 0 * MB);
    __hip_bfloat16* wxp  = (__hip_bfloat16*)(ws + 2 * MB);
    __hip_bfloat16* wdt  = (__hip_bfloat16*)(ws + 2 * MB + 512 * 1024);
    __hip_bfloat16* wop  = (__hip_bfloat16*)(ws + 3 * MB);
    __hip_bfloat16* wfc1 = (__hip_bfloat16*)(ws + 5 * MB);
    __hip_bfloat16* wfc2 = (__hip_bfloat16*)(ws + 7 * MB);
    float* dtbias        = (float*)(ws + 9 * MB);
    // phase 1 lifetimes:
    __hip_bfloat16* xz   = (__hip_bfloat16*)(ws + 10 * MB);  // in_proj..scanpost
    __hip_bfloat16* ucv  = (__hip_bfloat16*)(ws + 26 * MB);  // conv..scanprep
    float* Ps            = (float*)(ws + 26 * MB);           // p1..p2 (over dead ucv)
    float* Hend          = (float*)(ws + 34 * MB);           // p1..p3
    __hip_bfloat16* dtb  = (__hip_bfloat16*)(ws + 42 * MB);  // dtgemm..scanprep
    u16* ytr             = (u16*)(ws + 42 * MB);             // p3..scanpost (over dead dtb)
    __hip_bfloat16* xn1  = (__hip_bfloat16*)(ws + 58 * MB);  // ln1..in_proj
    float* xdbp          = (float*)(ws + 62 * MB);           // xproj..k_red2
    __hip_bfloat16* xdbb = (__hip_bfloat16*)(ws + 70 * MB);  // k_red2..dtgemm
    u32* sdtdu           = (u32*)(ws + 58 * MB);             // scanprep..p3 (32 MB)
    float* part          = (float*)(ws + 58 * MB);           // splitK partials (16 MB),
                                                             // over dead sdtdu/ytr region
    __hip_bfloat16* yall = (__hip_bfloat16*)(ws + 90 * MB);  // scanpost..out_proj
    float* sB4           = (float*)(ws + 106 * MB);          // k_red2..p3
    float* sC4           = (float*)(ws + 106 * MB + 512 * 1024);  // peak 107 MB
    // phase 2 (mamba buffers dead):
    float* xmid          = (float*)(ws + 10 * MB);           // out_proj..fc2
    __hip_bfloat16* xn2  = (__hip_bfloat16*)(ws + 18 * MB);
    __hip_bfloat16* h1   = (__hip_bfloat16*)(ws + 26 * MB);

    // --- weight prep ---
    k_cvt<<<4096, 256, 0, stream>>>(in_proj_w, wip, 2048 * 512);
    k_cvt<<<4096, 256, 0, stream>>>(fc1_w, wfc1, 2048 * 512);
    k_cvt<<<4096, 256, 0, stream>>>(fc2_w, wfc2, 512 * 2048);
    k_build_xp<<<1024, 256, 0, stream>>>(x_proj_w[0], x_proj_w[1], wxp);
    k_build_dt<<<1024, 256, 0, stream>>>(dt_proj_w[0], dt_proj_w[1],
                                         dt_proj_b[0], dt_proj_b[1], wdt, dtbias);
    k_build_wo<<<4096, 256, 0, stream>>>(out_proj_w, wop);

    // --- mamba branch ---
    ln_kernel<<<ROWS, 64, 0, stream>>>(x, ln1_w, ln1_b, xn1);

    mgemm<0, 1, 1><<<dim3(16, 32, 1), 256, 0, stream>>>(
        xn1, DM, wip, DM, nullptr, nullptr, 0, xz, E2, ROWS, DM);

    conv2_kernel<<<(B_ * L_ * E2) / 256, 256, 0, stream>>>(
        xz, conv_w[0], conv_b[0], conv_w[1], conv_b[1], ucv);

    mgemm<0, 2, 4><<<dim3(1, 32, 4), 256, 0, stream>>>(
        ucv, E2, wxp, E2, nullptr, nullptr, 0, xdbp, 128, ROWS, E2);
    k_red2<<<2048, 256, 0, stream>>>(xdbp, xdbb, sB4, sC4);

    mgemm<1, 1, 1><<<dim3(16, 32, 1), 256, 0, stream>>>(
        xdbb, 128, wdt, 128, dtbias, nullptr, 0, dtb, E2, ROWS, 128);

    k_scanprep<<<4096, 256, 0, stream>>>(dtb, ucv, sdtdu);

    scan_p1<<<(CH * NCH) / 64, 256, 0, stream>>>(
        sdtdu, sB4, A_log[0], A_log[1], Ps, Hend);
    scan_p2<<<NCH / 16, 256, 0, stream>>>(Ps, Hend);
    scan_p3<<<(CH * NCH) / 64, 256, 0, stream>>>(
        sdtdu, sB4, sC4, A_log[0], A_log[1], D_param[0], D_param[1],
        Hend, ytr);

    k_scanpost<<<4096, 256, 0, stream>>>(ytr, xz, yall);

    // out_proj split-K=2: partials then fused residual reduce -> xmid
    mgemm<0, 2, 2><<<dim3(4, 32, 2), 256, 0, stream>>>(
        yall, E2, wop, E2, nullptr, nullptr, 0, part, DM, ROWS, E2);
    k_redout<<<2048, 256, 0, stream>>>(part, x, xmid);

    // --- MLP branch ---
    ln_kernel<<<ROWS, 64, 0, stream>>>(xmid, ln2_w, ln2_b, xn2);

    mgemm<3, 1, 1><<<dim3(16, 32, 1), 256, 0, stream>>>(
        xn2, DM, wfc1, DM, fc1_b, nullptr, 0, h1, HID, ROWS, DM);

    // fc2 split-K=2: partials then fused bias+residual reduce -> out
    mgemm<0, 2, 2><<<dim3(4, 32, 2), 256, 0, stream>>>(
        h1, HID, wfc2, HID, nullptr, nullptr, 0, part, DM, ROWS, HID);
    k_redfc2<<<2048, 256, 0, stream>>>(part, xmid, fc2_b, out);
}

// Round 10
// 280.448 us; speedup vs baseline: 15.2107x; 1.0996x over previous
//
#include <hip/hip_runtime.h>
#include <hip/hip_bf16.h>

// ---------------------------------------------------------------------------
// MotionMambaBlock forward. Round 10: scan_p3 fused gate+transpose (no ytr),
// single weight-prep kernel, fused out_proj-reduce+LN2, x_proj split-K=8.
// ---------------------------------------------------------------------------

#define B_   2
#define L_   2048
#define DM   512
#define DI   1024
#define E2   2048
#define NS   16
#define HID  2048
#define ROWS (B_ * L_)     // 4096
#define CH   32            // scan chunks
#define TT   (L_ / CH)     // 64
#define NCH  4096          // chains = 2 dirs * B * DI

typedef __bf16 bf16_t;
typedef bf16_t bf16x8 __attribute__((ext_vector_type(8)));
typedef float f32x4 __attribute__((ext_vector_type(4)));
typedef unsigned int u32;
typedef unsigned short u16;

__device__ __forceinline__ float fexp2(float x) { return __builtin_amdgcn_exp2f(x); }
__device__ __forceinline__ float fexp(float x)  { return fexp2(x * 1.44269504f); }
__device__ __forceinline__ float frcp(float x)  { return __builtin_amdgcn_rcpf(x); }
__device__ __forceinline__ float sigm(float x)  { return frcp(1.f + fexp2(-1.44269504f * x)); }

template<int PAT>
__device__ __forceinline__ float swzadd(float q)
{
    return q + __int_as_float(__builtin_amdgcn_ds_swizzle(__float_as_int(q), PAT));
}

__device__ __forceinline__ u16 f2bu(float f)
{
    __hip_bfloat16 h = __float2bfloat16(f);
    return *(u16*)&h;
}

// ---------------------------------------------------------------------------
// LayerNorm over D=512, one wave per row, bf16 output (used for LN1).
// ---------------------------------------------------------------------------
__global__ __launch_bounds__(64)
void ln_kernel(const float* __restrict__ in, const float* __restrict__ w,
               const float* __restrict__ b, __hip_bfloat16* __restrict__ out)
{
    const int row  = blockIdx.x;
    const int lane = threadIdx.x;
    const float* p = in + (size_t)row * DM;
    float v[8];
    float s = 0.f;
#pragma unroll
    for (int i = 0; i < 8; ++i) { v[i] = p[lane + 64 * i]; s += v[i]; }
#pragma unroll
    for (int off = 32; off > 0; off >>= 1) s += __shfl_xor(s, off);
    const float mean = s * (1.f / DM);
    float vs = 0.f;
#pragma unroll
    for (int i = 0; i < 8; ++i) { float d = v[i] - mean; vs += d * d; }
#pragma unroll
    for (int off = 32; off > 0; off >>= 1) vs += __shfl_xor(vs, off);
    const float rstd = rsqrtf(vs * (1.f / DM) + 1e-5f);
    __hip_bfloat16* o = out + (size_t)row * DM;
#pragma unroll
    for (int i = 0; i < 8; ++i) {
        const int c = lane + 64 * i;
        o[c] = __float2bfloat16((v[i] - mean) * rstd * w[c] + b[c]);
    }
}

// ---------------------------------------------------------------------------
// bf16 MFMA GEMM: C[M][N] = epi( A[M][K] * W[N][K]^T ). 128x128 tile, BK=32.
// MODE: 0=none, 1=softplus(v+bias), 3=gelu(v+bias)
// OUT:  0=f32, 1=bf16, 2=f32 split-K partial
// ---------------------------------------------------------------------------
template<int MODE, int OUT, int SPLITK>
__global__ __launch_bounds__(256)
void mgemm(const __hip_bfloat16* __restrict__ A, int lda,
           const __hip_bfloat16* __restrict__ W, int ldw,
           const float* __restrict__ bias,
           const float* __restrict__ res, int ldres,
           void* __restrict__ Cptr, int ldc,
           int M, int K)
{
    __shared__ __align__(16) bf16_t lsA[128 * 32];
    __shared__ __align__(16) bf16_t lsB[128 * 32];

    const int bm = blockIdx.y * 128;
    const int bn = blockIdx.x * 128;
    const int kLen = K / SPLITK;
    const int kBeg = blockIdx.z * kLen;

    const int t = threadIdx.x;
    const int l = t & 63, wid = t >> 6;
    const int wr = wid >> 1, wc = wid & 1;
    const int lrow = l & 15, lk = l >> 4;
    const int xorf = (lrow >> 1) & 3;
    const int rdoff = (lk ^ xorf) * 8;

    const int r0 = t >> 2,          c0 = t & 3;
    const int r1 = (256 + t) >> 2,  c1 = t & 3;
    const int sc0 = c0 ^ ((r0 >> 1) & 3);
    const int sc1 = c1 ^ ((r1 >> 1) & 3);

    const bf16_t* gA0 = (const bf16_t*)A + (size_t)(bm + r0) * lda + kBeg + sc0 * 8;
    const bf16_t* gA1 = (const bf16_t*)A + (size_t)(bm + r1) * lda + kBeg + sc1 * 8;
    const bf16_t* gB0 = (const bf16_t*)W + (size_t)(bn + r0) * ldw + kBeg + sc0 * 8;
    const bf16_t* gB1 = (const bf16_t*)W + (size_t)(bn + r1) * ldw + kBeg + sc1 * 8;
    bf16_t* dA0 = &lsA[(size_t)t * 8];
    bf16_t* dA1 = &lsA[(size_t)(256 + t) * 8];
    bf16_t* dB0 = &lsB[(size_t)t * 8];
    bf16_t* dB1 = &lsB[(size_t)(256 + t) * 8];

    f32x4 acc[4][4] = {};

    for (int k0 = 0; k0 < kLen; k0 += 32) {
        __builtin_amdgcn_global_load_lds(
            (const __attribute__((address_space(1))) void*)gA0,
            (__attribute__((address_space(3))) void*)dA0, 16, 0, 0);
        __builtin_amdgcn_global_load_lds(
            (const __attribute__((address_space(1))) void*)gA1,
            (__attribute__((address_space(3))) void*)dA1, 16, 0, 0);
        __builtin_amdgcn_global_load_lds(
            (const __attribute__((address_space(1))) void*)gB0,
            (__attribute__((address_space(3))) void*)dB0, 16, 0, 0);
        __builtin_amdgcn_global_load_lds(
            (const __attribute__((address_space(1))) void*)gB1,
            (__attribute__((address_space(3))) void*)dB1, 16, 0, 0);
        gA0 += 32; gA1 += 32; gB0 += 32; gB1 += 32;
        __syncthreads();

        bf16x8 af[4], bfv[4];
#pragma unroll
        for (int m = 0; m < 4; ++m) {
            const int ra = wr * 64 + m * 16 + lrow;
            af[m] = *(const bf16x8*)&lsA[ra * 32 + rdoff];
        }
#pragma unroll
        for (int n = 0; n < 4; ++n) {
            const int rb = wc * 64 + n * 16 + lrow;
            bfv[n] = *(const bf16x8*)&lsB[rb * 32 + rdoff];
        }
#pragma unroll
        for (int m = 0; m < 4; ++m)
#pragma unroll
            for (int n = 0; n < 4; ++n)
                acc[m][n] = __builtin_amdgcn_mfma_f32_16x16x32_bf16(
                    af[m], bfv[n], acc[m][n], 0, 0, 0);
        __syncthreads();
    }

    float* Cf = (float*)Cptr;
    __hip_bfloat16* Cb = (__hip_bfloat16*)Cptr;
    if (OUT == 2) Cf += (size_t)blockIdx.z * M * ldc;

#pragma unroll
    for (int m = 0; m < 4; ++m) {
#pragma unroll
        for (int n = 0; n < 4; ++n) {
#pragma unroll
            for (int j = 0; j < 4; ++j) {
                const int row = bm + wr * 64 + m * 16 + lk * 4 + j;
                const int col = bn + wc * 64 + n * 16 + lrow;
                float v = acc[m][n][j];
                if (MODE == 1) {
                    v += bias[col];
                    v = (v > 20.f) ? v
                        : 0.69314718f * __builtin_amdgcn_logf(1.f + fexp2(1.44269504f * v));
                } else if (MODE == 3) {
                    v += bias[col];
                    v = 0.5f * v * (1.f + erff(v * 0.70710678118654752f));
                }
                if (OUT == 1) Cb[(size_t)row * ldc + col] = __float2bfloat16(v);
                else          Cf[(size_t)row * ldc + col] = v;
            }
        }
    }
}

// ---------------------------------------------------------------------------
// Combined weight prep: one kernel, range-dispatched on blockIdx.
// blocks [0,4096) wip | [4096,8192) wfc1 | [8192,12288) wfc2 |
// [12288,13312) wxp | [13312,14336) wdt+dtbias | [14336,18432) wop
// ---------------------------------------------------------------------------
__global__ __launch_bounds__(256)
void k_prep(const float* __restrict__ ipw, const float* __restrict__ f1w,
            const float* __restrict__ f2w,
            const float* __restrict__ xpf, const float* __restrict__ xpb,
            const float* __restrict__ dwf, const float* __restrict__ dwb,
            const float* __restrict__ dbf, const float* __restrict__ dbb,
            const float* __restrict__ wo,
            __hip_bfloat16* __restrict__ wip, __hip_bfloat16* __restrict__ wfc1,
            __hip_bfloat16* __restrict__ wfc2, __hip_bfloat16* __restrict__ wxp,
            __hip_bfloat16* __restrict__ wdt, __hip_bfloat16* __restrict__ wop,
            float* __restrict__ dtbias)
{
    const int bid = blockIdx.x;
    const int tid = threadIdx.x;
    if (bid < 4096) {
        const int i = bid * 256 + tid;
        wip[i] = __float2bfloat16(ipw[i]);
    } else if (bid < 8192) {
        const int i = (bid - 4096) * 256 + tid;
        wfc1[i] = __float2bfloat16(f1w[i]);
    } else if (bid < 12288) {
        const int i = (bid - 8192) * 256 + tid;
        wfc2[i] = __float2bfloat16(f2w[i]);
    } else if (bid < 13312) {
        const int idx = (bid - 12288) * 256 + tid;   // 128*2048
        const int r = idx >> 11, c = idx & 2047;
        float v = 0.f;
        if (r < 64) { if (c < 1024) v = xpf[r * 1024 + c]; }
        else        { if (c >= 1024) v = xpb[(r - 64) * 1024 + (c - 1024)]; }
        wxp[idx] = __float2bfloat16(v);
    } else if (bid < 14336) {
        const int idx = (bid - 13312) * 256 + tid;   // 2048*128
        const int r = idx >> 7, c = idx & 127;
        float v = 0.f;
        if (r < 1024) { if (c < 32) v = dwf[r * 32 + c]; }
        else          { if (c >= 64 && c < 96) v = dwb[(r - 1024) * 32 + (c - 64)]; }
        wdt[idx] = __float2bfloat16(v);
        if (idx < 2048) dtbias[idx] = (idx < 1024) ? dbf[idx] : dbb[idx - 1024];
    } else {
        const int idx = (bid - 14336) * 256 + tid;   // 512*2048
        const int r = idx >> 11, c = idx & 2047;
        wop[idx] = __float2bfloat16(0.5f * wo[r * 1024 + (c & 1023)]);
    }
}

// ---------------------------------------------------------------------------
// Depthwise conv (k=4) + SiLU, both directions, original time order.
// ---------------------------------------------------------------------------
__global__ __launch_bounds__(256)
void conv2_kernel(const __hip_bfloat16* __restrict__ xz,
                  const float* __restrict__ wf, const float* __restrict__ bf_,
                  const float* __restrict__ wb, const float* __restrict__ bb_,
                  __hip_bfloat16* __restrict__ out)
{
    const int idx = blockIdx.x * 256 + threadIdx.x;   // B*L*2048
    const int e = idx & 2047;
    const int dir = e >> 10;
    const int d = e & 1023;
    const int t = (idx >> 11) & (L_ - 1);
    const int b = idx >> 22;
    const __hip_bfloat16* base = xz + (size_t)b * L_ * E2 + d;
    const float* w = dir ? wb : wf;
    float acc = dir ? bb_[d] : bf_[d];
#pragma unroll
    for (int k = 0; k < 4; ++k) {
        const int tt = dir ? (t + 3 - k) : (t - 3 + k);
        if (tt >= 0 && tt < L_)
            acc += w[d * 4 + k] * __bfloat162float(base[(size_t)tt * E2]);
    }
    out[idx] = __float2bfloat16(acc * sigm(acc));
}

// ---------------------------------------------------------------------------
// Split-K(8) reduce for x_proj + scatter B/C into scan-order [g][s][16] f32.
// ---------------------------------------------------------------------------
__global__ void k_red2(const float* __restrict__ part,
                       __hip_bfloat16* __restrict__ xb,
                       float* __restrict__ sB4, float* __restrict__ sC4)
{
    const int idx = blockIdx.x * 256 + threadIdx.x;   // 4096*128
    float s4 = 0.f;
#pragma unroll
    for (int z = 0; z < 8; ++z) s4 += part[idx + z * 524288];
    xb[idx] = __float2bfloat16(s4);
    const int col = idx & 127, row = idx >> 7;
    const int c64 = col & 63, dirq = col >> 6;
    if (c64 >= 32) {
        const int bq = row >> 11, tt = row & 2047;
        const int s = dirq ? (L_ - 1 - tt) : tt;
        const int n = c64 & 15;
        const int g = dirq * 2 + bq;
        float* dst = (c64 < 48 ? sB4 : sC4) + ((size_t)g * L_ + s) * 16 + n;
        *dst = s4;
    }
}

// ---------------------------------------------------------------------------
// Transpose dt/u into packed scan-order layout: sdtdu[chain][s] u32.
// ---------------------------------------------------------------------------
__global__ __launch_bounds__(256)
void k_scanprep(const __hip_bfloat16* __restrict__ dtb,
                const __hip_bfloat16* __restrict__ ucv,
                u32* __restrict__ sdtdu)
{
    __shared__ u32 lds[32][65];
    const int bid = blockIdx.x;
    const int st  = bid & 63;
    const int dtl = (bid >> 6) & 15;
    const int b   = (bid >> 10) & 1;
    const int dir = bid >> 11;
    const int tid = threadIdx.x;
    {
        const int r = tid >> 3, c8 = (tid & 7) * 8;
        const int s = st * 32 + r;
        const int tt = dir ? (L_ - 1 - s) : s;
        const size_t row = (size_t)b * L_ + tt;
        const int e = dir * 1024 + dtl * 64 + c8;
        const uint4 dv = *(const uint4*)((const u16*)dtb + row * E2 + e);
        const uint4 uv = *(const uint4*)((const u16*)ucv + row * E2 + e);
        const u32 dw[4] = { dv.x, dv.y, dv.z, dv.w };
        const u32 uw[4] = { uv.x, uv.y, uv.z, uv.w };
#pragma unroll
        for (int j = 0; j < 4; ++j) {
            lds[r][c8 + 2 * j]     = ((uw[j] & 0xffffu) << 16) | (dw[j] & 0xffffu);
            lds[r][c8 + 2 * j + 1] = (uw[j] & 0xffff0000u) | (dw[j] >> 16);
        }
    }
    __syncthreads();
    {
        const int cd = tid >> 2, s8 = (tid & 3) * 8;
        const int chain = dir * 2048 + b * 1024 + dtl * 64 + cd;
        u32* dst = sdtdu + (size_t)chain * L_ + st * 32 + s8;
#pragma unroll
        for (int j = 0; j < 8; ++j) dst[j] = lds[s8 + j][cd];
    }
}

// ---------------------------------------------------------------------------
// Chunked selective scan: 4 states per lane, 4 lanes per chain.
// ---------------------------------------------------------------------------
__global__ __launch_bounds__(256)
void scan_p1(const u32* __restrict__ sdtdu, const float* __restrict__ sB4,
             const float* __restrict__ AlF, const float* __restrict__ AlB,
             float* __restrict__ P, float* __restrict__ Hend)
{
    const int tid = threadIdx.x;
    const int j = tid & 3;
    const int task = blockIdx.x * 64 + (tid >> 2);
    const int chain = task & (NCH - 1);
    const int c = task >> 12;
    const int dir = chain >> 11;
    const int b = (chain >> 10) & 1;
    const int d = chain & 1023;
    const int g = dir * 2 + b;

    const float* Al = dir ? AlB : AlF;
    const float4 al = *(const float4*)(Al + d * NS + j * 4);
    const float An2[4] = { -fexp(al.x) * 1.44269504f, -fexp(al.y) * 1.44269504f,
                           -fexp(al.z) * 1.44269504f, -fexp(al.w) * 1.44269504f };

    const u32* pdt = sdtdu + (size_t)chain * L_ + c * TT;
    const float* pB = sB4 + ((size_t)g * L_ + c * TT) * 16 + j * 4;

    float h[4] = { 0.f, 0.f, 0.f, 0.f };
    float sdt = 0.f;
    for (int i = 0; i < TT; i += 4) {
        const uint4 pk = *(const uint4*)(pdt + i);
        const u32 wv[4] = { pk.x, pk.y, pk.z, pk.w };
#pragma unroll
        for (int k = 0; k < 4; ++k) {
            const float dt = __uint_as_float(wv[k] << 16);
            const float uu = __uint_as_float(wv[k] & 0xffff0000u);
            const float w = dt * uu;
            const float4 B4 = *(const float4*)(pB + (i + k) * 16);
            h[0] = fexp2(dt * An2[0]) * h[0] + w * B4.x;
            h[1] = fexp2(dt * An2[1]) * h[1] + w * B4.y;
            h[2] = fexp2(dt * An2[2]) * h[2] + w * B4.z;
            h[3] = fexp2(dt * An2[3]) * h[3] + w * B4.w;
            sdt += dt;
        }
    }
    float4 Pv = { fexp2(An2[0] * sdt), fexp2(An2[1] * sdt),
                  fexp2(An2[2] * sdt), fexp2(An2[3] * sdt) };
    *(float4*)(P + (size_t)task * NS + j * 4) = Pv;
    float4 Hv = { h[0], h[1], h[2], h[3] };
    *(float4*)(Hend + (size_t)task * NS + j * 4) = Hv;
}

__global__ __launch_bounds__(256)
void scan_p2(const float* __restrict__ P, float* __restrict__ Hend)
{
    const int tid = threadIdx.x;
    const int n = tid & 15;
    const int chain = blockIdx.x * 16 + (tid >> 4);
    float hin = 0.f;
    for (int c = 0; c < CH; ++c) {
        const size_t idx = ((size_t)c * NCH + chain) * NS + n;
        const float nh = P[idx] * hin + Hend[idx];
        Hend[idx] = hin;
        hin = nh;
    }
}

// p3: scan + in-LDS transpose + SiLU(z) gate + direct coalesced yall write.
// Block = 64 contiguous chains (same dir/b/chunk) x 64 steps.
__global__ __launch_bounds__(256)
void scan_p3(const u32* __restrict__ sdtdu, const float* __restrict__ sB4,
             const float* __restrict__ sC4,
             const float* __restrict__ AlF, const float* __restrict__ AlB,
             const float* __restrict__ DpF, const float* __restrict__ DpB,
             const float* __restrict__ Hin,
             const __hip_bfloat16* __restrict__ xz,
             __hip_bfloat16* __restrict__ yall)
{
    __shared__ u16 ly[64][68];   // [chain_local][step], 136B rows (8B-aligned)
    const int tid = threadIdx.x;
    const int j = tid & 3;
    const int task = blockIdx.x * 64 + (tid >> 2);
    const int chain = task & (NCH - 1);
    const int c = task >> 12;
    const int dir = chain >> 11;
    const int b = (chain >> 10) & 1;
    const int d = chain & 1023;
    const int g = dir * 2 + b;

    const float* Al = dir ? AlB : AlF;
    const float4 al = *(const float4*)(Al + d * NS + j * 4);
    const float An2[4] = { -fexp(al.x) * 1.44269504f, -fexp(al.y) * 1.44269504f,
                           -fexp(al.z) * 1.44269504f, -fexp(al.w) * 1.44269504f };
    const float Dd = (dir ? DpB : DpF)[d];

    const u32* pdt = sdtdu + (size_t)chain * L_ + c * TT;
    const float* pB = sB4 + ((size_t)g * L_ + c * TT) * 16 + j * 4;
    const float* pC = sC4 + ((size_t)g * L_ + c * TT) * 16 + j * 4;

    const float4 hv = *(const float4*)(Hin + (size_t)task * NS + j * 4);
    float h[4] = { hv.x, hv.y, hv.z, hv.w };

    for (int i = 0; i < TT; i += 4) {
        const uint4 pk = *(const uint4*)(pdt + i);
        const u32 wv[4] = { pk.x, pk.y, pk.z, pk.w };
        float qv[4], us[4];
#pragma unroll
        for (int k = 0; k < 4; ++k) {
            const float dt = __uint_as_float(wv[k] << 16);
            const float uu = __uint_as_float(wv[k] & 0xffff0000u);
            us[k] = uu;
            const float w = dt * uu;
            const float4 B4 = *(const float4*)(pB + (i + k) * 16);
            const float4 C4 = *(const float4*)(pC + (i + k) * 16);
            h[0] = fexp2(dt * An2[0]) * h[0] + w * B4.x;
            h[1] = fexp2(dt * An2[1]) * h[1] + w * B4.y;
            h[2] = fexp2(dt * An2[2]) * h[2] + w * B4.z;
            h[3] = fexp2(dt * An2[3]) * h[3] + w * B4.w;
            qv[k] = h[0] * C4.x + h[1] * C4.y + h[2] * C4.z + h[3] * C4.w;
        }
#pragma unroll
        for (int k = 0; k < 4; ++k) qv[k] = swzadd<0x041F>(qv[k]);
#pragma unroll
        for (int k = 0; k < 4; ++k) qv[k] = swzadd<0x081F>(qv[k]);
        if (j == 0) {
            uint2 pkd;
            pkd.x = (u32)f2bu(qv[0] + us[0] * Dd) | ((u32)f2bu(qv[1] + us[1] * Dd) << 16);
            pkd.y = (u32)f2bu(qv[2] + us[2] * Dd) | ((u32)f2bu(qv[3] + us[3] * Dd) << 16);
            *(uint2*)&ly[tid >> 2][i] = pkd;
        }
    }
    __syncthreads();

    // gate + transpose: thread -> (step sl, 16 d-cols starting dql)
    {
        const int cb = (blockIdx.x * 64) & (NCH - 1);   // block chain base
        const int dir2 = cb >> 11, b2 = (cb >> 10) & 1, dbase = cb & 1023;
        const int c2 = (blockIdx.x * 64) >> 12;
        const int sl = tid >> 2;
        const int dql = (tid & 3) * 16;
        const int s = c2 * TT + sl;
        const int tt = dir2 ? (L_ - 1 - s) : s;
        const size_t row = (size_t)b2 * L_ + tt;
        const u16* zp = (const u16*)xz + row * E2 + 1024 + dbase + dql;
        const uint4 zv0 = *(const uint4*)zp;
        const uint4 zv1 = *(const uint4*)(zp + 8);
        const u32 zw[8] = { zv0.x, zv0.y, zv0.z, zv0.w, zv1.x, zv1.y, zv1.z, zv1.w };
        u16 ov[16];
#pragma unroll
        for (int jj = 0; jj < 8; ++jj) {
            const float z0 = __uint_as_float(zw[jj] << 16);
            const float z1 = __uint_as_float(zw[jj] & 0xffff0000u);
            const float y0 = __uint_as_float((u32)ly[dql + 2 * jj][sl] << 16);
            const float y1 = __uint_as_float((u32)ly[dql + 2 * jj + 1][sl] << 16);
            ov[2 * jj]     = f2bu(y0 * (z0 * sigm(z0)));
            ov[2 * jj + 1] = f2bu(y1 * (z1 * sigm(z1)));
        }
        u16* op = (u16*)yall + row * E2 + dir2 * 1024 + dbase + dql;
        *(uint4*)op = *(uint4*)ov;
        *(uint4*)(op + 8) = *(uint4*)(ov + 8);
    }
}

// ---------------------------------------------------------------------------
// Fused: out_proj split-K reduce + residual -> xmid, then LN2 -> xn2 (bf16).
// One wave per row, 4 rows per block.
// ---------------------------------------------------------------------------
__global__ __launch_bounds__(256)
void k_redln(const float* __restrict__ part, const float* __restrict__ x,
             const float* __restrict__ w, const float* __restrict__ bb,
             float* __restrict__ xmid, __hip_bfloat16* __restrict__ xn2)
{
    const int row = blockIdx.x * 4 + (threadIdx.x >> 6);
    const int lane = threadIdx.x & 63;
    const size_t base = (size_t)row * DM;
    const int c0 = lane * 4, c1 = 256 + lane * 4;

    const float4 p0a = *(const float4*)(part + base + c0);
    const float4 p1a = *(const float4*)(part + 2097152 + base + c0);
    const float4 xa  = *(const float4*)(x + base + c0);
    const float4 p0b = *(const float4*)(part + base + c1);
    const float4 p1b = *(const float4*)(part + 2097152 + base + c1);
    const float4 xb  = *(const float4*)(x + base + c1);
    float v[8];
    v[0] = xa.x + p0a.x + p1a.x; v[1] = xa.y + p0a.y + p1a.y;
    v[2] = xa.z + p0a.z + p1a.z; v[3] = xa.w + p0a.w + p1a.w;
    v[4] = xb.x + p0b.x + p1b.x; v[5] = xb.y + p0b.y + p1b.y;
    v[6] = xb.z + p0b.z + p1b.z; v[7] = xb.w + p0b.w + p1b.w;
    float4 oa = { v[0], v[1], v[2], v[3] }, ob = { v[4], v[5], v[6], v[7] };
    *(float4*)(xmid + base + c0) = oa;
    *(float4*)(xmid + base + c1) = ob;

    float s = 0.f;
#pragma unroll
    for (int i = 0; i < 8; ++i) s += v[i];
#pragma unroll
    for (int off = 32; off > 0; off >>= 1) s += __shfl_xor(s, off);
    const float mean = s * (1.f / DM);
    float vs = 0.f;
#pragma unroll
    for (int i = 0; i < 8; ++i) { float dd = v[i] - mean; vs += dd * dd; }
#pragma unroll
    for (int off = 32; off > 0; off >>= 1) vs += __shfl_xor(vs, off);
    const float rstd = rsqrtf(vs * (1.f / DM) + 1e-5f);

    u16 o0[4], o1[4];
#pragma unroll
    for (int i = 0; i < 4; ++i) {
        o0[i] = f2bu((v[i] - mean) * rstd * w[c0 + i] + bb[c0 + i]);
        o1[i] = f2bu((v[4 + i] - mean) * rstd * w[c1 + i] + bb[c1 + i]);
    }
    *(uint2*)((u16*)xn2 + base + c0) = *(uint2*)o0;
    *(uint2*)((u16*)xn2 + base + c1) = *(uint2*)o1;
}

__global__ __launch_bounds__(256)
void k_redfc2(const float* __restrict__ part, const float* __restrict__ res,
              const float* __restrict__ bias, float* __restrict__ out)
{
    const int i = (blockIdx.x * 256 + threadIdx.x) * 4;   // over 4096*512
    const int col = i & (DM - 1);
    const float4 p0 = *(const float4*)(part + i);
    const float4 p1 = *(const float4*)(part + 2097152 + i);
    const float4 rv = *(const float4*)(res + i);
    const float4 bv = *(const float4*)(bias + col);
    float4 o;
    o.x = rv.x + bv.x + p0.x + p1.x; o.y = rv.y + bv.y + p0.y + p1.y;
    o.z = rv.z + bv.z + p0.z + p1.z; o.w = rv.w + bv.w + p0.w + p1.w;
    *(float4*)(out + i) = o;
}

// ---------------------------------------------------------------------------
// Launch
// ---------------------------------------------------------------------------
extern "C" void kernel_launch(void* const* d_in, const int* in_sizes, int n_in,
                              void* d_out, int out_size, void* d_ws, size_t ws_size,
                              hipStream_t stream)
{
    const float* x         = (const float*)d_in[0];
    const float* ln1_w     = (const float*)d_in[1];
    const float* ln1_b     = (const float*)d_in[2];
    const float* in_proj_w = (const float*)d_in[3];
    const float* conv_w[2]    = { (const float*)d_in[4],  (const float*)d_in[11] };
    const float* conv_b[2]    = { (const float*)d_in[5],  (const float*)d_in[12] };
    const float* x_proj_w[2]  = { (const float*)d_in[6],  (const float*)d_in[13] };
    const float* dt_proj_w[2] = { (const float*)d_in[7],  (const float*)d_in[14] };
    const float* dt_proj_b[2] = { (const float*)d_in[8],  (const float*)d_in[15] };
    const float* A_log[2]     = { (const float*)d_in[9],  (const float*)d_in[16] };
    const float* D_param[2]   = { (const float*)d_in[10], (const float*)d_in[17] };
    const float* out_proj_w = (const float*)d_in[18];
    const float* ln2_w      = (const float*)d_in[19];
    const float* ln2_b      = (const float*)d_in[20];
    const float* fc1_w      = (const float*)d_in[21];
    const float* fc1_b      = (const float*)d_in[22];
    const float* fc2_w      = (const float*)d_in[23];
    const float* fc2_b      = (const float*)d_in[24];
    float* out = (float*)d_out;

    char* ws = (char*)d_ws;
    const size_t MB = 1u << 20;
    // resident weights: 0..9.01 MB
    __hip_bfloat16* wip  = (__hip_bfloat16*)(ws + 0 * MB);
    __hip_bfloat16* wxp  = (__hip_bfloat16*)(ws + 2 * MB);
    __hip_bfloat16* wdt  = (__hip_bfloat16*)(ws + 2 * MB + 512 * 1024);
    __hip_bfloat16* wop  = (__hip_bfloat16*)(ws + 3 * MB);
    __hip_bfloat16* wfc1 = (__hip_bfloat16*)(ws + 5 * MB);
    __hip_bfloat16* wfc2 = (__hip_bfloat16*)(ws + 7 * MB);
    float* dtbias        = (float*)(ws + 9 * MB);
    // phase 1 lifetimes:
    __hip_bfloat16* xz   = (__hip_bfloat16*)(ws + 10 * MB);  // in_proj..p3
    __hip_bfloat16* ucv  = (__hip_bfloat16*)(ws + 26 * MB);  // conv..scanprep
    float* Ps            = (float*)(ws + 26 * MB);           // p1..p2 (over dead ucv)
    float* Hend          = (float*)(ws + 34 * MB);           // p1..p3
    __hip_bfloat16* dtb  = (__hip_bfloat16*)(ws + 42 * MB);  // dtgemm..scanprep
    float* xdbp          = (float*)(ws + 58 * MB);           // xproj..k_red2 (8x2MB,
                                                             //  over dead xn1 region)
    __hip_bfloat16* xn1  = (__hip_bfloat16*)(ws + 74 * MB);  // ln1..in_proj
    __hip_bfloat16* xdbb = (__hip_bfloat16*)(ws + 78 * MB);  // k_red2..dtgemm
    u32* sdtdu           = (u32*)(ws + 58 * MB);             // scanprep..p3 (32 MB)
    float* part          = (float*)(ws + 58 * MB);           // splitK partials (16 MB),
                                                             // over dead sdtdu
    __hip_bfloat16* yall = (__hip_bfloat16*)(ws + 90 * MB);  // p3..out_proj
    float* sB4           = (float*)(ws + 106 * MB);          // k_red2..p3
    float* sC4           = (float*)(ws + 106 * MB + 512 * 1024);  // peak 107 MB
    // phase 2 (mamba buffers dead):
    float* xmid          = (float*)(ws + 10 * MB);           // k_redln..fc2
    __hip_bfloat16* xn2  = (__hip_bfloat16*)(ws + 18 * MB);
    __hip_bfloat16* h1   = (__hip_bfloat16*)(ws + 26 * MB);

    // --- weight prep (single kernel) ---
    k_prep<<<18432, 256, 0, stream>>>(
        in_proj_w, fc1_w, fc2_w, x_proj_w[0], x_proj_w[1],
        dt_proj_w[0], dt_proj_w[1], dt_proj_b[0], dt_proj_b[1], out_proj_w,
        wip, wfc1, wfc2, wxp, wdt, wop, dtbias);

    // --- mamba branch ---
    ln_kernel<<<ROWS, 64, 0, stream>>>(x, ln1_w, ln1_b, xn1);

    mgemm<0, 1, 1><<<dim3(16, 32, 1), 256, 0, stream>>>(
        xn1, DM, wip, DM, nullptr, nullptr, 0, xz, E2, ROWS, DM);

    conv2_kernel<<<(B_ * L_ * E2) / 256, 256, 0, stream>>>(
        xz, conv_w[0], conv_b[0], conv_w[1], conv_b[1], ucv);

    mgemm<0, 2, 8><<<dim3(1, 32, 8), 256, 0, stream>>>(
        ucv, E2, wxp, E2, nullptr, nullptr, 0, xdbp, 128, ROWS, E2);
    k_red2<<<2048, 256, 0, stream>>>(xdbp, xdbb, sB4, sC4);

    mgemm<1, 1, 1><<<dim3(16, 32, 1), 256, 0, stream>>>(
        xdbb, 128, wdt, 128, dtbias, nullptr, 0, dtb, E2, ROWS, 128);

    k_scanprep<<<4096, 256, 0, stream>>>(dtb, ucv, sdtdu);

    scan_p1<<<(CH * NCH) / 64, 256, 0, stream>>>(
        sdtdu, sB4, A_log[0], A_log[1], Ps, Hend);
    scan_p2<<<NCH / 16, 256, 0, stream>>>(Ps, Hend);
    scan_p3<<<(CH * NCH) / 64, 256, 0, stream>>>(
        sdtdu, sB4, sC4, A_log[0], A_log[1], D_param[0], D_param[1],
        Hend, xz, yall);

    // out_proj split-K=2 -> partials; fused reduce+residual+LN2
    mgemm<0, 2, 2><<<dim3(4, 32, 2), 256, 0, stream>>>(
        yall, E2, wop, E2, nullptr, nullptr, 0, part, DM, ROWS, E2);
    k_redln<<<1024, 256, 0, stream>>>(part, x, ln2_w, ln2_b, xmid, xn2);

    // --- MLP branch ---
    mgemm<3, 1, 1><<<dim3(16, 32, 1), 256, 0, stream>>>(
        xn2, DM, wfc1, DM, fc1_b, nullptr, 0, h1, HID, ROWS, DM);

    mgemm<0, 2, 2><<<dim3(4, 32, 2), 256, 0, stream>>>(
        h1, HID, wfc2, HID, nullptr, nullptr, 0, part, DM, ROWS, HID);
    k_redfc2<<<2048, 256, 0, stream>>>(part, xmid, fc2_b, out);
}

// Round 11
// 272.869 us; speedup vs baseline: 15.6332x; 1.0278x over previous
//
#include <hip/hip_runtime.h>
#include <hip/hip_bf16.h>

// ---------------------------------------------------------------------------
// MotionMambaBlock forward. Round 11: p3 LDS stride fix (odd-dword rows),
// scan_p1 fused into the transpose kernel (k_scanscan, 64x64 tile = 1 chunk).
// ---------------------------------------------------------------------------

#define B_   2
#define L_   2048
#define DM   512
#define DI   1024
#define E2   2048
#define NS   16
#define HID  2048
#define ROWS (B_ * L_)     // 4096
#define CH   32            // scan chunks
#define TT   (L_ / CH)     // 64
#define NCH  4096          // chains = 2 dirs * B * DI

typedef __bf16 bf16_t;
typedef bf16_t bf16x8 __attribute__((ext_vector_type(8)));
typedef float f32x4 __attribute__((ext_vector_type(4)));
typedef unsigned int u32;
typedef unsigned short u16;

__device__ __forceinline__ float fexp2(float x) { return __builtin_amdgcn_exp2f(x); }
__device__ __forceinline__ float fexp(float x)  { return fexp2(x * 1.44269504f); }
__device__ __forceinline__ float frcp(float x)  { return __builtin_amdgcn_rcpf(x); }
__device__ __forceinline__ float sigm(float x)  { return frcp(1.f + fexp2(-1.44269504f * x)); }

template<int PAT>
__device__ __forceinline__ float swzadd(float q)
{
    return q + __int_as_float(__builtin_amdgcn_ds_swizzle(__float_as_int(q), PAT));
}

__device__ __forceinline__ u16 f2bu(float f)
{
    __hip_bfloat16 h = __float2bfloat16(f);
    return *(u16*)&h;
}

// ---------------------------------------------------------------------------
// LayerNorm over D=512, one wave per row, bf16 output (LN1).
// ---------------------------------------------------------------------------
__global__ __launch_bounds__(64)
void ln_kernel(const float* __restrict__ in, const float* __restrict__ w,
               const float* __restrict__ b, __hip_bfloat16* __restrict__ out)
{
    const int row  = blockIdx.x;
    const int lane = threadIdx.x;
    const float* p = in + (size_t)row * DM;
    float v[8];
    float s = 0.f;
#pragma unroll
    for (int i = 0; i < 8; ++i) { v[i] = p[lane + 64 * i]; s += v[i]; }
#pragma unroll
    for (int off = 32; off > 0; off >>= 1) s += __shfl_xor(s, off);
    const float mean = s * (1.f / DM);
    float vs = 0.f;
#pragma unroll
    for (int i = 0; i < 8; ++i) { float d = v[i] - mean; vs += d * d; }
#pragma unroll
    for (int off = 32; off > 0; off >>= 1) vs += __shfl_xor(vs, off);
    const float rstd = rsqrtf(vs * (1.f / DM) + 1e-5f);
    __hip_bfloat16* o = out + (size_t)row * DM;
#pragma unroll
    for (int i = 0; i < 8; ++i) {
        const int c = lane + 64 * i;
        o[c] = __float2bfloat16((v[i] - mean) * rstd * w[c] + b[c]);
    }
}

// ---------------------------------------------------------------------------
// bf16 MFMA GEMM: C[M][N] = epi( A[M][K] * W[N][K]^T ). 128x128 tile, BK=32.
// MODE: 0=none, 1=softplus(v+bias), 3=gelu(v+bias)
// OUT:  0=f32, 1=bf16, 2=f32 split-K partial
// ---------------------------------------------------------------------------
template<int MODE, int OUT, int SPLITK>
__global__ __launch_bounds__(256)
void mgemm(const __hip_bfloat16* __restrict__ A, int lda,
           const __hip_bfloat16* __restrict__ W, int ldw,
           const float* __restrict__ bias,
           const float* __restrict__ res, int ldres,
           void* __restrict__ Cptr, int ldc,
           int M, int K)
{
    __shared__ __align__(16) bf16_t lsA[128 * 32];
    __shared__ __align__(16) bf16_t lsB[128 * 32];

    const int bm = blockIdx.y * 128;
    const int bn = blockIdx.x * 128;
    const int kLen = K / SPLITK;
    const int kBeg = blockIdx.z * kLen;

    const int t = threadIdx.x;
    const int l = t & 63, wid = t >> 6;
    const int wr = wid >> 1, wc = wid & 1;
    const int lrow = l & 15, lk = l >> 4;
    const int xorf = (lrow >> 1) & 3;
    const int rdoff = (lk ^ xorf) * 8;

    const int r0 = t >> 2,          c0 = t & 3;
    const int r1 = (256 + t) >> 2,  c1 = t & 3;
    const int sc0 = c0 ^ ((r0 >> 1) & 3);
    const int sc1 = c1 ^ ((r1 >> 1) & 3);

    const bf16_t* gA0 = (const bf16_t*)A + (size_t)(bm + r0) * lda + kBeg + sc0 * 8;
    const bf16_t* gA1 = (const bf16_t*)A + (size_t)(bm + r1) * lda + kBeg + sc1 * 8;
    const bf16_t* gB0 = (const bf16_t*)W + (size_t)(bn + r0) * ldw + kBeg + sc0 * 8;
    const bf16_t* gB1 = (const bf16_t*)W + (size_t)(bn + r1) * ldw + kBeg + sc1 * 8;
    bf16_t* dA0 = &lsA[(size_t)t * 8];
    bf16_t* dA1 = &lsA[(size_t)(256 + t) * 8];
    bf16_t* dB0 = &lsB[(size_t)t * 8];
    bf16_t* dB1 = &lsB[(size_t)(256 + t) * 8];

    f32x4 acc[4][4] = {};

    for (int k0 = 0; k0 < kLen; k0 += 32) {
        __builtin_amdgcn_global_load_lds(
            (const __attribute__((address_space(1))) void*)gA0,
            (__attribute__((address_space(3))) void*)dA0, 16, 0, 0);
        __builtin_amdgcn_global_load_lds(
            (const __attribute__((address_space(1))) void*)gA1,
            (__attribute__((address_space(3))) void*)dA1, 16, 0, 0);
        __builtin_amdgcn_global_load_lds(
            (const __attribute__((address_space(1))) void*)gB0,
            (__attribute__((address_space(3))) void*)dB0, 16, 0, 0);
        __builtin_amdgcn_global_load_lds(
            (const __attribute__((address_space(1))) void*)gB1,
            (__attribute__((address_space(3))) void*)dB1, 16, 0, 0);
        gA0 += 32; gA1 += 32; gB0 += 32; gB1 += 32;
        __syncthreads();

        bf16x8 af[4], bfv[4];
#pragma unroll
        for (int m = 0; m < 4; ++m) {
            const int ra = wr * 64 + m * 16 + lrow;
            af[m] = *(const bf16x8*)&lsA[ra * 32 + rdoff];
        }
#pragma unroll
        for (int n = 0; n < 4; ++n) {
            const int rb = wc * 64 + n * 16 + lrow;
            bfv[n] = *(const bf16x8*)&lsB[rb * 32 + rdoff];
        }
#pragma unroll
        for (int m = 0; m < 4; ++m)
#pragma unroll
            for (int n = 0; n < 4; ++n)
                acc[m][n] = __builtin_amdgcn_mfma_f32_16x16x32_bf16(
                    af[m], bfv[n], acc[m][n], 0, 0, 0);
        __syncthreads();
    }

    float* Cf = (float*)Cptr;
    __hip_bfloat16* Cb = (__hip_bfloat16*)Cptr;
    if (OUT == 2) Cf += (size_t)blockIdx.z * M * ldc;

#pragma unroll
    for (int m = 0; m < 4; ++m) {
#pragma unroll
        for (int n = 0; n < 4; ++n) {
#pragma unroll
            for (int j = 0; j < 4; ++j) {
                const int row = bm + wr * 64 + m * 16 + lk * 4 + j;
                const int col = bn + wc * 64 + n * 16 + lrow;
                float v = acc[m][n][j];
                if (MODE == 1) {
                    v += bias[col];
                    v = (v > 20.f) ? v
                        : 0.69314718f * __builtin_amdgcn_logf(1.f + fexp2(1.44269504f * v));
                } else if (MODE == 3) {
                    v += bias[col];
                    v = 0.5f * v * (1.f + erff(v * 0.70710678118654752f));
                }
                if (OUT == 1) Cb[(size_t)row * ldc + col] = __float2bfloat16(v);
                else          Cf[(size_t)row * ldc + col] = v;
            }
        }
    }
}

// ---------------------------------------------------------------------------
// Combined weight prep (range-dispatched on blockIdx).
// ---------------------------------------------------------------------------
__global__ __launch_bounds__(256)
void k_prep(const float* __restrict__ ipw, const float* __restrict__ f1w,
            const float* __restrict__ f2w,
            const float* __restrict__ xpf, const float* __restrict__ xpb,
            const float* __restrict__ dwf, const float* __restrict__ dwb,
            const float* __restrict__ dbf, const float* __restrict__ dbb,
            const float* __restrict__ wo,
            __hip_bfloat16* __restrict__ wip, __hip_bfloat16* __restrict__ wfc1,
            __hip_bfloat16* __restrict__ wfc2, __hip_bfloat16* __restrict__ wxp,
            __hip_bfloat16* __restrict__ wdt, __hip_bfloat16* __restrict__ wop,
            float* __restrict__ dtbias)
{
    const int bid = blockIdx.x;
    const int tid = threadIdx.x;
    if (bid < 4096) {
        const int i = bid * 256 + tid;
        wip[i] = __float2bfloat16(ipw[i]);
    } else if (bid < 8192) {
        const int i = (bid - 4096) * 256 + tid;
        wfc1[i] = __float2bfloat16(f1w[i]);
    } else if (bid < 12288) {
        const int i = (bid - 8192) * 256 + tid;
        wfc2[i] = __float2bfloat16(f2w[i]);
    } else if (bid < 13312) {
        const int idx = (bid - 12288) * 256 + tid;   // 128*2048
        const int r = idx >> 11, c = idx & 2047;
        float v = 0.f;
        if (r < 64) { if (c < 1024) v = xpf[r * 1024 + c]; }
        else        { if (c >= 1024) v = xpb[(r - 64) * 1024 + (c - 1024)]; }
        wxp[idx] = __float2bfloat16(v);
    } else if (bid < 14336) {
        const int idx = (bid - 13312) * 256 + tid;   // 2048*128
        const int r = idx >> 7, c = idx & 127;
        float v = 0.f;
        if (r < 1024) { if (c < 32) v = dwf[r * 32 + c]; }
        else          { if (c >= 64 && c < 96) v = dwb[(r - 1024) * 32 + (c - 64)]; }
        wdt[idx] = __float2bfloat16(v);
        if (idx < 2048) dtbias[idx] = (idx < 1024) ? dbf[idx] : dbb[idx - 1024];
    } else {
        const int idx = (bid - 14336) * 256 + tid;   // 512*2048
        const int r = idx >> 11, c = idx & 2047;
        wop[idx] = __float2bfloat16(0.5f * wo[r * 1024 + (c & 1023)]);
    }
}

// ---------------------------------------------------------------------------
// Depthwise conv (k=4) + SiLU, both directions, original time order.
// ---------------------------------------------------------------------------
__global__ __launch_bounds__(256)
void conv2_kernel(const __hip_bfloat16* __restrict__ xz,
                  const float* __restrict__ wf, const float* __restrict__ bf_,
                  const float* __restrict__ wb, const float* __restrict__ bb_,
                  __hip_bfloat16* __restrict__ out)
{
    const int idx = blockIdx.x * 256 + threadIdx.x;   // B*L*2048
    const int e = idx & 2047;
    const int dir = e >> 10;
    const int d = e & 1023;
    const int t = (idx >> 11) & (L_ - 1);
    const int b = idx >> 22;
    const __hip_bfloat16* base = xz + (size_t)b * L_ * E2 + d;
    const float* w = dir ? wb : wf;
    float acc = dir ? bb_[d] : bf_[d];
#pragma unroll
    for (int k = 0; k < 4; ++k) {
        const int tt = dir ? (t + 3 - k) : (t - 3 + k);
        if (tt >= 0 && tt < L_)
            acc += w[d * 4 + k] * __bfloat162float(base[(size_t)tt * E2]);
    }
    out[idx] = __float2bfloat16(acc * sigm(acc));
}

// ---------------------------------------------------------------------------
// Split-K(8) reduce for x_proj + scatter B/C into scan-order [g][s][16] f32.
// ---------------------------------------------------------------------------
__global__ void k_red2(const float* __restrict__ part,
                       __hip_bfloat16* __restrict__ xb,
                       float* __restrict__ sB4, float* __restrict__ sC4)
{
    const int idx = blockIdx.x * 256 + threadIdx.x;   // 4096*128
    float s4 = 0.f;
#pragma unroll
    for (int z = 0; z < 8; ++z) s4 += part[idx + z * 524288];
    xb[idx] = __float2bfloat16(s4);
    const int col = idx & 127, row = idx >> 7;
    const int c64 = col & 63, dirq = col >> 6;
    if (c64 >= 32) {
        const int bq = row >> 11, tt = row & 2047;
        const int s = dirq ? (L_ - 1 - tt) : tt;
        const int n = c64 & 15;
        const int g = dirq * 2 + bq;
        float* dst = (c64 < 48 ? sB4 : sC4) + ((size_t)g * L_ + s) * 16 + n;
        *dst = s4;
    }
}

// ---------------------------------------------------------------------------
// Fused transpose + local scan (p1). Block tile = 64 chains x 64 steps
// (exactly one chunk). Packs (dt|u) into LDS [chain][step], writes sdtdu,
// then runs the local h-scan from LDS and emits P/Hend.
// ---------------------------------------------------------------------------
__global__ __launch_bounds__(256)
void k_scanscan(const __hip_bfloat16* __restrict__ dtb,
                const __hip_bfloat16* __restrict__ ucv,
                const float* __restrict__ sB4,
                const float* __restrict__ AlF, const float* __restrict__ AlB,
                u32* __restrict__ sdtdu,
                float* __restrict__ P, float* __restrict__ Hend)
{
    __shared__ u32 lds[64][65];   // [chain_local][step], 65-dw rows (2-way banks)
    const int bid = blockIdx.x;
    const int st  = bid & 31;          // chunk index (64 steps)
    const int dtl = (bid >> 5) & 15;
    const int b   = (bid >> 9) & 1;
    const int dir = bid >> 10;
    const int tid = threadIdx.x;
    const int g = dir * 2 + b;

    // Phase A: load 64x64 tile of dt/u, pack into LDS [d][s].
    {
        const int c8 = (tid & 7) * 8;
#pragma unroll
        for (int rr = 0; rr < 2; ++rr) {
            const int r = (tid >> 3) + rr * 32;    // step local 0..63
            const int s = st * 64 + r;
            const int tt = dir ? (L_ - 1 - s) : s;
            const size_t row = (size_t)b * L_ + tt;
            const int e = dir * 1024 + dtl * 64 + c8;
            const uint4 dv = *(const uint4*)((const u16*)dtb + row * E2 + e);
            const uint4 uv = *(const uint4*)((const u16*)ucv + row * E2 + e);
            const u32 dw[4] = { dv.x, dv.y, dv.z, dv.w };
            const u32 uw[4] = { uv.x, uv.y, uv.z, uv.w };
#pragma unroll
            for (int jj = 0; jj < 4; ++jj) {
                lds[c8 + 2 * jj][r]     = ((uw[jj] & 0xffffu) << 16) | (dw[jj] & 0xffffu);
                lds[c8 + 2 * jj + 1][r] = (uw[jj] & 0xffff0000u) | (dw[jj] >> 16);
            }
        }
    }
    __syncthreads();

    // Phase B: write sdtdu [chain][step] (16 u32 per thread).
    {
        const int cd = tid >> 2, s16 = (tid & 3) * 16;
        const int chain = dir * 2048 + b * 1024 + dtl * 64 + cd;
        u32* dst = sdtdu + (size_t)chain * L_ + st * 64 + s16;
#pragma unroll
        for (int jj = 0; jj < 4; ++jj) {
            uint4 v;
            v.x = lds[cd][s16 + 4 * jj + 0];
            v.y = lds[cd][s16 + 4 * jj + 1];
            v.z = lds[cd][s16 + 4 * jj + 2];
            v.w = lds[cd][s16 + 4 * jj + 3];
            *(uint4*)(dst + 4 * jj) = v;
        }
    }

    // Phase C: local scan over the 64 steps (from LDS; quad-broadcast reads).
    {
        const int j = tid & 3;
        const int cd = tid >> 2;
        const int chain = dir * 2048 + b * 1024 + dtl * 64 + cd;
        const int d = chain & 1023;
        const float* Al = dir ? AlB : AlF;
        const float4 al = *(const float4*)(Al + d * NS + j * 4);
        const float An2[4] = { -fexp(al.x) * 1.44269504f, -fexp(al.y) * 1.44269504f,
                               -fexp(al.z) * 1.44269504f, -fexp(al.w) * 1.44269504f };
        const float* pB = sB4 + ((size_t)g * L_ + st * 64) * 16 + j * 4;

        float h[4] = { 0.f, 0.f, 0.f, 0.f };
        float sdt = 0.f;
        for (int i = 0; i < 64; ++i) {
            const u32 w32 = lds[cd][i];
            const float dt = __uint_as_float(w32 << 16);
            const float uu = __uint_as_float(w32 & 0xffff0000u);
            const float w = dt * uu;
            const float4 B4 = *(const float4*)(pB + i * 16);
            h[0] = fexp2(dt * An2[0]) * h[0] + w * B4.x;
            h[1] = fexp2(dt * An2[1]) * h[1] + w * B4.y;
            h[2] = fexp2(dt * An2[2]) * h[2] + w * B4.z;
            h[3] = fexp2(dt * An2[3]) * h[3] + w * B4.w;
            sdt += dt;
        }
        const int task = st * NCH + chain;
        float4 Pv = { fexp2(An2[0] * sdt), fexp2(An2[1] * sdt),
                      fexp2(An2[2] * sdt), fexp2(An2[3] * sdt) };
        *(float4*)(P + (size_t)task * NS + j * 4) = Pv;
        float4 Hv = { h[0], h[1], h[2], h[3] };
        *(float4*)(Hend + (size_t)task * NS + j * 4) = Hv;
    }
}

__global__ __launch_bounds__(256)
void scan_p2(const float* __restrict__ P, float* __restrict__ Hend)
{
    const int tid = threadIdx.x;
    const int n = tid & 15;
    const int chain = blockIdx.x * 16 + (tid >> 4);
    float hin = 0.f;
    for (int c = 0; c < CH; ++c) {
        const size_t idx = ((size_t)c * NCH + chain) * NS + n;
        const float nh = P[idx] * hin + Hend[idx];
        Hend[idx] = hin;
        hin = nh;
    }
}

// p3: scan + in-LDS transpose + SiLU(z) gate + coalesced yall write.
// ly rows = 70 u16 = 35 dw (odd) -> 16-row stride is 16 mod 32: ~2-way banks.
__global__ __launch_bounds__(256)
void scan_p3(const u32* __restrict__ sdtdu, const float* __restrict__ sB4,
             const float* __restrict__ sC4,
             const float* __restrict__ AlF, const float* __restrict__ AlB,
             const float* __restrict__ DpF, const float* __restrict__ DpB,
             const float* __restrict__ Hin,
             const __hip_bfloat16* __restrict__ xz,
             __hip_bfloat16* __restrict__ yall)
{
    __shared__ u16 ly[64][70];
    const int tid = threadIdx.x;
    const int j = tid & 3;
    const int task = blockIdx.x * 64 + (tid >> 2);
    const int chain = task & (NCH - 1);
    const int c = task >> 12;
    const int dir = chain >> 11;
    const int b = (chain >> 10) & 1;
    const int d = chain & 1023;
    const int g = dir * 2 + b;

    const float* Al = dir ? AlB : AlF;
    const float4 al = *(const float4*)(Al + d * NS + j * 4);
    const float An2[4] = { -fexp(al.x) * 1.44269504f, -fexp(al.y) * 1.44269504f,
                           -fexp(al.z) * 1.44269504f, -fexp(al.w) * 1.44269504f };
    const float Dd = (dir ? DpB : DpF)[d];

    const u32* pdt = sdtdu + (size_t)chain * L_ + c * TT;
    const float* pB = sB4 + ((size_t)g * L_ + c * TT) * 16 + j * 4;
    const float* pC = sC4 + ((size_t)g * L_ + c * TT) * 16 + j * 4;

    const float4 hv = *(const float4*)(Hin + (size_t)task * NS + j * 4);
    float h[4] = { hv.x, hv.y, hv.z, hv.w };

    for (int i = 0; i < TT; i += 4) {
        const uint4 pk = *(const uint4*)(pdt + i);
        const u32 wv[4] = { pk.x, pk.y, pk.z, pk.w };
        float qv[4], us[4];
#pragma unroll
        for (int k = 0; k < 4; ++k) {
            const float dt = __uint_as_float(wv[k] << 16);
            const float uu = __uint_as_float(wv[k] & 0xffff0000u);
            us[k] = uu;
            const float w = dt * uu;
            const float4 B4 = *(const float4*)(pB + (i + k) * 16);
            const float4 C4 = *(const float4*)(pC + (i + k) * 16);
            h[0] = fexp2(dt * An2[0]) * h[0] + w * B4.x;
            h[1] = fexp2(dt * An2[1]) * h[1] + w * B4.y;
            h[2] = fexp2(dt * An2[2]) * h[2] + w * B4.z;
            h[3] = fexp2(dt * An2[3]) * h[3] + w * B4.w;
            qv[k] = h[0] * C4.x + h[1] * C4.y + h[2] * C4.z + h[3] * C4.w;
        }
#pragma unroll
        for (int k = 0; k < 4; ++k) qv[k] = swzadd<0x041F>(qv[k]);
#pragma unroll
        for (int k = 0; k < 4; ++k) qv[k] = swzadd<0x081F>(qv[k]);
        if (j == 0) {
            u32* lp = (u32*)&ly[tid >> 2][i];   // 4B-aligned (140B rows, i%4==0)
            lp[0] = (u32)f2bu(qv[0] + us[0] * Dd) | ((u32)f2bu(qv[1] + us[1] * Dd) << 16);
            lp[1] = (u32)f2bu(qv[2] + us[2] * Dd) | ((u32)f2bu(qv[3] + us[3] * Dd) << 16);
        }
    }
    __syncthreads();

    // gate + transpose: thread -> (step sl, 16 d-cols starting dql)
    {
        const int cb = (blockIdx.x * 64) & (NCH - 1);   // block chain base
        const int dir2 = cb >> 11, b2 = (cb >> 10) & 1, dbase = cb & 1023;
        const int c2 = (blockIdx.x * 64) >> 12;
        const int sl = tid >> 2;
        const int dql = (tid & 3) * 16;
        const int s = c2 * TT + sl;
        const int tt = dir2 ? (L_ - 1 - s) : s;
        const size_t row = (size_t)b2 * L_ + tt;
        const u16* zp = (const u16*)xz + row * E2 + 1024 + dbase + dql;
        const uint4 zv0 = *(const uint4*)zp;
        const uint4 zv1 = *(const uint4*)(zp + 8);
        const u32 zw[8] = { zv0.x, zv0.y, zv0.z, zv0.w, zv1.x, zv1.y, zv1.z, zv1.w };
        u16 ov[16];
#pragma unroll
        for (int jj = 0; jj < 8; ++jj) {
            const float z0 = __uint_as_float(zw[jj] << 16);
            const float z1 = __uint_as_float(zw[jj] & 0xffff0000u);
            const float y0 = __uint_as_float((u32)ly[dql + 2 * jj][sl] << 16);
            const float y1 = __uint_as_float((u32)ly[dql + 2 * jj + 1][sl] << 16);
            ov[2 * jj]     = f2bu(y0 * (z0 * sigm(z0)));
            ov[2 * jj + 1] = f2bu(y1 * (z1 * sigm(z1)));
        }
        u16* op = (u16*)yall + row * E2 + dir2 * 1024 + dbase + dql;
        *(uint4*)op = *(uint4*)ov;
        *(uint4*)(op + 8) = *(uint4*)(ov + 8);
    }
}

// ---------------------------------------------------------------------------
// Fused: out_proj split-K reduce + residual -> xmid, then LN2 -> xn2 (bf16).
// ---------------------------------------------------------------------------
__global__ __launch_bounds__(256)
void k_redln(const float* __restrict__ part, const float* __restrict__ x,
             const float* __restrict__ w, const float* __restrict__ bb,
             float* __restrict__ xmid, __hip_bfloat16* __restrict__ xn2)
{
    const int row = blockIdx.x * 4 + (threadIdx.x >> 6);
    const int lane = threadIdx.x & 63;
    const size_t base = (size_t)row * DM;
    const int c0 = lane * 4, c1 = 256 + lane * 4;

    const float4 p0a = *(const float4*)(part + base + c0);
    const float4 p1a = *(const float4*)(part + 2097152 + base + c0);
    const float4 xa  = *(const float4*)(x + base + c0);
    const float4 p0b = *(const float4*)(part + base + c1);
    const float4 p1b = *(const float4*)(part + 2097152 + base + c1);
    const float4 xb  = *(const float4*)(x + base + c1);
    float v[8];
    v[0] = xa.x + p0a.x + p1a.x; v[1] = xa.y + p0a.y + p1a.y;
    v[2] = xa.z + p0a.z + p1a.z; v[3] = xa.w + p0a.w + p1a.w;
    v[4] = xb.x + p0b.x + p1b.x; v[5] = xb.y + p0b.y + p1b.y;
    v[6] = xb.z + p0b.z + p1b.z; v[7] = xb.w + p0b.w + p1b.w;
    float4 oa = { v[0], v[1], v[2], v[3] }, ob = { v[4], v[5], v[6], v[7] };
    *(float4*)(xmid + base + c0) = oa;
    *(float4*)(xmid + base + c1) = ob;

    float s = 0.f;
#pragma unroll
    for (int i = 0; i < 8; ++i) s += v[i];
#pragma unroll
    for (int off = 32; off > 0; off >>= 1) s += __shfl_xor(s, off);
    const float mean = s * (1.f / DM);
    float vs = 0.f;
#pragma unroll
    for (int i = 0; i < 8; ++i) { float dd = v[i] - mean; vs += dd * dd; }
#pragma unroll
    for (int off = 32; off > 0; off >>= 1) vs += __shfl_xor(vs, off);
    const float rstd = rsqrtf(vs * (1.f / DM) + 1e-5f);

    u16 o0[4], o1[4];
#pragma unroll
    for (int i = 0; i < 4; ++i) {
        o0[i] = f2bu((v[i] - mean) * rstd * w[c0 + i] + bb[c0 + i]);
        o1[i] = f2bu((v[4 + i] - mean) * rstd * w[c1 + i] + bb[c1 + i]);
    }
    *(uint2*)((u16*)xn2 + base + c0) = *(uint2*)o0;
    *(uint2*)((u16*)xn2 + base + c1) = *(uint2*)o1;
}

__global__ __launch_bounds__(256)
void k_redfc2(const float* __restrict__ part, const float* __restrict__ res,
              const float* __restrict__ bias, float* __restrict__ out)
{
    const int i = (blockIdx.x * 256 + threadIdx.x) * 4;   // over 4096*512
    const int col = i & (DM - 1);
    const float4 p0 = *(const float4*)(part + i);
    const float4 p1 = *(const float4*)(part + 2097152 + i);
    const float4 rv = *(const float4*)(res + i);
    const float4 bv = *(const float4*)(bias + col);
    float4 o;
    o.x = rv.x + bv.x + p0.x + p1.x; o.y = rv.y + bv.y + p0.y + p1.y;
    o.z = rv.z + bv.z + p0.z + p1.z; o.w = rv.w + bv.w + p0.w + p1.w;
    *(float4*)(out + i) = o;
}

// ---------------------------------------------------------------------------
// Launch
// ---------------------------------------------------------------------------
extern "C" void kernel_launch(void* const* d_in, const int* in_sizes, int n_in,
                              void* d_out, int out_size, void* d_ws, size_t ws_size,
                              hipStream_t stream)
{
    const float* x         = (const float*)d_in[0];
    const float* ln1_w     = (const float*)d_in[1];
    const float* ln1_b     = (const float*)d_in[2];
    const float* in_proj_w = (const float*)d_in[3];
    const float* conv_w[2]    = { (const float*)d_in[4],  (const float*)d_in[11] };
    const float* conv_b[2]    = { (const float*)d_in[5],  (const float*)d_in[12] };
    const float* x_proj_w[2]  = { (const float*)d_in[6],  (const float*)d_in[13] };
    const float* dt_proj_w[2] = { (const float*)d_in[7],  (const float*)d_in[14] };
    const float* dt_proj_b[2] = { (const float*)d_in[8],  (const float*)d_in[15] };
    const float* A_log[2]     = { (const float*)d_in[9],  (const float*)d_in[16] };
    const float* D_param[2]   = { (const float*)d_in[10], (const float*)d_in[17] };
    const float* out_proj_w = (const float*)d_in[18];
    const float* ln2_w      = (const float*)d_in[19];
    const float* ln2_b      = (const float*)d_in[20];
    const float* fc1_w      = (const float*)d_in[21];
    const float* fc1_b      = (const float*)d_in[22];
    const float* fc2_w      = (const float*)d_in[23];
    const float* fc2_b      = (const float*)d_in[24];
    float* out = (float*)d_out;

    char* ws = (char*)d_ws;
    const size_t MB = 1u << 20;
    // resident weights: 0..9.01 MB
    __hip_bfloat16* wip  = (__hip_bfloat16*)(ws + 0 * MB);
    __hip_bfloat16* wxp  = (__hip_bfloat16*)(ws + 2 * MB);
    __hip_bfloat16* wdt  = (__hip_bfloat16*)(ws + 2 * MB + 512 * 1024);
    __hip_bfloat16* wop  = (__hip_bfloat16*)(ws + 3 * MB);
    __hip_bfloat16* wfc1 = (__hip_bfloat16*)(ws + 5 * MB);
    __hip_bfloat16* wfc2 = (__hip_bfloat16*)(ws + 7 * MB);
    float* dtbias        = (float*)(ws + 9 * MB);
    // phase 1 lifetimes:
    __hip_bfloat16* xz   = (__hip_bfloat16*)(ws + 10 * MB);  // in_proj..p3
    __hip_bfloat16* ucv  = (__hip_bfloat16*)(ws + 26 * MB);  // conv..scanscan
    __hip_bfloat16* dtb  = (__hip_bfloat16*)(ws + 42 * MB);  // dtgemm..scanscan
    float* xdbp          = (float*)(ws + 58 * MB);           // xproj..k_red2 (16 MB)
    float* Ps            = (float*)(ws + 58 * MB);           // scanscan..p2 (8 MB)
    float* Hend          = (float*)(ws + 66 * MB);           // scanscan..p3 (8 MB)
    __hip_bfloat16* xn1  = (__hip_bfloat16*)(ws + 74 * MB);  // ln1..in_proj
    __hip_bfloat16* xdbb = (__hip_bfloat16*)(ws + 78 * MB);  // k_red2..dtgemm
    u32* sdtdu           = (u32*)(ws + 74 * MB);             // scanscan..p3 (32 MB)
    float* part          = (float*)(ws + 74 * MB);           // opgemm/fc2 partials
                                                             // (16 MB, after p3)
    __hip_bfloat16* yall = (__hip_bfloat16*)(ws + 26 * MB);  // p3..opgemm (over ucv)
    float* sB4           = (float*)(ws + 106 * MB);          // k_red2..p3
    float* sC4           = (float*)(ws + 106 * MB + 512 * 1024);  // peak 107 MB
    // phase 2 (mamba buffers dead):
    float* xmid          = (float*)(ws + 10 * MB);           // k_redln..redfc2
    __hip_bfloat16* xn2  = (__hip_bfloat16*)(ws + 18 * MB);
    __hip_bfloat16* h1   = (__hip_bfloat16*)(ws + 42 * MB);  // fc1..fc2 (over dtb)

    // --- weight prep ---
    k_prep<<<18432, 256, 0, stream>>>(
        in_proj_w, fc1_w, fc2_w, x_proj_w[0], x_proj_w[1],
        dt_proj_w[0], dt_proj_w[1], dt_proj_b[0], dt_proj_b[1], out_proj_w,
        wip, wfc1, wfc2, wxp, wdt, wop, dtbias);

    // --- mamba branch ---
    ln_kernel<<<ROWS, 64, 0, stream>>>(x, ln1_w, ln1_b, xn1);

    mgemm<0, 1, 1><<<dim3(16, 32, 1), 256, 0, stream>>>(
        xn1, DM, wip, DM, nullptr, nullptr, 0, xz, E2, ROWS, DM);

    conv2_kernel<<<(B_ * L_ * E2) / 256, 256, 0, stream>>>(
        xz, conv_w[0], conv_b[0], conv_w[1], conv_b[1], ucv);

    mgemm<0, 2, 8><<<dim3(1, 32, 8), 256, 0, stream>>>(
        ucv, E2, wxp, E2, nullptr, nullptr, 0, xdbp, 128, ROWS, E2);
    k_red2<<<2048, 256, 0, stream>>>(xdbp, xdbb, sB4, sC4);

    mgemm<1, 1, 1><<<dim3(16, 32, 1), 256, 0, stream>>>(
        xdbb, 128, wdt, 128, dtbias, nullptr, 0, dtb, E2, ROWS, 128);

    // fused transpose + local scan (replaces scanprep + scan_p1)
    k_scanscan<<<2048, 256, 0, stream>>>(
        dtb, ucv, sB4, A_log[0], A_log[1], sdtdu, Ps, Hend);
    scan_p2<<<NCH / 16, 256, 0, stream>>>(Ps, Hend);
    scan_p3<<<(CH * NCH) / 64, 256, 0, stream>>>(
        sdtdu, sB4, sC4, A_log[0], A_log[1], D_param[0], D_param[1],
        Hend, xz, yall);

    // out_proj split-K=2 -> partials; fused reduce+residual+LN2
    mgemm<0, 2, 2><<<dim3(4, 32, 2), 256, 0, stream>>>(
        yall, E2, wop, E2, nullptr, nullptr, 0, part, DM, ROWS, E2);
    k_redln<<<1024, 256, 0, stream>>>(part, x, ln2_w, ln2_b, xmid, xn2);

    // --- MLP branch ---
    mgemm<3, 1, 1><<<dim3(16, 32, 1), 256, 0, stream>>>(
        xn2, DM, wfc1, DM, fc1_b, nullptr, 0, h1, HID, ROWS, DM);

    mgemm<0, 2, 2><<<dim3(4, 32, 2), 256, 0, stream>>>(
        h1, HID, wfc2, HID, nullptr, nullptr, 0, part, DM, ROWS, HID);
    k_redfc2<<<2048, 256, 0, stream>>>(part, xmid, fc2_b, out);
}

// Round 12
// 262.400 us; speedup vs baseline: 16.2569x; 1.0399x over previous
//
#include <hip/hip_runtime.h>
#include <hip/hip_bf16.h>

// ---------------------------------------------------------------------------
// MotionMambaBlock forward. Round 12: B/C staged in LDS per block in scan_p3
// (kills ~1 GB of L2 broadcast re-reads) and in k_scanscan phase C.
// ---------------------------------------------------------------------------

#define B_   2
#define L_   2048
#define DM   512
#define DI   1024
#define E2   2048
#define NS   16
#define HID  2048
#define ROWS (B_ * L_)     // 4096
#define CH   32            // scan chunks
#define TT   (L_ / CH)     // 64
#define NCH  4096          // chains = 2 dirs * B * DI

typedef __bf16 bf16_t;
typedef bf16_t bf16x8 __attribute__((ext_vector_type(8)));
typedef float f32x4 __attribute__((ext_vector_type(4)));
typedef unsigned int u32;
typedef unsigned short u16;

__device__ __forceinline__ float fexp2(float x) { return __builtin_amdgcn_exp2f(x); }
__device__ __forceinline__ float fexp(float x)  { return fexp2(x * 1.44269504f); }
__device__ __forceinline__ float frcp(float x)  { return __builtin_amdgcn_rcpf(x); }
__device__ __forceinline__ float sigm(float x)  { return frcp(1.f + fexp2(-1.44269504f * x)); }

template<int PAT>
__device__ __forceinline__ float swzadd(float q)
{
    return q + __int_as_float(__builtin_amdgcn_ds_swizzle(__float_as_int(q), PAT));
}

__device__ __forceinline__ u16 f2bu(float f)
{
    __hip_bfloat16 h = __float2bfloat16(f);
    return *(u16*)&h;
}

// ---------------------------------------------------------------------------
// LayerNorm over D=512, one wave per row, bf16 output (LN1).
// ---------------------------------------------------------------------------
__global__ __launch_bounds__(64)
void ln_kernel(const float* __restrict__ in, const float* __restrict__ w,
               const float* __restrict__ b, __hip_bfloat16* __restrict__ out)
{
    const int row  = blockIdx.x;
    const int lane = threadIdx.x;
    const float* p = in + (size_t)row * DM;
    float v[8];
    float s = 0.f;
#pragma unroll
    for (int i = 0; i < 8; ++i) { v[i] = p[lane + 64 * i]; s += v[i]; }
#pragma unroll
    for (int off = 32; off > 0; off >>= 1) s += __shfl_xor(s, off);
    const float mean = s * (1.f / DM);
    float vs = 0.f;
#pragma unroll
    for (int i = 0; i < 8; ++i) { float d = v[i] - mean; vs += d * d; }
#pragma unroll
    for (int off = 32; off > 0; off >>= 1) vs += __shfl_xor(vs, off);
    const float rstd = rsqrtf(vs * (1.f / DM) + 1e-5f);
    __hip_bfloat16* o = out + (size_t)row * DM;
#pragma unroll
    for (int i = 0; i < 8; ++i) {
        const int c = lane + 64 * i;
        o[c] = __float2bfloat16((v[i] - mean) * rstd * w[c] + b[c]);
    }
}

// ---------------------------------------------------------------------------
// bf16 MFMA GEMM: C[M][N] = epi( A[M][K] * W[N][K]^T ). 128x128 tile, BK=32.
// MODE: 0=none, 1=softplus(v+bias), 3=gelu(v+bias)
// OUT:  0=f32, 1=bf16, 2=f32 split-K partial
// ---------------------------------------------------------------------------
template<int MODE, int OUT, int SPLITK>
__global__ __launch_bounds__(256)
void mgemm(const __hip_bfloat16* __restrict__ A, int lda,
           const __hip_bfloat16* __restrict__ W, int ldw,
           const float* __restrict__ bias,
           const float* __restrict__ res, int ldres,
           void* __restrict__ Cptr, int ldc,
           int M, int K)
{
    __shared__ __align__(16) bf16_t lsA[128 * 32];
    __shared__ __align__(16) bf16_t lsB[128 * 32];

    const int bm = blockIdx.y * 128;
    const int bn = blockIdx.x * 128;
    const int kLen = K / SPLITK;
    const int kBeg = blockIdx.z * kLen;

    const int t = threadIdx.x;
    const int l = t & 63, wid = t >> 6;
    const int wr = wid >> 1, wc = wid & 1;
    const int lrow = l & 15, lk = l >> 4;
    const int xorf = (lrow >> 1) & 3;
    const int rdoff = (lk ^ xorf) * 8;

    const int r0 = t >> 2,          c0 = t & 3;
    const int r1 = (256 + t) >> 2,  c1 = t & 3;
    const int sc0 = c0 ^ ((r0 >> 1) & 3);
    const int sc1 = c1 ^ ((r1 >> 1) & 3);

    const bf16_t* gA0 = (const bf16_t*)A + (size_t)(bm + r0) * lda + kBeg + sc0 * 8;
    const bf16_t* gA1 = (const bf16_t*)A + (size_t)(bm + r1) * lda + kBeg + sc1 * 8;
    const bf16_t* gB0 = (const bf16_t*)W + (size_t)(bn + r0) * ldw + kBeg + sc0 * 8;
    const bf16_t* gB1 = (const bf16_t*)W + (size_t)(bn + r1) * ldw + kBeg + sc1 * 8;
    bf16_t* dA0 = &lsA[(size_t)t * 8];
    bf16_t* dA1 = &lsA[(size_t)(256 + t) * 8];
    bf16_t* dB0 = &lsB[(size_t)t * 8];
    bf16_t* dB1 = &lsB[(size_t)(256 + t) * 8];

    f32x4 acc[4][4] = {};

    for (int k0 = 0; k0 < kLen; k0 += 32) {
        __builtin_amdgcn_global_load_lds(
            (const __attribute__((address_space(1))) void*)gA0,
            (__attribute__((address_space(3))) void*)dA0, 16, 0, 0);
        __builtin_amdgcn_global_load_lds(
            (const __attribute__((address_space(1))) void*)gA1,
            (__attribute__((address_space(3))) void*)dA1, 16, 0, 0);
        __builtin_amdgcn_global_load_lds(
            (const __attribute__((address_space(1))) void*)gB0,
            (__attribute__((address_space(3))) void*)dB0, 16, 0, 0);
        __builtin_amdgcn_global_load_lds(
            (const __attribute__((address_space(1))) void*)gB1,
            (__attribute__((address_space(3))) void*)dB1, 16, 0, 0);
        gA0 += 32; gA1 += 32; gB0 += 32; gB1 += 32;
        __syncthreads();

        bf16x8 af[4], bfv[4];
#pragma unroll
        for (int m = 0; m < 4; ++m) {
            const int ra = wr * 64 + m * 16 + lrow;
            af[m] = *(const bf16x8*)&lsA[ra * 32 + rdoff];
        }
#pragma unroll
        for (int n = 0; n < 4; ++n) {
            const int rb = wc * 64 + n * 16 + lrow;
            bfv[n] = *(const bf16x8*)&lsB[rb * 32 + rdoff];
        }
#pragma unroll
        for (int m = 0; m < 4; ++m)
#pragma unroll
            for (int n = 0; n < 4; ++n)
                acc[m][n] = __builtin_amdgcn_mfma_f32_16x16x32_bf16(
                    af[m], bfv[n], acc[m][n], 0, 0, 0);
        __syncthreads();
    }

    float* Cf = (float*)Cptr;
    __hip_bfloat16* Cb = (__hip_bfloat16*)Cptr;
    if (OUT == 2) Cf += (size_t)blockIdx.z * M * ldc;

#pragma unroll
    for (int m = 0; m < 4; ++m) {
#pragma unroll
        for (int n = 0; n < 4; ++n) {
#pragma unroll
            for (int j = 0; j < 4; ++j) {
                const int row = bm + wr * 64 + m * 16 + lk * 4 + j;
                const int col = bn + wc * 64 + n * 16 + lrow;
                float v = acc[m][n][j];
                if (MODE == 1) {
                    v += bias[col];
                    v = (v > 20.f) ? v
                        : 0.69314718f * __builtin_amdgcn_logf(1.f + fexp2(1.44269504f * v));
                } else if (MODE == 3) {
                    v += bias[col];
                    v = 0.5f * v * (1.f + erff(v * 0.70710678118654752f));
                }
                if (OUT == 1) Cb[(size_t)row * ldc + col] = __float2bfloat16(v);
                else          Cf[(size_t)row * ldc + col] = v;
            }
        }
    }
}

// ---------------------------------------------------------------------------
// Combined weight prep (range-dispatched on blockIdx).
// ---------------------------------------------------------------------------
__global__ __launch_bounds__(256)
void k_prep(const float* __restrict__ ipw, const float* __restrict__ f1w,
            const float* __restrict__ f2w,
            const float* __restrict__ xpf, const float* __restrict__ xpb,
            const float* __restrict__ dwf, const float* __restrict__ dwb,
            const float* __restrict__ dbf, const float* __restrict__ dbb,
            const float* __restrict__ wo,
            __hip_bfloat16* __restrict__ wip, __hip_bfloat16* __restrict__ wfc1,
            __hip_bfloat16* __restrict__ wfc2, __hip_bfloat16* __restrict__ wxp,
            __hip_bfloat16* __restrict__ wdt, __hip_bfloat16* __restrict__ wop,
            float* __restrict__ dtbias)
{
    const int bid = blockIdx.x;
    const int tid = threadIdx.x;
    if (bid < 4096) {
        const int i = bid * 256 + tid;
        wip[i] = __float2bfloat16(ipw[i]);
    } else if (bid < 8192) {
        const int i = (bid - 4096) * 256 + tid;
        wfc1[i] = __float2bfloat16(f1w[i]);
    } else if (bid < 12288) {
        const int i = (bid - 8192) * 256 + tid;
        wfc2[i] = __float2bfloat16(f2w[i]);
    } else if (bid < 13312) {
        const int idx = (bid - 12288) * 256 + tid;   // 128*2048
        const int r = idx >> 11, c = idx & 2047;
        float v = 0.f;
        if (r < 64) { if (c < 1024) v = xpf[r * 1024 + c]; }
        else        { if (c >= 1024) v = xpb[(r - 64) * 1024 + (c - 1024)]; }
        wxp[idx] = __float2bfloat16(v);
    } else if (bid < 14336) {
        const int idx = (bid - 13312) * 256 + tid;   // 2048*128
        const int r = idx >> 7, c = idx & 127;
        float v = 0.f;
        if (r < 1024) { if (c < 32) v = dwf[r * 32 + c]; }
        else          { if (c >= 64 && c < 96) v = dwb[(r - 1024) * 32 + (c - 64)]; }
        wdt[idx] = __float2bfloat16(v);
        if (idx < 2048) dtbias[idx] = (idx < 1024) ? dbf[idx] : dbb[idx - 1024];
    } else {
        const int idx = (bid - 14336) * 256 + tid;   // 512*2048
        const int r = idx >> 11, c = idx & 2047;
        wop[idx] = __float2bfloat16(0.5f * wo[r * 1024 + (c & 1023)]);
    }
}

// ---------------------------------------------------------------------------
// Depthwise conv (k=4) + SiLU, both directions, original time order.
// ---------------------------------------------------------------------------
__global__ __launch_bounds__(256)
void conv2_kernel(const __hip_bfloat16* __restrict__ xz,
                  const float* __restrict__ wf, const float* __restrict__ bf_,
                  const float* __restrict__ wb, const float* __restrict__ bb_,
                  __hip_bfloat16* __restrict__ out)
{
    const int idx = blockIdx.x * 256 + threadIdx.x;   // B*L*2048
    const int e = idx & 2047;
    const int dir = e >> 10;
    const int d = e & 1023;
    const int t = (idx >> 11) & (L_ - 1);
    const int b = idx >> 22;
    const __hip_bfloat16* base = xz + (size_t)b * L_ * E2 + d;
    const float* w = dir ? wb : wf;
    float acc = dir ? bb_[d] : bf_[d];
#pragma unroll
    for (int k = 0; k < 4; ++k) {
        const int tt = dir ? (t + 3 - k) : (t - 3 + k);
        if (tt >= 0 && tt < L_)
            acc += w[d * 4 + k] * __bfloat162float(base[(size_t)tt * E2]);
    }
    out[idx] = __float2bfloat16(acc * sigm(acc));
}

// ---------------------------------------------------------------------------
// Split-K(8) reduce for x_proj + scatter B/C into scan-order [g][s][16] f32.
// ---------------------------------------------------------------------------
__global__ void k_red2(const float* __restrict__ part,
                       __hip_bfloat16* __restrict__ xb,
                       float* __restrict__ sB4, float* __restrict__ sC4)
{
    const int idx = blockIdx.x * 256 + threadIdx.x;   // 4096*128
    float s4 = 0.f;
#pragma unroll
    for (int z = 0; z < 8; ++z) s4 += part[idx + z * 524288];
    xb[idx] = __float2bfloat16(s4);
    const int col = idx & 127, row = idx >> 7;
    const int c64 = col & 63, dirq = col >> 6;
    if (c64 >= 32) {
        const int bq = row >> 11, tt = row & 2047;
        const int s = dirq ? (L_ - 1 - tt) : tt;
        const int n = c64 & 15;
        const int g = dirq * 2 + bq;
        float* dst = (c64 < 48 ? sB4 : sC4) + ((size_t)g * L_ + s) * 16 + n;
        *dst = s4;
    }
}

// ---------------------------------------------------------------------------
// Fused transpose + local scan (p1). Block tile = 64 chains x 64 steps
// (exactly one chunk). B staged in LDS for phase C.
// ---------------------------------------------------------------------------
__global__ __launch_bounds__(256)
void k_scanscan(const __hip_bfloat16* __restrict__ dtb,
                const __hip_bfloat16* __restrict__ ucv,
                const float* __restrict__ sB4,
                const float* __restrict__ AlF, const float* __restrict__ AlB,
                u32* __restrict__ sdtdu,
                float* __restrict__ P, float* __restrict__ Hend)
{
    __shared__ u32 lds[64][65];   // [chain_local][step]
    __shared__ float lBs[64 * 16];
    const int bid = blockIdx.x;
    const int st  = bid & 31;          // chunk index (64 steps)
    const int dtl = (bid >> 5) & 15;
    const int b   = (bid >> 9) & 1;
    const int dir = bid >> 10;
    const int tid = threadIdx.x;
    const int g = dir * 2 + b;

    // Phase A: load 64x64 tile of dt/u, pack into LDS [d][s]; stage B.
    {
        ((float4*)lBs)[tid] =
            ((const float4*)(sB4 + ((size_t)g * L_ + st * 64) * 16))[tid];
        const int c8 = (tid & 7) * 8;
#pragma unroll
        for (int rr = 0; rr < 2; ++rr) {
            const int r = (tid >> 3) + rr * 32;    // step local 0..63
            const int s = st * 64 + r;
            const int tt = dir ? (L_ - 1 - s) : s;
            const size_t row = (size_t)b * L_ + tt;
            const int e = dir * 1024 + dtl * 64 + c8;
            const uint4 dv = *(const uint4*)((const u16*)dtb + row * E2 + e);
            const uint4 uv = *(const uint4*)((const u16*)ucv + row * E2 + e);
            const u32 dw[4] = { dv.x, dv.y, dv.z, dv.w };
            const u32 uw[4] = { uv.x, uv.y, uv.z, uv.w };
#pragma unroll
            for (int jj = 0; jj < 4; ++jj) {
                lds[c8 + 2 * jj][r]     = ((uw[jj] & 0xffffu) << 16) | (dw[jj] & 0xffffu);
                lds[c8 + 2 * jj + 1][r] = (uw[jj] & 0xffff0000u) | (dw[jj] >> 16);
            }
        }
    }
    __syncthreads();

    // Phase B: write sdtdu [chain][step] (16 u32 per thread).
    {
        const int cd = tid >> 2, s16 = (tid & 3) * 16;
        const int chain = dir * 2048 + b * 1024 + dtl * 64 + cd;
        u32* dst = sdtdu + (size_t)chain * L_ + st * 64 + s16;
#pragma unroll
        for (int jj = 0; jj < 4; ++jj) {
            uint4 v;
            v.x = lds[cd][s16 + 4 * jj + 0];
            v.y = lds[cd][s16 + 4 * jj + 1];
            v.z = lds[cd][s16 + 4 * jj + 2];
            v.w = lds[cd][s16 + 4 * jj + 3];
            *(uint4*)(dst + 4 * jj) = v;
        }
    }

    // Phase C: local scan over the 64 steps (dt/u + B both from LDS).
    {
        const int j = tid & 3;
        const int cd = tid >> 2;
        const int chain = dir * 2048 + b * 1024 + dtl * 64 + cd;
        const int d = chain & 1023;
        const float* Al = dir ? AlB : AlF;
        const float4 al = *(const float4*)(Al + d * NS + j * 4);
        const float An2[4] = { -fexp(al.x) * 1.44269504f, -fexp(al.y) * 1.44269504f,
                               -fexp(al.z) * 1.44269504f, -fexp(al.w) * 1.44269504f };

        float h[4] = { 0.f, 0.f, 0.f, 0.f };
        float sdt = 0.f;
        for (int i = 0; i < 64; ++i) {
            const u32 w32 = lds[cd][i];
            const float dt = __uint_as_float(w32 << 16);
            const float uu = __uint_as_float(w32 & 0xffff0000u);
            const float w = dt * uu;
            const float4 B4 = *(const float4*)(lBs + i * 16 + j * 4);
            h[0] = fexp2(dt * An2[0]) * h[0] + w * B4.x;
            h[1] = fexp2(dt * An2[1]) * h[1] + w * B4.y;
            h[2] = fexp2(dt * An2[2]) * h[2] + w * B4.z;
            h[3] = fexp2(dt * An2[3]) * h[3] + w * B4.w;
            sdt += dt;
        }
        const int task = st * NCH + chain;
        float4 Pv = { fexp2(An2[0] * sdt), fexp2(An2[1] * sdt),
                      fexp2(An2[2] * sdt), fexp2(An2[3] * sdt) };
        *(float4*)(P + (size_t)task * NS + j * 4) = Pv;
        float4 Hv = { h[0], h[1], h[2], h[3] };
        *(float4*)(Hend + (size_t)task * NS + j * 4) = Hv;
    }
}

__global__ __launch_bounds__(256)
void scan_p2(const float* __restrict__ P, float* __restrict__ Hend)
{
    const int tid = threadIdx.x;
    const int n = tid & 15;
    const int chain = blockIdx.x * 16 + (tid >> 4);
    float hin = 0.f;
    for (int c = 0; c < CH; ++c) {
        const size_t idx = ((size_t)c * NCH + chain) * NS + n;
        const float nh = P[idx] * hin + Hend[idx];
        Hend[idx] = hin;
        hin = nh;
    }
}

// p3: scan (B/C from LDS) + in-LDS transpose + SiLU(z) gate + yall write.
__global__ __launch_bounds__(256)
void scan_p3(const u32* __restrict__ sdtdu, const float* __restrict__ sB4,
             const float* __restrict__ sC4,
             const float* __restrict__ AlF, const float* __restrict__ AlB,
             const float* __restrict__ DpF, const float* __restrict__ DpB,
             const float* __restrict__ Hin,
             const __hip_bfloat16* __restrict__ xz,
             __hip_bfloat16* __restrict__ yall)
{
    __shared__ u16 ly[64][70];
    __shared__ float lB[64 * 16];
    __shared__ float lC[64 * 16];
    const int tid = threadIdx.x;
    const int j = tid & 3;
    const int task = blockIdx.x * 64 + (tid >> 2);
    const int chain = task & (NCH - 1);
    const int c = task >> 12;
    const int dir = chain >> 11;
    const int b = (chain >> 10) & 1;
    const int d = chain & 1023;
    const int g = dir * 2 + b;

    // Stage B/C for the block's (g, chunk) once (coalesced float4).
    {
        const float* gBp = sB4 + ((size_t)g * L_ + c * TT) * 16;
        const float* gCp = sC4 + ((size_t)g * L_ + c * TT) * 16;
        ((float4*)lB)[tid] = ((const float4*)gBp)[tid];
        ((float4*)lC)[tid] = ((const float4*)gCp)[tid];
    }
    __syncthreads();

    const float* Al = dir ? AlB : AlF;
    const float4 al = *(const float4*)(Al + d * NS + j * 4);
    const float An2[4] = { -fexp(al.x) * 1.44269504f, -fexp(al.y) * 1.44269504f,
                           -fexp(al.z) * 1.44269504f, -fexp(al.w) * 1.44269504f };
    const float Dd = (dir ? DpB : DpF)[d];

    const u32* pdt = sdtdu + (size_t)chain * L_ + c * TT;

    const float4 hv = *(const float4*)(Hin + (size_t)task * NS + j * 4);
    float h[4] = { hv.x, hv.y, hv.z, hv.w };

    for (int i = 0; i < TT; i += 4) {
        const uint4 pk = *(const uint4*)(pdt + i);
        const u32 wv[4] = { pk.x, pk.y, pk.z, pk.w };
        float qv[4], us[4];
#pragma unroll
        for (int k = 0; k < 4; ++k) {
            const float dt = __uint_as_float(wv[k] << 16);
            const float uu = __uint_as_float(wv[k] & 0xffff0000u);
            us[k] = uu;
            const float w = dt * uu;
            const float4 B4 = *(const float4*)(lB + (i + k) * 16 + j * 4);
            const float4 C4 = *(const float4*)(lC + (i + k) * 16 + j * 4);
            h[0] = fexp2(dt * An2[0]) * h[0] + w * B4.x;
            h[1] = fexp2(dt * An2[1]) * h[1] + w * B4.y;
            h[2] = fexp2(dt * An2[2]) * h[2] + w * B4.z;
            h[3] = fexp2(dt * An2[3]) * h[3] + w * B4.w;
            qv[k] = h[0] * C4.x + h[1] * C4.y + h[2] * C4.z + h[3] * C4.w;
        }
#pragma unroll
        for (int k = 0; k < 4; ++k) qv[k] = swzadd<0x041F>(qv[k]);
#pragma unroll
        for (int k = 0; k < 4; ++k) qv[k] = swzadd<0x081F>(qv[k]);
        if (j == 0) {
            u32* lp = (u32*)&ly[tid >> 2][i];   // 4B-aligned (140B rows, i%4==0)
            lp[0] = (u32)f2bu(qv[0] + us[0] * Dd) | ((u32)f2bu(qv[1] + us[1] * Dd) << 16);
            lp[1] = (u32)f2bu(qv[2] + us[2] * Dd) | ((u32)f2bu(qv[3] + us[3] * Dd) << 16);
        }
    }
    __syncthreads();

    // gate + transpose: thread -> (step sl, 16 d-cols starting dql)
    {
        const int cb = (blockIdx.x * 64) & (NCH - 1);   // block chain base
        const int dir2 = cb >> 11, b2 = (cb >> 10) & 1, dbase = cb & 1023;
        const int c2 = (blockIdx.x * 64) >> 12;
        const int sl = tid >> 2;
        const int dql = (tid & 3) * 16;
        const int s = c2 * TT + sl;
        const int tt = dir2 ? (L_ - 1 - s) : s;
        const size_t row = (size_t)b2 * L_ + tt;
        const u16* zp = (const u16*)xz + row * E2 + 1024 + dbase + dql;
        const uint4 zv0 = *(const uint4*)zp;
        const uint4 zv1 = *(const uint4*)(zp + 8);
        const u32 zw[8] = { zv0.x, zv0.y, zv0.z, zv0.w, zv1.x, zv1.y, zv1.z, zv1.w };
        u16 ov[16];
#pragma unroll
        for (int jj = 0; jj < 8; ++jj) {
            const float z0 = __uint_as_float(zw[jj] << 16);
            const float z1 = __uint_as_float(zw[jj] & 0xffff0000u);
            const float y0 = __uint_as_float((u32)ly[dql + 2 * jj][sl] << 16);
            const float y1 = __uint_as_float((u32)ly[dql + 2 * jj + 1][sl] << 16);
            ov[2 * jj]     = f2bu(y0 * (z0 * sigm(z0)));
            ov[2 * jj + 1] = f2bu(y1 * (z1 * sigm(z1)));
        }
        u16* op = (u16*)yall + row * E2 + dir2 * 1024 + dbase + dql;
        *(uint4*)op = *(uint4*)ov;
        *(uint4*)(op + 8) = *(uint4*)(ov + 8);
    }
}

// ---------------------------------------------------------------------------
// Fused: out_proj split-K reduce + residual -> xmid, then LN2 -> xn2 (bf16).
// ---------------------------------------------------------------------------
__global__ __launch_bounds__(256)
void k_redln(const float* __restrict__ part, const float* __restrict__ x,
             const float* __restrict__ w, const float* __restrict__ bb,
             float* __restrict__ xmid, __hip_bfloat16* __restrict__ xn2)
{
    const int row = blockIdx.x * 4 + (threadIdx.x >> 6);
    const int lane = threadIdx.x & 63;
    const size_t base = (size_t)row * DM;
    const int c0 = lane * 4, c1 = 256 + lane * 4;

    const float4 p0a = *(const float4*)(part + base + c0);
    const float4 p1a = *(const float4*)(part + 2097152 + base + c0);
    const float4 xa  = *(const float4*)(x + base + c0);
    const float4 p0b = *(const float4*)(part + base + c1);
    const float4 p1b = *(const float4*)(part + 2097152 + base + c1);
    const float4 xb  = *(const float4*)(x + base + c1);
    float v[8];
    v[0] = xa.x + p0a.x + p1a.x; v[1] = xa.y + p0a.y + p1a.y;
    v[2] = xa.z + p0a.z + p1a.z; v[3] = xa.w + p0a.w + p1a.w;
    v[4] = xb.x + p0b.x + p1b.x; v[5] = xb.y + p0b.y + p1b.y;
    v[6] = xb.z + p0b.z + p1b.z; v[7] = xb.w + p0b.w + p1b.w;
    float4 oa = { v[0], v[1], v[2], v[3] }, ob = { v[4], v[5], v[6], v[7] };
    *(float4*)(xmid + base + c0) = oa;
    *(float4*)(xmid + base + c1) = ob;

    float s = 0.f;
#pragma unroll
    for (int i = 0; i < 8; ++i) s += v[i];
#pragma unroll
    for (int off = 32; off > 0; off >>= 1) s += __shfl_xor(s, off);
    const float mean = s * (1.f / DM);
    float vs = 0.f;
#pragma unroll
    for (int i = 0; i < 8; ++i) { float dd = v[i] - mean; vs += dd * dd; }
#pragma unroll
    for (int off = 32; off > 0; off >>= 1) vs += __shfl_xor(vs, off);
    const float rstd = rsqrtf(vs * (1.f / DM) + 1e-5f);

    u16 o0[4], o1[4];
#pragma unroll
    for (int i = 0; i < 4; ++i) {
        o0[i] = f2bu((v[i] - mean) * rstd * w[c0 + i] + bb[c0 + i]);
        o1[i] = f2bu((v[4 + i] - mean) * rstd * w[c1 + i] + bb[c1 + i]);
    }
    *(uint2*)((u16*)xn2 + base + c0) = *(uint2*)o0;
    *(uint2*)((u16*)xn2 + base + c1) = *(uint2*)o1;
}

__global__ __launch_bounds__(256)
void k_redfc2(const float* __restrict__ part, const float* __restrict__ res,
              const float* __restrict__ bias, float* __restrict__ out)
{
    const int i = (blockIdx.x * 256 + threadIdx.x) * 4;   // over 4096*512
    const int col = i & (DM - 1);
    const float4 p0 = *(const float4*)(part + i);
    const float4 p1 = *(const float4*)(part + 2097152 + i);
    const float4 rv = *(const float4*)(res + i);
    const float4 bv = *(const float4*)(bias + col);
    float4 o;
    o.x = rv.x + bv.x + p0.x + p1.x; o.y = rv.y + bv.y + p0.y + p1.y;
    o.z = rv.z + bv.z + p0.z + p1.z; o.w = rv.w + bv.w + p0.w + p1.w;
    *(float4*)(out + i) = o;
}

// ---------------------------------------------------------------------------
// Launch
// ---------------------------------------------------------------------------
extern "C" void kernel_launch(void* const* d_in, const int* in_sizes, int n_in,
                              void* d_out, int out_size, void* d_ws, size_t ws_size,
                              hipStream_t stream)
{
    const float* x         = (const float*)d_in[0];
    const float* ln1_w     = (const float*)d_in[1];
    const float* ln1_b     = (const float*)d_in[2];
    const float* in_proj_w = (const float*)d_in[3];
    const float* conv_w[2]    = { (const float*)d_in[4],  (const float*)d_in[11] };
    const float* conv_b[2]    = { (const float*)d_in[5],  (const float*)d_in[12] };
    const float* x_proj_w[2]  = { (const float*)d_in[6],  (const float*)d_in[13] };
    const float* dt_proj_w[2] = { (const float*)d_in[7],  (const float*)d_in[14] };
    const float* dt_proj_b[2] = { (const float*)d_in[8],  (const float*)d_in[15] };
    const float* A_log[2]     = { (const float*)d_in[9],  (const float*)d_in[16] };
    const float* D_param[2]   = { (const float*)d_in[10], (const float*)d_in[17] };
    const float* out_proj_w = (const float*)d_in[18];
    const float* ln2_w      = (const float*)d_in[19];
    const float* ln2_b      = (const float*)d_in[20];
    const float* fc1_w      = (const float*)d_in[21];
    const float* fc1_b      = (const float*)d_in[22];
    const float* fc2_w      = (const float*)d_in[23];
    const float* fc2_b      = (const float*)d_in[24];
    float* out = (float*)d_out;

    char* ws = (char*)d_ws;
    const size_t MB = 1u << 20;
    // resident weights: 0..9.01 MB
    __hip_bfloat16* wip  = (__hip_bfloat16*)(ws + 0 * MB);
    __hip_bfloat16* wxp  = (__hip_bfloat16*)(ws + 2 * MB);
    __hip_bfloat16* wdt  = (__hip_bfloat16*)(ws + 2 * MB + 512 * 1024);
    __hip_bfloat16* wop  = (__hip_bfloat16*)(ws + 3 * MB);
    __hip_bfloat16* wfc1 = (__hip_bfloat16*)(ws + 5 * MB);
    __hip_bfloat16* wfc2 = (__hip_bfloat16*)(ws + 7 * MB);
    float* dtbias        = (float*)(ws + 9 * MB);
    // phase 1 lifetimes:
    __hip_bfloat16* xz   = (__hip_bfloat16*)(ws + 10 * MB);  // in_proj..p3
    __hip_bfloat16* ucv  = (__hip_bfloat16*)(ws + 26 * MB);  // conv..scanscan
    __hip_bfloat16* dtb  = (__hip_bfloat16*)(ws + 42 * MB);  // dtgemm..scanscan
    float* xdbp          = (float*)(ws + 58 * MB);           // xproj..k_red2 (16 MB)
    float* Ps            = (float*)(ws + 58 * MB);           // scanscan..p2 (8 MB)
    float* Hend          = (float*)(ws + 66 * MB);           // scanscan..p3 (8 MB)
    __hip_bfloat16* xn1  = (__hip_bfloat16*)(ws + 74 * MB);  // ln1..in_proj
    __hip_bfloat16* xdbb = (__hip_bfloat16*)(ws + 78 * MB);  // k_red2..dtgemm
    u32* sdtdu           = (u32*)(ws + 74 * MB);             // scanscan..p3 (32 MB)
    float* part          = (float*)(ws + 74 * MB);           // opgemm/fc2 partials
                                                             // (16 MB, after p3)
    __hip_bfloat16* yall = (__hip_bfloat16*)(ws + 26 * MB);  // p3..opgemm (over ucv)
    float* sB4           = (float*)(ws + 106 * MB);          // k_red2..p3
    float* sC4           = (float*)(ws + 106 * MB + 512 * 1024);  // peak 107 MB
    // phase 2 (mamba buffers dead):
    float* xmid          = (float*)(ws + 10 * MB);           // k_redln..redfc2
    __hip_bfloat16* xn2  = (__hip_bfloat16*)(ws + 18 * MB);
    __hip_bfloat16* h1   = (__hip_bfloat16*)(ws + 42 * MB);  // fc1..fc2 (over dtb)

    // --- weight prep ---
    k_prep<<<18432, 256, 0, stream>>>(
        in_proj_w, fc1_w, fc2_w, x_proj_w[0], x_proj_w[1],
        dt_proj_w[0], dt_proj_w[1], dt_proj_b[0], dt_proj_b[1], out_proj_w,
        wip, wfc1, wfc2, wxp, wdt, wop, dtbias);

    // --- mamba branch ---
    ln_kernel<<<ROWS, 64, 0, stream>>>(x, ln1_w, ln1_b, xn1);

    mgemm<0, 1, 1><<<dim3(16, 32, 1), 256, 0, stream>>>(
        xn1, DM, wip, DM, nullptr, nullptr, 0, xz, E2, ROWS, DM);

    conv2_kernel<<<(B_ * L_ * E2) / 256, 256, 0, stream>>>(
        xz, conv_w[0], conv_b[0], conv_w[1], conv_b[1], ucv);

    mgemm<0, 2, 8><<<dim3(1, 32, 8), 256, 0, stream>>>(
        ucv, E2, wxp, E2, nullptr, nullptr, 0, xdbp, 128, ROWS, E2);
    k_red2<<<2048, 256, 0, stream>>>(xdbp, xdbb, sB4, sC4);

    mgemm<1, 1, 1><<<dim3(16, 32, 1), 256, 0, stream>>>(
        xdbb, 128, wdt, 128, dtbias, nullptr, 0, dtb, E2, ROWS, 128);

    // fused transpose + local scan (replaces scanprep + scan_p1)
    k_scanscan<<<2048, 256, 0, stream>>>(
        dtb, ucv, sB4, A_log[0], A_log[1], sdtdu, Ps, Hend);
    scan_p2<<<NCH / 16, 256, 0, stream>>>(Ps, Hend);
    scan_p3<<<(CH * NCH) / 64, 256, 0, stream>>>(
        sdtdu, sB4, sC4, A_log[0], A_log[1], D_param[0], D_param[1],
        Hend, xz, yall);

    // out_proj split-K=2 -> partials; fused reduce+residual+LN2
    mgemm<0, 2, 2><<<dim3(4, 32, 2), 256, 0, stream>>>(
        yall, E2, wop, E2, nullptr, nullptr, 0, part, DM, ROWS, E2);
    k_redln<<<1024, 256, 0, stream>>>(part, x, ln2_w, ln2_b, xmid, xn2);

    // --- MLP branch ---
    mgemm<3, 1, 1><<<dim3(16, 32, 1), 256, 0, stream>>>(
        xn2, DM, wfc1, DM, fc1_b, nullptr, 0, h1, HID, ROWS, DM);

    mgemm<0, 2, 2><<<dim3(4, 32, 2), 256, 0, stream>>>(
        h1, HID, wfc2, HID, nullptr, nullptr, 0, part, DM, ROWS, HID);
    k_redfc2<<<2048, 256, 0, stream>>>(part, xmid, fc2_b, out);
}

// Round 13
// 235.786 us; speedup vs baseline: 18.0919x; 1.1129x over previous
//
#include <hip/hip_runtime.h>
#include <hip/hip_bf16.h>

// ---------------------------------------------------------------------------
// MotionMambaBlock forward. Round 13: conv rewritten as register-sliding-
// window, 8-wide vectorized (1x16B load + 1x16B store per 8 outputs).
// ---------------------------------------------------------------------------

#define B_   2
#define L_   2048
#define DM   512
#define DI   1024
#define E2   2048
#define NS   16
#define HID  2048
#define ROWS (B_ * L_)     // 4096
#define CH   32            // scan chunks
#define TT   (L_ / CH)     // 64
#define NCH  4096          // chains = 2 dirs * B * DI

typedef __bf16 bf16_t;
typedef bf16_t bf16x8 __attribute__((ext_vector_type(8)));
typedef float f32x4 __attribute__((ext_vector_type(4)));
typedef unsigned int u32;
typedef unsigned short u16;

__device__ __forceinline__ float fexp2(float x) { return __builtin_amdgcn_exp2f(x); }
__device__ __forceinline__ float fexp(float x)  { return fexp2(x * 1.44269504f); }
__device__ __forceinline__ float frcp(float x)  { return __builtin_amdgcn_rcpf(x); }
__device__ __forceinline__ float sigm(float x)  { return frcp(1.f + fexp2(-1.44269504f * x)); }

template<int PAT>
__device__ __forceinline__ float swzadd(float q)
{
    return q + __int_as_float(__builtin_amdgcn_ds_swizzle(__float_as_int(q), PAT));
}

__device__ __forceinline__ u16 f2bu(float f)
{
    __hip_bfloat16 h = __float2bfloat16(f);
    return *(u16*)&h;
}

// ---------------------------------------------------------------------------
// LayerNorm over D=512, one wave per row, bf16 output (LN1).
// ---------------------------------------------------------------------------
__global__ __launch_bounds__(64)
void ln_kernel(const float* __restrict__ in, const float* __restrict__ w,
               const float* __restrict__ b, __hip_bfloat16* __restrict__ out)
{
    const int row  = blockIdx.x;
    const int lane = threadIdx.x;
    const float* p = in + (size_t)row * DM;
    float v[8];
    float s = 0.f;
#pragma unroll
    for (int i = 0; i < 8; ++i) { v[i] = p[lane + 64 * i]; s += v[i]; }
#pragma unroll
    for (int off = 32; off > 0; off >>= 1) s += __shfl_xor(s, off);
    const float mean = s * (1.f / DM);
    float vs = 0.f;
#pragma unroll
    for (int i = 0; i < 8; ++i) { float d = v[i] - mean; vs += d * d; }
#pragma unroll
    for (int off = 32; off > 0; off >>= 1) vs += __shfl_xor(vs, off);
    const float rstd = rsqrtf(vs * (1.f / DM) + 1e-5f);
    __hip_bfloat16* o = out + (size_t)row * DM;
#pragma unroll
    for (int i = 0; i < 8; ++i) {
        const int c = lane + 64 * i;
        o[c] = __float2bfloat16((v[i] - mean) * rstd * w[c] + b[c]);
    }
}

// ---------------------------------------------------------------------------
// bf16 MFMA GEMM: C[M][N] = epi( A[M][K] * W[N][K]^T ). 128x128 tile, BK=32.
// MODE: 0=none, 1=softplus(v+bias), 3=gelu(v+bias)
// OUT:  0=f32, 1=bf16, 2=f32 split-K partial
// ---------------------------------------------------------------------------
template<int MODE, int OUT, int SPLITK>
__global__ __launch_bounds__(256)
void mgemm(const __hip_bfloat16* __restrict__ A, int lda,
           const __hip_bfloat16* __restrict__ W, int ldw,
           const float* __restrict__ bias,
           const float* __restrict__ res, int ldres,
           void* __restrict__ Cptr, int ldc,
           int M, int K)
{
    __shared__ __align__(16) bf16_t lsA[128 * 32];
    __shared__ __align__(16) bf16_t lsB[128 * 32];

    const int bm = blockIdx.y * 128;
    const int bn = blockIdx.x * 128;
    const int kLen = K / SPLITK;
    const int kBeg = blockIdx.z * kLen;

    const int t = threadIdx.x;
    const int l = t & 63, wid = t >> 6;
    const int wr = wid >> 1, wc = wid & 1;
    const int lrow = l & 15, lk = l >> 4;
    const int xorf = (lrow >> 1) & 3;
    const int rdoff = (lk ^ xorf) * 8;

    const int r0 = t >> 2,          c0 = t & 3;
    const int r1 = (256 + t) >> 2,  c1 = t & 3;
    const int sc0 = c0 ^ ((r0 >> 1) & 3);
    const int sc1 = c1 ^ ((r1 >> 1) & 3);

    const bf16_t* gA0 = (const bf16_t*)A + (size_t)(bm + r0) * lda + kBeg + sc0 * 8;
    const bf16_t* gA1 = (const bf16_t*)A + (size_t)(bm + r1) * lda + kBeg + sc1 * 8;
    const bf16_t* gB0 = (const bf16_t*)W + (size_t)(bn + r0) * ldw + kBeg + sc0 * 8;
    const bf16_t* gB1 = (const bf16_t*)W + (size_t)(bn + r1) * ldw + kBeg + sc1 * 8;
    bf16_t* dA0 = &lsA[(size_t)t * 8];
    bf16_t* dA1 = &lsA[(size_t)(256 + t) * 8];
    bf16_t* dB0 = &lsB[(size_t)t * 8];
    bf16_t* dB1 = &lsB[(size_t)(256 + t) * 8];

    f32x4 acc[4][4] = {};

    for (int k0 = 0; k0 < kLen; k0 += 32) {
        __builtin_amdgcn_global_load_lds(
            (const __attribute__((address_space(1))) void*)gA0,
            (__attribute__((address_space(3))) void*)dA0, 16, 0, 0);
        __builtin_amdgcn_global_load_lds(
            (const __attribute__((address_space(1))) void*)gA1,
            (__attribute__((address_space(3))) void*)dA1, 16, 0, 0);
        __builtin_amdgcn_global_load_lds(
            (const __attribute__((address_space(1))) void*)gB0,
            (__attribute__((address_space(3))) void*)dB0, 16, 0, 0);
        __builtin_amdgcn_global_load_lds(
            (const __attribute__((address_space(1))) void*)gB1,
            (__attribute__((address_space(3))) void*)dB1, 16, 0, 0);
        gA0 += 32; gA1 += 32; gB0 += 32; gB1 += 32;
        __syncthreads();

        bf16x8 af[4], bfv[4];
#pragma unroll
        for (int m = 0; m < 4; ++m) {
            const int ra = wr * 64 + m * 16 + lrow;
            af[m] = *(const bf16x8*)&lsA[ra * 32 + rdoff];
        }
#pragma unroll
        for (int n = 0; n < 4; ++n) {
            const int rb = wc * 64 + n * 16 + lrow;
            bfv[n] = *(const bf16x8*)&lsB[rb * 32 + rdoff];
        }
#pragma unroll
        for (int m = 0; m < 4; ++m)
#pragma unroll
            for (int n = 0; n < 4; ++n)
                acc[m][n] = __builtin_amdgcn_mfma_f32_16x16x32_bf16(
                    af[m], bfv[n], acc[m][n], 0, 0, 0);
        __syncthreads();
    }

    float* Cf = (float*)Cptr;
    __hip_bfloat16* Cb = (__hip_bfloat16*)Cptr;
    if (OUT == 2) Cf += (size_t)blockIdx.z * M * ldc;

#pragma unroll
    for (int m = 0; m < 4; ++m) {
#pragma unroll
        for (int n = 0; n < 4; ++n) {
#pragma unroll
            for (int j = 0; j < 4; ++j) {
                const int row = bm + wr * 64 + m * 16 + lk * 4 + j;
                const int col = bn + wc * 64 + n * 16 + lrow;
                float v = acc[m][n][j];
                if (MODE == 1) {
                    v += bias[col];
                    v = (v > 20.f) ? v
                        : 0.69314718f * __builtin_amdgcn_logf(1.f + fexp2(1.44269504f * v));
                } else if (MODE == 3) {
                    v += bias[col];
                    v = 0.5f * v * (1.f + erff(v * 0.70710678118654752f));
                }
                if (OUT == 1) Cb[(size_t)row * ldc + col] = __float2bfloat16(v);
                else          Cf[(size_t)row * ldc + col] = v;
            }
        }
    }
}

// ---------------------------------------------------------------------------
// Combined weight prep (range-dispatched on blockIdx).
// ---------------------------------------------------------------------------
__global__ __launch_bounds__(256)
void k_prep(const float* __restrict__ ipw, const float* __restrict__ f1w,
            const float* __restrict__ f2w,
            const float* __restrict__ xpf, const float* __restrict__ xpb,
            const float* __restrict__ dwf, const float* __restrict__ dwb,
            const float* __restrict__ dbf, const float* __restrict__ dbb,
            const float* __restrict__ wo,
            __hip_bfloat16* __restrict__ wip, __hip_bfloat16* __restrict__ wfc1,
            __hip_bfloat16* __restrict__ wfc2, __hip_bfloat16* __restrict__ wxp,
            __hip_bfloat16* __restrict__ wdt, __hip_bfloat16* __restrict__ wop,
            float* __restrict__ dtbias)
{
    const int bid = blockIdx.x;
    const int tid = threadIdx.x;
    if (bid < 4096) {
        const int i = bid * 256 + tid;
        wip[i] = __float2bfloat16(ipw[i]);
    } else if (bid < 8192) {
        const int i = (bid - 4096) * 256 + tid;
        wfc1[i] = __float2bfloat16(f1w[i]);
    } else if (bid < 12288) {
        const int i = (bid - 8192) * 256 + tid;
        wfc2[i] = __float2bfloat16(f2w[i]);
    } else if (bid < 13312) {
        const int idx = (bid - 12288) * 256 + tid;   // 128*2048
        const int r = idx >> 11, c = idx & 2047;
        float v = 0.f;
        if (r < 64) { if (c < 1024) v = xpf[r * 1024 + c]; }
        else        { if (c >= 1024) v = xpb[(r - 64) * 1024 + (c - 1024)]; }
        wxp[idx] = __float2bfloat16(v);
    } else if (bid < 14336) {
        const int idx = (bid - 13312) * 256 + tid;   // 2048*128
        const int r = idx >> 7, c = idx & 127;
        float v = 0.f;
        if (r < 1024) { if (c < 32) v = dwf[r * 32 + c]; }
        else          { if (c >= 64 && c < 96) v = dwb[(r - 1024) * 32 + (c - 64)]; }
        wdt[idx] = __float2bfloat16(v);
        if (idx < 2048) dtbias[idx] = (idx < 1024) ? dbf[idx] : dbb[idx - 1024];
    } else {
        const int idx = (bid - 14336) * 256 + tid;   // 512*2048
        const int r = idx >> 11, c = idx & 2047;
        wop[idx] = __float2bfloat16(0.5f * wo[r * 1024 + (c & 1023)]);
    }
}

// ---------------------------------------------------------------------------
// Depthwise conv (k=4) + SiLU, register sliding window, 8-wide d vector.
// Thread: (b, dir, d8 group of 8 channels) x 8 timesteps.
// dir0: out[t] = b + w0*x[t-3] + w1*x[t-2] + w2*x[t-1] + w3*x[t]
// dir1: out[t] = b + w0*x[t+3] + w1*x[t+2] + w2*x[t+1] + w3*x[t]
// ---------------------------------------------------------------------------
#define CSTEPS 8
__global__ __launch_bounds__(256)
void conv3_kernel(const __hip_bfloat16* __restrict__ xz,
                  const float* __restrict__ wf, const float* __restrict__ bf_,
                  const float* __restrict__ wb, const float* __restrict__ bb_,
                  __hip_bfloat16* __restrict__ out)
{
    const int gid = blockIdx.x * 256 + threadIdx.x;
    const int d8  = gid & 127;
    const int dir = (gid >> 7) & 1;
    const int b   = (gid >> 8) & 1;
    const int tc  = gid >> 9;              // 0..(L/CSTEPS-1)
    const int t0  = tc * CSTEPS;
    const int d0  = d8 * 8;

    // weights + bias in registers
    const float* wsrc = (dir ? wb : wf) + d0 * 4;
    const float* bsrc = (dir ? bb_ : bf_) + d0;
    float w0[8], w1[8], w2[8], w3[8], bs[8];
#pragma unroll
    for (int dd = 0; dd < 8; ++dd) {
        const float4 wv = *(const float4*)(wsrc + dd * 4);
        w0[dd] = wv.x; w1[dd] = wv.y; w2[dd] = wv.z; w3[dd] = wv.w;
    }
    {
        const float4 b0 = *(const float4*)bsrc;
        const float4 b1 = *(const float4*)(bsrc + 4);
        bs[0] = b0.x; bs[1] = b0.y; bs[2] = b0.z; bs[3] = b0.w;
        bs[4] = b1.x; bs[5] = b1.y; bs[6] = b1.z; bs[7] = b1.w;
    }

    const u16* ubase = (const u16*)xz + (size_t)b * L_ * E2 + d0;
    u16* obase = (u16*)out + (size_t)b * L_ * E2 + dir * 1024 + d0;

    // row load + unpack (zero outside [0,L))
    auto loadrow = [&](int tt, float* r) {
        if (tt >= 0 && tt < L_) {
            const uint4 v = *(const uint4*)(ubase + (size_t)tt * E2);
            const u32 vw[4] = { v.x, v.y, v.z, v.w };
#pragma unroll
            for (int jj = 0; jj < 4; ++jj) {
                r[2 * jj]     = __uint_as_float(vw[jj] << 16);
                r[2 * jj + 1] = __uint_as_float(vw[jj] & 0xffff0000u);
            }
        } else {
#pragma unroll
            for (int jj = 0; jj < 8; ++jj) r[jj] = 0.f;
        }
    };

    float r0[8], r1[8], r2[8], rN[8];
    if (dir == 0) { loadrow(t0 - 3, r0); loadrow(t0 - 2, r1); loadrow(t0 - 1, r2); }
    else          { loadrow(t0, r0); loadrow(t0 + 1, r1); loadrow(t0 + 2, r2); }

    for (int i = 0; i < CSTEPS; ++i) {
        const int t = t0 + i;
        loadrow(dir ? (t + 3) : t, rN);
        u16 ov[8];
#pragma unroll
        for (int dd = 0; dd < 8; ++dd) {
            float acc;
            if (dir == 0)
                acc = bs[dd] + w0[dd] * r0[dd] + w1[dd] * r1[dd]
                             + w2[dd] * r2[dd] + w3[dd] * rN[dd];
            else
                acc = bs[dd] + w0[dd] * rN[dd] + w1[dd] * r2[dd]
                             + w2[dd] * r1[dd] + w3[dd] * r0[dd];
            ov[dd] = f2bu(acc * sigm(acc));
        }
        *(uint4*)(obase + (size_t)t * E2) = *(uint4*)ov;
#pragma unroll
        for (int dd = 0; dd < 8; ++dd) { r0[dd] = r1[dd]; r1[dd] = r2[dd]; r2[dd] = rN[dd]; }
    }
}

// ---------------------------------------------------------------------------
// Split-K(8) reduce for x_proj + scatter B/C into scan-order [g][s][16] f32.
// ---------------------------------------------------------------------------
__global__ void k_red2(const float* __restrict__ part,
                       __hip_bfloat16* __restrict__ xb,
                       float* __restrict__ sB4, float* __restrict__ sC4)
{
    const int idx = blockIdx.x * 256 + threadIdx.x;   // 4096*128
    float s4 = 0.f;
#pragma unroll
    for (int z = 0; z < 8; ++z) s4 += part[idx + z * 524288];
    xb[idx] = __float2bfloat16(s4);
    const int col = idx & 127, row = idx >> 7;
    const int c64 = col & 63, dirq = col >> 6;
    if (c64 >= 32) {
        const int bq = row >> 11, tt = row & 2047;
        const int s = dirq ? (L_ - 1 - tt) : tt;
        const int n = c64 & 15;
        const int g = dirq * 2 + bq;
        float* dst = (c64 < 48 ? sB4 : sC4) + ((size_t)g * L_ + s) * 16 + n;
        *dst = s4;
    }
}

// ---------------------------------------------------------------------------
// Fused transpose + local scan (p1). Block tile = 64 chains x 64 steps.
// ---------------------------------------------------------------------------
__global__ __launch_bounds__(256)
void k_scanscan(const __hip_bfloat16* __restrict__ dtb,
                const __hip_bfloat16* __restrict__ ucv,
                const float* __restrict__ sB4,
                const float* __restrict__ AlF, const float* __restrict__ AlB,
                u32* __restrict__ sdtdu,
                float* __restrict__ P, float* __restrict__ Hend)
{
    __shared__ u32 lds[64][65];   // [chain_local][step]
    __shared__ float lBs[64 * 16];
    const int bid = blockIdx.x;
    const int st  = bid & 31;          // chunk index (64 steps)
    const int dtl = (bid >> 5) & 15;
    const int b   = (bid >> 9) & 1;
    const int dir = bid >> 10;
    const int tid = threadIdx.x;
    const int g = dir * 2 + b;

    // Phase A: load 64x64 tile of dt/u, pack into LDS [d][s]; stage B.
    {
        ((float4*)lBs)[tid] =
            ((const float4*)(sB4 + ((size_t)g * L_ + st * 64) * 16))[tid];
        const int c8 = (tid & 7) * 8;
#pragma unroll
        for (int rr = 0; rr < 2; ++rr) {
            const int r = (tid >> 3) + rr * 32;    // step local 0..63
            const int s = st * 64 + r;
            const int tt = dir ? (L_ - 1 - s) : s;
            const size_t row = (size_t)b * L_ + tt;
            const int e = dir * 1024 + dtl * 64 + c8;
            const uint4 dv = *(const uint4*)((const u16*)dtb + row * E2 + e);
            const uint4 uv = *(const uint4*)((const u16*)ucv + row * E2 + e);
            const u32 dw[4] = { dv.x, dv.y, dv.z, dv.w };
            const u32 uw[4] = { uv.x, uv.y, uv.z, uv.w };
#pragma unroll
            for (int jj = 0; jj < 4; ++jj) {
                lds[c8 + 2 * jj][r]     = ((uw[jj] & 0xffffu) << 16) | (dw[jj] & 0xffffu);
                lds[c8 + 2 * jj + 1][r] = (uw[jj] & 0xffff0000u) | (dw[jj] >> 16);
            }
        }
    }
    __syncthreads();

    // Phase B: write sdtdu [chain][step] (16 u32 per thread).
    {
        const int cd = tid >> 2, s16 = (tid & 3) * 16;
        const int chain = dir * 2048 + b * 1024 + dtl * 64 + cd;
        u32* dst = sdtdu + (size_t)chain * L_ + st * 64 + s16;
#pragma unroll
        for (int jj = 0; jj < 4; ++jj) {
            uint4 v;
            v.x = lds[cd][s16 + 4 * jj + 0];
            v.y = lds[cd][s16 + 4 * jj + 1];
            v.z = lds[cd][s16 + 4 * jj + 2];
            v.w = lds[cd][s16 + 4 * jj + 3];
            *(uint4*)(dst + 4 * jj) = v;
        }
    }

    // Phase C: local scan over the 64 steps (dt/u + B both from LDS).
    {
        const int j = tid & 3;
        const int cd = tid >> 2;
        const int chain = dir * 2048 + b * 1024 + dtl * 64 + cd;
        const int d = chain & 1023;
        const float* Al = dir ? AlB : AlF;
        const float4 al = *(const float4*)(Al + d * NS + j * 4);
        const float An2[4] = { -fexp(al.x) * 1.44269504f, -fexp(al.y) * 1.44269504f,
                               -fexp(al.z) * 1.44269504f, -fexp(al.w) * 1.44269504f };

        float h[4] = { 0.f, 0.f, 0.f, 0.f };
        float sdt = 0.f;
        for (int i = 0; i < 64; ++i) {
            const u32 w32 = lds[cd][i];
            const float dt = __uint_as_float(w32 << 16);
            const float uu = __uint_as_float(w32 & 0xffff0000u);
            const float w = dt * uu;
            const float4 B4 = *(const float4*)(lBs + i * 16 + j * 4);
            h[0] = fexp2(dt * An2[0]) * h[0] + w * B4.x;
            h[1] = fexp2(dt * An2[1]) * h[1] + w * B4.y;
            h[2] = fexp2(dt * An2[2]) * h[2] + w * B4.z;
            h[3] = fexp2(dt * An2[3]) * h[3] + w * B4.w;
            sdt += dt;
        }
        const int task = st * NCH + chain;
        float4 Pv = { fexp2(An2[0] * sdt), fexp2(An2[1] * sdt),
                      fexp2(An2[2] * sdt), fexp2(An2[3] * sdt) };
        *(float4*)(P + (size_t)task * NS + j * 4) = Pv;
        float4 Hv = { h[0], h[1], h[2], h[3] };
        *(float4*)(Hend + (size_t)task * NS + j * 4) = Hv;
    }
}

__global__ __launch_bounds__(256)
void scan_p2(const float* __restrict__ P, float* __restrict__ Hend)
{
    const int tid = threadIdx.x;
    const int n = tid & 15;
    const int chain = blockIdx.x * 16 + (tid >> 4);
    float hin = 0.f;
    for (int c = 0; c < CH; ++c) {
        const size_t idx = ((size_t)c * NCH + chain) * NS + n;
        const float nh = P[idx] * hin + Hend[idx];
        Hend[idx] = hin;
        hin = nh;
    }
}

// p3: scan (B/C from LDS) + in-LDS transpose + SiLU(z) gate + yall write.
__global__ __launch_bounds__(256)
void scan_p3(const u32* __restrict__ sdtdu, const float* __restrict__ sB4,
             const float* __restrict__ sC4,
             const float* __restrict__ AlF, const float* __restrict__ AlB,
             const float* __restrict__ DpF, const float* __restrict__ DpB,
             const float* __restrict__ Hin,
             const __hip_bfloat16* __restrict__ xz,
             __hip_bfloat16* __restrict__ yall)
{
    __shared__ u16 ly[64][70];
    __shared__ float lB[64 * 16];
    __shared__ float lC[64 * 16];
    const int tid = threadIdx.x;
    const int j = tid & 3;
    const int task = blockIdx.x * 64 + (tid >> 2);
    const int chain = task & (NCH - 1);
    const int c = task >> 12;
    const int dir = chain >> 11;
    const int b = (chain >> 10) & 1;
    const int d = chain & 1023;
    const int g = dir * 2 + b;

    {
        const float* gBp = sB4 + ((size_t)g * L_ + c * TT) * 16;
        const float* gCp = sC4 + ((size_t)g * L_ + c * TT) * 16;
        ((float4*)lB)[tid] = ((const float4*)gBp)[tid];
        ((float4*)lC)[tid] = ((const float4*)gCp)[tid];
    }
    __syncthreads();

    const float* Al = dir ? AlB : AlF;
    const float4 al = *(const float4*)(Al + d * NS + j * 4);
    const float An2[4] = { -fexp(al.x) * 1.44269504f, -fexp(al.y) * 1.44269504f,
                           -fexp(al.z) * 1.44269504f, -fexp(al.w) * 1.44269504f };
    const float Dd = (dir ? DpB : DpF)[d];

    const u32* pdt = sdtdu + (size_t)chain * L_ + c * TT;

    const float4 hv = *(const float4*)(Hin + (size_t)task * NS + j * 4);
    float h[4] = { hv.x, hv.y, hv.z, hv.w };

    for (int i = 0; i < TT; i += 4) {
        const uint4 pk = *(const uint4*)(pdt + i);
        const u32 wv[4] = { pk.x, pk.y, pk.z, pk.w };
        float qv[4], us[4];
#pragma unroll
        for (int k = 0; k < 4; ++k) {
            const float dt = __uint_as_float(wv[k] << 16);
            const float uu = __uint_as_float(wv[k] & 0xffff0000u);
            us[k] = uu;
            const float w = dt * uu;
            const float4 B4 = *(const float4*)(lB + (i + k) * 16 + j * 4);
            const float4 C4 = *(const float4*)(lC + (i + k) * 16 + j * 4);
            h[0] = fexp2(dt * An2[0]) * h[0] + w * B4.x;
            h[1] = fexp2(dt * An2[1]) * h[1] + w * B4.y;
            h[2] = fexp2(dt * An2[2]) * h[2] + w * B4.z;
            h[3] = fexp2(dt * An2[3]) * h[3] + w * B4.w;
            qv[k] = h[0] * C4.x + h[1] * C4.y + h[2] * C4.z + h[3] * C4.w;
        }
#pragma unroll
        for (int k = 0; k < 4; ++k) qv[k] = swzadd<0x041F>(qv[k]);
#pragma unroll
        for (int k = 0; k < 4; ++k) qv[k] = swzadd<0x081F>(qv[k]);
        if (j == 0) {
            u32* lp = (u32*)&ly[tid >> 2][i];
            lp[0] = (u32)f2bu(qv[0] + us[0] * Dd) | ((u32)f2bu(qv[1] + us[1] * Dd) << 16);
            lp[1] = (u32)f2bu(qv[2] + us[2] * Dd) | ((u32)f2bu(qv[3] + us[3] * Dd) << 16);
        }
    }
    __syncthreads();

    {
        const int cb = (blockIdx.x * 64) & (NCH - 1);
        const int dir2 = cb >> 11, b2 = (cb >> 10) & 1, dbase = cb & 1023;
        const int c2 = (blockIdx.x * 64) >> 12;
        const int sl = tid >> 2;
        const int dql = (tid & 3) * 16;
        const int s = c2 * TT + sl;
        const int tt = dir2 ? (L_ - 1 - s) : s;
        const size_t row = (size_t)b2 * L_ + tt;
        const u16* zp = (const u16*)xz + row * E2 + 1024 + dbase + dql;
        const uint4 zv0 = *(const uint4*)zp;
        const uint4 zv1 = *(const uint4*)(zp + 8);
        const u32 zw[8] = { zv0.x, zv0.y, zv0.z, zv0.w, zv1.x, zv1.y, zv1.z, zv1.w };
        u16 ov[16];
#pragma unroll
        for (int jj = 0; jj < 8; ++jj) {
            const float z0 = __uint_as_float(zw[jj] << 16);
            const float z1 = __uint_as_float(zw[jj] & 0xffff0000u);
            const float y0 = __uint_as_float((u32)ly[dql + 2 * jj][sl] << 16);
            const float y1 = __uint_as_float((u32)ly[dql + 2 * jj + 1][sl] << 16);
            ov[2 * jj]     = f2bu(y0 * (z0 * sigm(z0)));
            ov[2 * jj + 1] = f2bu(y1 * (z1 * sigm(z1)));
        }
        u16* op = (u16*)yall + row * E2 + dir2 * 1024 + dbase + dql;
        *(uint4*)op = *(uint4*)ov;
        *(uint4*)(op + 8) = *(uint4*)(ov + 8);
    }
}

// ---------------------------------------------------------------------------
// Fused: out_proj split-K reduce + residual -> xmid, then LN2 -> xn2 (bf16).
// ---------------------------------------------------------------------------
__global__ __launch_bounds__(256)
void k_redln(const float* __restrict__ part, const float* __restrict__ x,
             const float* __restrict__ w, const float* __restrict__ bb,
             float* __restrict__ xmid, __hip_bfloat16* __restrict__ xn2)
{
    const int row = blockIdx.x * 4 + (threadIdx.x >> 6);
    const int lane = threadIdx.x & 63;
    const size_t base = (size_t)row * DM;
    const int c0 = lane * 4, c1 = 256 + lane * 4;

    const float4 p0a = *(const float4*)(part + base + c0);
    const float4 p1a = *(const float4*)(part + 2097152 + base + c0);
    const float4 xa  = *(const float4*)(x + base + c0);
    const float4 p0b = *(const float4*)(part + base + c1);
    const float4 p1b = *(const float4*)(part + 2097152 + base + c1);
    const float4 xb  = *(const float4*)(x + base + c1);
    float v[8];
    v[0] = xa.x + p0a.x + p1a.x; v[1] = xa.y + p0a.y + p1a.y;
    v[2] = xa.z + p0a.z + p1a.z; v[3] = xa.w + p0a.w + p1a.w;
    v[4] = xb.x + p0b.x + p1b.x; v[5] = xb.y + p0b.y + p1b.y;
    v[6] = xb.z + p0b.z + p1b.z; v[7] = xb.w + p0b.w + p1b.w;
    float4 oa = { v[0], v[1], v[2], v[3] }, ob = { v[4], v[5], v[6], v[7] };
    *(float4*)(xmid + base + c0) = oa;
    *(float4*)(xmid + base + c1) = ob;

    float s = 0.f;
#pragma unroll
    for (int i = 0; i < 8; ++i) s += v[i];
#pragma unroll
    for (int off = 32; off > 0; off >>= 1) s += __shfl_xor(s, off);
    const float mean = s * (1.f / DM);
    float vs = 0.f;
#pragma unroll
    for (int i = 0; i < 8; ++i) { float dd = v[i] - mean; vs += dd * dd; }
#pragma unroll
    for (int off = 32; off > 0; off >>= 1) vs += __shfl_xor(vs, off);
    const float rstd = rsqrtf(vs * (1.f / DM) + 1e-5f);

    u16 o0[4], o1[4];
#pragma unroll
    for (int i = 0; i < 4; ++i) {
        o0[i] = f2bu((v[i] - mean) * rstd * w[c0 + i] + bb[c0 + i]);
        o1[i] = f2bu((v[4 + i] - mean) * rstd * w[c1 + i] + bb[c1 + i]);
    }
    *(uint2*)((u16*)xn2 + base + c0) = *(uint2*)o0;
    *(uint2*)((u16*)xn2 + base + c1) = *(uint2*)o1;
}

__global__ __launch_bounds__(256)
void k_redfc2(const float* __restrict__ part, const float* __restrict__ res,
              const float* __restrict__ bias, float* __restrict__ out)
{
    const int i = (blockIdx.x * 256 + threadIdx.x) * 4;   // over 4096*512
    const int col = i & (DM - 1);
    const float4 p0 = *(const float4*)(part + i);
    const float4 p1 = *(const float4*)(part + 2097152 + i);
    const float4 rv = *(const float4*)(res + i);
    const float4 bv = *(const float4*)(bias + col);
    float4 o;
    o.x = rv.x + bv.x + p0.x + p1.x; o.y = rv.y + bv.y + p0.y + p1.y;
    o.z = rv.z + bv.z + p0.z + p1.z; o.w = rv.w + bv.w + p0.w + p1.w;
    *(float4*)(out + i) = o;
}

// ---------------------------------------------------------------------------
// Launch
// ---------------------------------------------------------------------------
extern "C" void kernel_launch(void* const* d_in, const int* in_sizes, int n_in,
                              void* d_out, int out_size, void* d_ws, size_t ws_size,
                              hipStream_t stream)
{
    const float* x         = (const float*)d_in[0];
    const float* ln1_w     = (const float*)d_in[1];
    const float* ln1_b     = (const float*)d_in[2];
    const float* in_proj_w = (const float*)d_in[3];
    const float* conv_w[2]    = { (const float*)d_in[4],  (const float*)d_in[11] };
    const float* conv_b[2]    = { (const float*)d_in[5],  (const float*)d_in[12] };
    const float* x_proj_w[2]  = { (const float*)d_in[6],  (const float*)d_in[13] };
    const float* dt_proj_w[2] = { (const float*)d_in[7],  (const float*)d_in[14] };
    const float* dt_proj_b[2] = { (const float*)d_in[8],  (const float*)d_in[15] };
    const float* A_log[2]     = { (const float*)d_in[9],  (const float*)d_in[16] };
    const float* D_param[2]   = { (const float*)d_in[10], (const float*)d_in[17] };
    const float* out_proj_w = (const float*)d_in[18];
    const float* ln2_w      = (const float*)d_in[19];
    const float* ln2_b      = (const float*)d_in[20];
    const float* fc1_w      = (const float*)d_in[21];
    const float* fc1_b      = (const float*)d_in[22];
    const float* fc2_w      = (const float*)d_in[23];
    const float* fc2_b      = (const float*)d_in[24];
    float* out = (float*)d_out;

    char* ws = (char*)d_ws;
    const size_t MB = 1u << 20;
    // resident weights: 0..9.01 MB
    __hip_bfloat16* wip  = (__hip_bfloat16*)(ws + 0 * MB);
    __hip_bfloat16* wxp  = (__hip_bfloat16*)(ws + 2 * MB);
    __hip_bfloat16* wdt  = (__hip_bfloat16*)(ws + 2 * MB + 512 * 1024);
    __hip_bfloat16* wop  = (__hip_bfloat16*)(ws + 3 * MB);
    __hip_bfloat16* wfc1 = (__hip_bfloat16*)(ws + 5 * MB);
    __hip_bfloat16* wfc2 = (__hip_bfloat16*)(ws + 7 * MB);
    float* dtbias        = (float*)(ws + 9 * MB);
    // phase 1 lifetimes:
    __hip_bfloat16* xz   = (__hip_bfloat16*)(ws + 10 * MB);  // in_proj..p3
    __hip_bfloat16* ucv  = (__hip_bfloat16*)(ws + 26 * MB);  // conv..scanscan
    __hip_bfloat16* dtb  = (__hip_bfloat16*)(ws + 42 * MB);  // dtgemm..scanscan
    float* xdbp          = (float*)(ws + 58 * MB);           // xproj..k_red2 (16 MB)
    float* Ps            = (float*)(ws + 58 * MB);           // scanscan..p2 (8 MB)
    float* Hend          = (float*)(ws + 66 * MB);           // scanscan..p3 (8 MB)
    __hip_bfloat16* xn1  = (__hip_bfloat16*)(ws + 74 * MB);  // ln1..in_proj
    __hip_bfloat16* xdbb = (__hip_bfloat16*)(ws + 78 * MB);  // k_red2..dtgemm
    u32* sdtdu           = (u32*)(ws + 74 * MB);             // scanscan..p3 (32 MB)
    float* part          = (float*)(ws + 74 * MB);           // opgemm/fc2 partials
    __hip_bfloat16* yall = (__hip_bfloat16*)(ws + 26 * MB);  // p3..opgemm (over ucv)
    float* sB4           = (float*)(ws + 106 * MB);          // k_red2..p3
    float* sC4           = (float*)(ws + 106 * MB + 512 * 1024);  // peak 107 MB
    // phase 2 (mamba buffers dead):
    float* xmid          = (float*)(ws + 10 * MB);           // k_redln..redfc2
    __hip_bfloat16* xn2  = (__hip_bfloat16*)(ws + 18 * MB);
    __hip_bfloat16* h1   = (__hip_bfloat16*)(ws + 42 * MB);  // fc1..fc2 (over dtb)

    // --- weight prep ---
    k_prep<<<18432, 256, 0, stream>>>(
        in_proj_w, fc1_w, fc2_w, x_proj_w[0], x_proj_w[1],
        dt_proj_w[0], dt_proj_w[1], dt_proj_b[0], dt_proj_b[1], out_proj_w,
        wip, wfc1, wfc2, wxp, wdt, wop, dtbias);

    // --- mamba branch ---
    ln_kernel<<<ROWS, 64, 0, stream>>>(x, ln1_w, ln1_b, xn1);

    mgemm<0, 1, 1><<<dim3(16, 32, 1), 256, 0, stream>>>(
        xn1, DM, wip, DM, nullptr, nullptr, 0, xz, E2, ROWS, DM);

    conv3_kernel<<<(2 * 2 * 128 * (L_ / CSTEPS)) / 256, 256, 0, stream>>>(
        xz, conv_w[0], conv_b[0], conv_w[1], conv_b[1], ucv);

    mgemm<0, 2, 8><<<dim3(1, 32, 8), 256, 0, stream>>>(
        ucv, E2, wxp, E2, nullptr, nullptr, 0, xdbp, 128, ROWS, E2);
    k_red2<<<2048, 256, 0, stream>>>(xdbp, xdbb, sB4, sC4);

    mgemm<1, 1, 1><<<dim3(16, 32, 1), 256, 0, stream>>>(
        xdbb, 128, wdt, 128, dtbias, nullptr, 0, dtb, E2, ROWS, 128);

    k_scanscan<<<2048, 256, 0, stream>>>(
        dtb, ucv, sB4, A_log[0], A_log[1], sdtdu, Ps, Hend);
    scan_p2<<<NCH / 16, 256, 0, stream>>>(Ps, Hend);
    scan_p3<<<(CH * NCH) / 64, 256, 0, stream>>>(
        sdtdu, sB4, sC4, A_log[0], A_log[1], D_param[0], D_param[1],
        Hend, xz, yall);

    // out_proj split-K=2 -> partials; fused reduce+residual+LN2
    mgemm<0, 2, 2><<<dim3(4, 32, 2), 256, 0, stream>>>(
        yall, E2, wop, E2, nullptr, nullptr, 0, part, DM, ROWS, E2);
    k_redln<<<1024, 256, 0, stream>>>(part, x, ln2_w, ln2_b, xmid, xn2);

    // --- MLP branch ---
    mgemm<3, 1, 1><<<dim3(16, 32, 1), 256, 0, stream>>>(
        xn2, DM, wfc1, DM, fc1_b, nullptr, 0, h1, HID, ROWS, DM);

    mgemm<0, 2, 2><<<dim3(4, 32, 2), 256, 0, stream>>>(
        h1, HID, wfc2, HID, nullptr, nullptr, 0, part, DM, ROWS, HID);
    k_redfc2<<<2048, 256, 0, stream>>>(part, xmid, fc2_b, out);
}